// Round 4
// baseline (977.968 us; speedup 1.0000x reference)
//
#include <hip/hip_runtime.h>
#include <stdint.h>

#define B_    64
#define T_    49
#define E_    512
#define H_    512
#define ENC_  1024
#define V_    32000
#define G4_   2048        // 4*H
#define M_    3136        // T_*B_
#define MPAD_ 3328        // 13*256
#define NPROD 32
#define NBLK  256
#define NTM   13
#define NTN   125
#define NTILES (NTM * NTN)   // 1625

typedef __attribute__((ext_vector_type(8))) short bf16x8;
typedef __attribute__((ext_vector_type(4))) float f32x4;

static __device__ __forceinline__ unsigned short f2bf(float f) {
  union { float f; uint32_t u; } v; v.f = f;
  uint32_t r = v.u + 0x7FFFu + ((v.u >> 16) & 1u);
  return (unsigned short)(r >> 16);
}

static __device__ __forceinline__ void async16(const void* g, void* lds) {
  __builtin_amdgcn_global_load_lds(
      (const __attribute__((address_space(1))) unsigned int*)g,
      (__attribute__((address_space(3))) unsigned int*)lds, 16, 0, 0);
}

static __device__ __forceinline__ float sigf(float x) { return 1.0f / (1.0f + expf(-x)); }

// ---------------- convert weights to bf16 (+ embeddings transpose (b,t)->(t,b)) ----------------
__global__ __launch_bounds__(256) void convert_kernel(
    const float* __restrict__ Wih, const float* __restrict__ Whh,
    const float* __restrict__ Wfc, const float* __restrict__ emb,
    unsigned short* __restrict__ WihB, unsigned short* __restrict__ WhhB,
    unsigned short* __restrict__ WfcB, unsigned short* __restrict__ AxB) {
  const int n_wih = (G4_ * E_) / 4;
  const int n_whh = (G4_ * H_) / 4;
  const int n_wfc = (V_ * H_) / 4;
  const int n_emb = (B_ * T_ * E_) / 4;
  const int n_pad = ((MPAD_ - M_) * E_) / 4;
  const long total = (long)n_wih + n_whh + n_wfc + n_emb + n_pad;
  for (long u = (long)blockIdx.x * blockDim.x + threadIdx.x; u < total;
       u += (long)gridDim.x * blockDim.x) {
    long i = u;
    if (i < n_wih) {
      float4 v = ((const float4*)Wih)[i];
      ushort4 o; o.x = f2bf(v.x); o.y = f2bf(v.y); o.z = f2bf(v.z); o.w = f2bf(v.w);
      ((ushort4*)WihB)[i] = o; continue;
    }
    i -= n_wih;
    if (i < n_whh) {
      float4 v = ((const float4*)Whh)[i];
      ushort4 o; o.x = f2bf(v.x); o.y = f2bf(v.y); o.z = f2bf(v.z); o.w = f2bf(v.w);
      ((ushort4*)WhhB)[i] = o; continue;
    }
    i -= n_whh;
    if (i < n_wfc) {
      float4 v = ((const float4*)Wfc)[i];
      ushort4 o; o.x = f2bf(v.x); o.y = f2bf(v.y); o.z = f2bf(v.z); o.w = f2bf(v.w);
      ((ushort4*)WfcB)[i] = o; continue;
    }
    i -= n_wfc;
    if (i < n_emb) {
      int bt = (int)(i >> 7);
      int e4 = (int)(i & 127);
      int b = bt / T_, t = bt - b * T_;
      float4 v = ((const float4*)emb)[i];
      ushort4 o; o.x = f2bf(v.x); o.y = f2bf(v.y); o.z = f2bf(v.z); o.w = f2bf(v.w);
      ((ushort4*)AxB)[((long)(t * 64 + b) << 7) + e4] = o; continue;
    }
    i -= n_emb;
    ushort4 z; z.x = z.y = z.z = z.w = 0;
    ((ushort4*)AxB)[((long)M_ << 7) + i] = z;
  }
}

// ---------------- init: h0, c0 (fp32) + decode_lengths to out tail ----------------
__global__ __launch_bounds__(256) void init_kernel(
    const float* __restrict__ enc, const int* __restrict__ cap,
    const float* __restrict__ Wh, const float* __restrict__ bh,
    const float* __restrict__ Wc, const float* __restrict__ bc,
    unsigned short* __restrict__ h0b, float* __restrict__ c0,
    float* __restrict__ out_dl) {
  __shared__ __align__(16) float e[ENC_];
  const int b = blockIdx.x, q = blockIdx.y, tid = threadIdx.x;
  ((float4*)e)[tid] = ((const float4*)(enc + (size_t)b * ENC_))[tid];
  __syncthreads();
  const bool is_c = tid >= 128;
  const int j = q * 128 + (tid & 127);
  const float* W = is_c ? Wc : Wh;
  float s = is_c ? bc[j] : bh[j];
  const float4* wr = (const float4*)(W + (size_t)j * ENC_);
  const float4* e4 = (const float4*)e;
#pragma unroll 4
  for (int k = 0; k < ENC_ / 4; ++k) {
    float4 w = wr[k], v = e4[k];
    s += w.x * v.x + w.y * v.y + w.z * v.z + w.w * v.w;
  }
  if (is_c) c0[(size_t)b * H_ + j] = s;
  else      h0b[(size_t)b * H_ + j] = f2bf(s);
  if (b == 0 && q == 0 && tid < B_) out_dl[tid] = (float)(cap[tid] - 1);
}

// ---------------- shared 256x256 bf16 GEMM mainloop (K=512, BK=64, 2-phase dbuf) ----------------
// A: [*,512] bf16 row-major rows m0..m0+255; Bm: [*,512] bf16 rows n0..n0+255.
// acc[rt][j]: rows wr*128+rt*16+(lane>>4)*4+r, cols wc*64+j*16+(lane&15).
static __device__ __forceinline__ void gemm256_mainloop(
    const unsigned short* __restrict__ A, const unsigned short* __restrict__ Bm,
    char* smem, int m0, int n0, int lane, int wv, int wr, int wc,
    f32x4 (&acc)[8][4]) {
  auto stage = [&](int buf, int kit) {
    const int k0b = kit * 128;
#pragma unroll
    for (int i = 0; i < 4; ++i) {
      int chunk = wv * 4 + i;             // 0..31, 1KB each
      int d = chunk * 1024 + lane * 16;   // byte in 32KB tile
      int row = d >> 7, colb = d & 127;
      int sc = colb ^ ((row & 7) << 4);   // pre-swizzled source (T2 both-sides)
      async16((const char*)A + (size_t)(m0 + row) * 1024 + k0b + sc,
              smem + buf * 32768 + chunk * 1024);
      async16((const char*)Bm + (size_t)(n0 + row) * 1024 + k0b + sc,
              smem + 65536 + buf * 32768 + chunk * 1024);
    }
  };
  stage(0, 0);
  __syncthreads();
  for (int kit = 0; kit < 8; ++kit) {
    const int buf = kit & 1;
    if (kit < 7) stage(buf ^ 1, kit + 1);
    const char* Ab = smem + buf * 32768;
    const char* Bb = smem + 65536 + buf * 32768;
#pragma unroll
    for (int kb = 0; kb < 2; ++kb) {
      const int colb = kb * 64 + (lane >> 4) * 16;
      bf16x8 bf[4];
#pragma unroll
      for (int j = 0; j < 4; ++j) {
        const int br = wc * 64 + j * 16 + (lane & 15);
        bf[j] = *(const bf16x8*)(Bb + br * 128 + (colb ^ ((br & 7) << 4)));
      }
#pragma unroll
      for (int rt = 0; rt < 8; ++rt) {
        const int ar = wr * 128 + rt * 16 + (lane & 15);
        bf16x8 af = *(const bf16x8*)(Ab + ar * 128 + (colb ^ ((ar & 7) << 4)));
#pragma unroll
        for (int j = 0; j < 4; ++j)
          acc[rt][j] = __builtin_amdgcn_mfma_f32_16x16x32_bf16(af, bf[j], acc[rt][j], 0, 0, 0);
      }
    }
    __syncthreads();
  }
}

// ---------------- Gx GEMM: Gx = AxB @ WihB^T + bih + bhh ----------------
__global__ __launch_bounds__(512, 2) void gemm_gx(
    const unsigned short* __restrict__ A, const unsigned short* __restrict__ Bm,
    float* __restrict__ C, const float* __restrict__ bias0, const float* __restrict__ bias1) {
  __shared__ __align__(16) char smem[131072];
  const int tid = threadIdx.x, lane = tid & 63, wv = tid >> 6;
  const int wr = wv >> 2, wc = wv & 3;
  const int m0 = blockIdx.y * 256, n0 = blockIdx.x * 256;
  f32x4 acc[8][4] = {};
  gemm256_mainloop(A, Bm, smem, m0, n0, lane, wv, wr, wc, acc);
  float bz[4];
#pragma unroll
  for (int j = 0; j < 4; ++j) {
    const int col = n0 + wc * 64 + j * 16 + (lane & 15);
    bz[j] = bias0[col] + bias1[col];
  }
#pragma unroll
  for (int rt = 0; rt < 8; ++rt) {
    const int rbase = m0 + wr * 128 + rt * 16 + (lane >> 4) * 4;
#pragma unroll
    for (int j = 0; j < 4; ++j) {
      const int col = n0 + wc * 64 + j * 16 + (lane & 15);
#pragma unroll
      for (int r = 0; r < 4; ++r)
        C[(size_t)(rbase + r) * G4_ + col] = acc[rt][j][r] + bz[j];
    }
  }
}

// ---------------- fused: persistent LSTM producers (blocks 0..31) + vocab-GEMM consumers ----------------
// ctrl[w*16] = producer-w flag (monotonic); ctrl[512] = prog; ctrl[528] = tile counter.
__global__ __launch_bounds__(512, 2) void fused_kernel(
    const float* __restrict__ Gx, const unsigned short* __restrict__ WhhB,
    const unsigned short* __restrict__ h0b, const float* __restrict__ c0,
    unsigned short* __restrict__ hsl, unsigned short* __restrict__ Hall,
    const unsigned short* __restrict__ WfcB, const float* __restrict__ bfc,
    const int* __restrict__ cap, float* __restrict__ outp,
    int* __restrict__ ctrl) {
  __shared__ __align__(16) char smem[131072];
  __shared__ int s_tile;
  const int tid = threadIdx.x, lane = tid & 63, wv = tid >> 6;

  if (blockIdx.x < NPROD) {
    // ================= producer: one WG = 16 h-cols, all 49 steps =================
    __builtin_amdgcn_s_setprio(1);
    const int w = blockIdx.x, hc0 = w * 16;
    const bool act = tid < 256;
    const int g = wv & 3;
    const int chunk_hi = lane >> 5;
    bf16x8 wf[16];
    f32x4 creg = {};
    ushort4 hold = {};
    int b = 0, hq = 0, hc = 0, dl = 0, myoff = 0;
    int arb[4] = {};
    if (act) {
      const int gcol = g * 512 + hc0 + (lane & 15);
      const int ko = (lane >> 4) * 8;
#pragma unroll
      for (int kb = 0; kb < 16; ++kb)
        wf[kb] = *(const bf16x8*)&WhhB[(size_t)gcol * 512 + kb * 32 + ko];
      b = tid >> 2; hq = (tid & 3) * 4; hc = hc0 + hq;
      dl = cap[b] - 1;
      creg = *(const f32x4*)&c0[b * H_ + hc];
      hold = *(const ushort4*)&h0b[b * H_ + hc];
      myoff = ((b * 32) ^ (((b >> 2) & 7) << 4) ^ ((hq >> 3) << 4)) + ((hq & 7) * 2);
      *(ushort4*)((char*)hsl + w * 2048 + myoff) = hold;   // h(0) slice, buf0
#pragma unroll
      for (int rt = 0; rt < 4; ++rt) {
        int ar = rt * 16 + (lane & 15);
        arb[rt] = (ar * 32) ^ (((ar >> 2) & 7) << 4) ^ (((lane >> 4) & 1) << 4);
      }
    }
    float (*gl)[64][16] = (float (*)[64][16])(smem + 65536);
    __syncthreads();
    if (tid == 0)
      __hip_atomic_store(&ctrl[w * 16], 1, __ATOMIC_RELEASE, __HIP_MEMORY_SCOPE_AGENT);

    for (int t = 0; t < T_; ++t) {
      f32x4 xi = {}, xf = {}, xg = {}, xo = {};
      if (act) {
        const size_t gxr = ((size_t)t * 64 + b) * (size_t)G4_ + hc;
        xi = *(const f32x4*)&Gx[gxr + 0];
        xf = *(const f32x4*)&Gx[gxr + 512];
        xg = *(const f32x4*)&Gx[gxr + 1024];
        xo = *(const f32x4*)&Gx[gxr + 1536];
      }
      __builtin_amdgcn_sched_barrier(0);
      if (tid < 64) {
        const int need = t + 1;
        for (;;) {
          int v = (lane < NPROD)
                      ? __hip_atomic_load(&ctrl[lane * 16], __ATOMIC_RELAXED, __HIP_MEMORY_SCOPE_AGENT)
                      : need;
          if (__all(v >= need)) break;
          __builtin_amdgcn_s_sleep(1);
        }
        if (tid == 0) {
          __builtin_amdgcn_fence(__ATOMIC_ACQUIRE, "agent");
          if (w == 0 && t > 0)
            __hip_atomic_store(&ctrl[512], t, __ATOMIC_RELEASE, __HIP_MEMORY_SCOPE_AGENT);
        }
      }
      __syncthreads();
      // stage all 32 slices of h(t): 64KB linear (swizzle baked into slice data), 8 waves
      {
        const char* src = (const char*)hsl + (t & 1) * 65536;
#pragma unroll
        for (int it = 0; it < 8; ++it) {
          const int chunk = wv * 8 + it;
          async16(src + chunk * 1024 + lane * 16, smem + chunk * 1024);
        }
      }
      __syncthreads();
      if (act) {
        f32x4 accp[4] = {};
#pragma unroll
        for (int kb = 0; kb < 16; ++kb) {
          const int cbase = (kb * 2 + chunk_hi) * 2048;
#pragma unroll
          for (int rt = 0; rt < 4; ++rt) {
            bf16x8 af = *(const bf16x8*)(smem + cbase + arb[rt]);
            accp[rt] = __builtin_amdgcn_mfma_f32_16x16x32_bf16(af, wf[kb], accp[rt], 0, 0, 0);
          }
        }
#pragma unroll
        for (int rt = 0; rt < 4; ++rt)
#pragma unroll
          for (int r = 0; r < 4; ++r)
            gl[g][rt * 16 + (lane >> 4) * 4 + r][lane & 15] = accp[rt][r];
      }
      __syncthreads();
      if (act) {
        f32x4 vi = xi + *(const f32x4*)&gl[0][b][hq];
        f32x4 vf = xf + *(const f32x4*)&gl[1][b][hq];
        f32x4 vg = xg + *(const f32x4*)&gl[2][b][hq];
        f32x4 vo = xo + *(const f32x4*)&gl[3][b][hq];
        f32x4 cn;
        ushort4 hb16;
        {
          float hv[4];
#pragma unroll
          for (int k = 0; k < 4; ++k) {
            float iv = sigf(vi[k]), fv = sigf(vf[k]), gv = tanhf(vg[k]), ov = sigf(vo[k]);
            cn[k] = fv * creg[k] + iv * gv;
            hv[k] = ov * tanhf(cn[k]);
          }
          hb16.x = f2bf(hv[0]); hb16.y = f2bf(hv[1]); hb16.z = f2bf(hv[2]); hb16.w = f2bf(hv[3]);
        }
        *(ushort4*)&Hall[((size_t)t * 64 + b) * H_ + hc] = hb16;  // pre-mask h_new
        if (t < dl) { hold = hb16; creg = cn; }
        if (t + 1 < T_)
          *(ushort4*)((char*)hsl + ((t + 1) & 1) * 65536 + w * 2048 + myoff) = hold;
      }
      __syncthreads();   // drains this WG's global stores before flagging
      if (tid == 0)
        __hip_atomic_store(&ctrl[w * 16], t + 2, __ATOMIC_RELEASE, __HIP_MEMORY_SCOPE_AGENT);
    }
    if (w == 0 && tid < 64) {
      const int need = T_ + 1;
      for (;;) {
        int v = (lane < NPROD)
                    ? __hip_atomic_load(&ctrl[lane * 16], __ATOMIC_RELAXED, __HIP_MEMORY_SCOPE_AGENT)
                    : need;
        if (__all(v >= need)) break;
        __builtin_amdgcn_s_sleep(1);
      }
      if (tid == 0) {
        __builtin_amdgcn_fence(__ATOMIC_ACQUIRE, "agent");
        __hip_atomic_store(&ctrl[512], T_, __ATOMIC_RELEASE, __HIP_MEMORY_SCOPE_AGENT);
      }
    }
    __builtin_amdgcn_s_setprio(0);
  }

  // ================= consumer: 256x256 vocab GEMM tiles, dependency-gated =================
  const int wr = wv >> 2, wc = wv & 3;
  for (;;) {
    __syncthreads();
    if (tid == 0)
      s_tile = __hip_atomic_fetch_add(&ctrl[528], 1, __ATOMIC_RELAXED, __HIP_MEMORY_SCOPE_AGENT);
    __syncthreads();
    const int tile = s_tile;
    if (tile >= NTILES) break;
    const int mt = tile / NTN, nt = tile - mt * NTN;
    const int m0 = mt * 256, n0 = nt * 256;
    const int need = (4 * mt + 4 < T_) ? (4 * mt + 4) : T_;
    if (tid == 0) {
      while (__hip_atomic_load(&ctrl[512], __ATOMIC_RELAXED, __HIP_MEMORY_SCOPE_AGENT) < need)
        __builtin_amdgcn_s_sleep(8);
      __builtin_amdgcn_fence(__ATOMIC_ACQUIRE, "agent");
    }
    __syncthreads();

    f32x4 acc[8][4] = {};
    gemm256_mainloop(Hall, WfcB, smem, m0, n0, lane, wv, wr, wc, acc);

    // epilogue: two-half LDS transpose (XOR-swizzled) -> coalesced masked f32x4 stores
    float bz[4];
#pragma unroll
    for (int j = 0; j < 4; ++j) bz[j] = bfc[n0 + wc * 64 + j * 16 + (lane & 15)];
    float* Ct = (float*)smem;   // [128][256] f32
#pragma unroll
    for (int half = 0; half < 2; ++half) {
      __syncthreads();
      if (wr == half) {
#pragma unroll
        for (int rt = 0; rt < 8; ++rt) {
#pragma unroll
          for (int j = 0; j < 4; ++j) {
            const int col = wc * 64 + j * 16 + (lane & 15);
#pragma unroll
            for (int r = 0; r < 4; ++r) {
              const int lr = rt * 16 + (lane >> 4) * 4 + r;
              Ct[lr * 256 + (col ^ ((lr & 7) << 2))] = acc[rt][j][r] + bz[j];
            }
          }
        }
      }
      __syncthreads();
#pragma unroll
      for (int rr = 0; rr < 16; ++rr) {
        const int lr = rr * 8 + wv;
        const int grow = m0 + half * 128 + lr;
        if (grow >= M_) continue;
        const int tt = grow >> 6, bb = grow & 63;
        f32x4 v = {0.0f, 0.0f, 0.0f, 0.0f};
        if (tt < cap[bb] - 1)
          v = *(const f32x4*)&Ct[lr * 256 + ((lane * 4) ^ ((lr & 7) << 2))];
        *(f32x4*)(outp + ((size_t)bb * T_ + tt) * V_ + n0 + lane * 4) = v;
      }
    }
  }
}

// ---------------- launch ----------------
extern "C" void kernel_launch(void* const* d_in, const int* in_sizes, int n_in,
                              void* d_out, int out_size, void* d_ws, size_t ws_size,
                              hipStream_t stream) {
  const float* emb = (const float*)d_in[0];
  const float* enc = (const float*)d_in[1];
  const int*   cap = (const int*)d_in[2];
  const float* Wih = (const float*)d_in[3];
  const float* Whh = (const float*)d_in[4];
  const float* bih = (const float*)d_in[5];
  const float* bhh = (const float*)d_in[6];
  const float* Wh0 = (const float*)d_in[7];
  const float* bh0 = (const float*)d_in[8];
  const float* Wc0 = (const float*)d_in[9];
  const float* bc0 = (const float*)d_in[10];
  const float* Wfc = (const float*)d_in[11];
  const float* bfc = (const float*)d_in[12];
  float* out = (float*)d_out;

  char* ws = (char*)d_ws;
  size_t o = 0;
  auto carve = [&](size_t bytes) { void* p = ws + o; o += (bytes + 255) & ~(size_t)255; return p; };
  unsigned short* WihB = (unsigned short*)carve((size_t)G4_ * E_ * 2);
  unsigned short* WhhB = (unsigned short*)carve((size_t)G4_ * H_ * 2);
  unsigned short* WfcB = (unsigned short*)carve((size_t)V_ * H_ * 2);
  unsigned short* AxB  = (unsigned short*)carve((size_t)MPAD_ * E_ * 2);
  float*          Gx   = (float*)carve((size_t)MPAD_ * G4_ * 4);
  unsigned short* Hall = (unsigned short*)carve((size_t)MPAD_ * H_ * 2);
  unsigned short* h0b  = (unsigned short*)carve((size_t)B_ * H_ * 2);
  float*          cst  = (float*)carve((size_t)B_ * H_ * 4);
  unsigned short* hsl  = (unsigned short*)carve((size_t)2 * NPROD * 2048);
  int*            ctrl = (int*)carve(4096);
  (void)ws_size; (void)in_sizes; (void)n_in; (void)out_size;

  hipMemsetAsync(ctrl, 0, 4096, stream);
  convert_kernel<<<dim3(2048), dim3(256), 0, stream>>>(Wih, Whh, Wfc, emb, WihB, WhhB, WfcB, AxB);
  init_kernel<<<dim3(64, 4), dim3(256), 0, stream>>>(enc, cap, Wh0, bh0, Wc0, bc0, h0b, cst,
                                                     out + (size_t)B_ * T_ * V_);
  gemm_gx<<<dim3(G4_ / 256, MPAD_ / 256), dim3(512), 0, stream>>>(AxB, WihB, Gx, bih, bhh);
  fused_kernel<<<dim3(NBLK), dim3(512), 0, stream>>>(Gx, WhhB, h0b, cst, hsl, Hall,
                                                     WfcB, bfc, cap, out, ctrl);
}

// Round 5
// 548.084 us; speedup vs baseline: 1.7843x; 1.7843x over previous
//
#include <hip/hip_runtime.h>
#include <stdint.h>

#define B_    64
#define T_    49
#define E_    512
#define H_    512
#define ENC_  1024
#define V_    32000
#define G4_   2048        // 4*H
#define M_    3136        // T_*B_
#define MPAD_ 3200        // 25*128
#define NPROD 32
#define NWG   512
#define NTN   250         // 32000/128

typedef __attribute__((ext_vector_type(8))) short bf16x8;
typedef __attribute__((ext_vector_type(4))) float f32x4;

static __device__ __forceinline__ unsigned short f2bf(float f) {
  union { float f; uint32_t u; } v; v.f = f;
  uint32_t r = v.u + 0x7FFFu + ((v.u >> 16) & 1u);
  return (unsigned short)(r >> 16);
}

static __device__ __forceinline__ void async16(const void* g, void* lds) {
  __builtin_amdgcn_global_load_lds(
      (const __attribute__((address_space(1))) unsigned int*)g,
      (__attribute__((address_space(3))) unsigned int*)lds, 16, 0, 0);
}

static __device__ __forceinline__ float sigf(float x) { return 1.0f / (1.0f + expf(-x)); }

// ---------------- convert weights to bf16 (+ embeddings transpose (b,t)->(t,b)) ----------------
__global__ __launch_bounds__(256) void convert_kernel(
    const float* __restrict__ Wih, const float* __restrict__ Whh,
    const float* __restrict__ Wfc, const float* __restrict__ emb,
    unsigned short* __restrict__ WihB, unsigned short* __restrict__ WhhB,
    unsigned short* __restrict__ WfcB, unsigned short* __restrict__ AxB) {
  const int n_wih = (G4_ * E_) / 4;
  const int n_whh = (G4_ * H_) / 4;
  const int n_wfc = (V_ * H_) / 4;
  const int n_emb = (B_ * T_ * E_) / 4;
  const int n_pad = ((MPAD_ - M_) * E_) / 4;
  const long total = (long)n_wih + n_whh + n_wfc + n_emb + n_pad;
  for (long u = (long)blockIdx.x * blockDim.x + threadIdx.x; u < total;
       u += (long)gridDim.x * blockDim.x) {
    long i = u;
    if (i < n_wih) {
      float4 v = ((const float4*)Wih)[i];
      ushort4 o; o.x = f2bf(v.x); o.y = f2bf(v.y); o.z = f2bf(v.z); o.w = f2bf(v.w);
      ((ushort4*)WihB)[i] = o; continue;
    }
    i -= n_wih;
    if (i < n_whh) {
      float4 v = ((const float4*)Whh)[i];
      ushort4 o; o.x = f2bf(v.x); o.y = f2bf(v.y); o.z = f2bf(v.z); o.w = f2bf(v.w);
      ((ushort4*)WhhB)[i] = o; continue;
    }
    i -= n_whh;
    if (i < n_wfc) {
      float4 v = ((const float4*)Wfc)[i];
      ushort4 o; o.x = f2bf(v.x); o.y = f2bf(v.y); o.z = f2bf(v.z); o.w = f2bf(v.w);
      ((ushort4*)WfcB)[i] = o; continue;
    }
    i -= n_wfc;
    if (i < n_emb) {
      int bt = (int)(i >> 7);
      int e4 = (int)(i & 127);
      int b = bt / T_, t = bt - b * T_;
      float4 v = ((const float4*)emb)[i];
      ushort4 o; o.x = f2bf(v.x); o.y = f2bf(v.y); o.z = f2bf(v.z); o.w = f2bf(v.w);
      ((ushort4*)AxB)[((long)(t * 64 + b) << 7) + e4] = o; continue;
    }
    i -= n_emb;
    ushort4 z; z.x = z.y = z.z = z.w = 0;
    ((ushort4*)AxB)[((long)M_ << 7) + i] = z;
  }
}

// ---------------- init: h0, c0, decode_lengths + compaction metadata ----------------
// meta[0..48] = start[t]; meta[100]=Mc; meta[101]=MT; meta[102]=MT*NTN;
// meta[103]=NZROW; meta[104]=NZI; meta[105]=NTOT; meta[110+mt]=need[mt]
__global__ __launch_bounds__(256) void init_kernel(
    const float* __restrict__ enc, const int* __restrict__ cap,
    const float* __restrict__ Wh, const float* __restrict__ bh,
    const float* __restrict__ Wc, const float* __restrict__ bc,
    unsigned short* __restrict__ h0b, float* __restrict__ c0,
    float* __restrict__ out_dl, int* __restrict__ meta,
    int* __restrict__ rowmap, int* __restrict__ zrowmap) {
  __shared__ __align__(16) float e[ENC_];
  __shared__ int s_nb[T_];
  __shared__ int s_start[T_ + 1];
  const int b = blockIdx.x, q = blockIdx.y, tid = threadIdx.x;
  ((float4*)e)[tid] = ((const float4*)(enc + (size_t)b * ENC_))[tid];
  __syncthreads();
  const bool is_c = tid >= 128;
  const int j = q * 128 + (tid & 127);
  const float* W = is_c ? Wc : Wh;
  float s = is_c ? bc[j] : bh[j];
  const float4* wr = (const float4*)(W + (size_t)j * ENC_);
  const float4* e4 = (const float4*)e;
#pragma unroll 4
  for (int k = 0; k < ENC_ / 4; ++k) {
    float4 w = wr[k], v = e4[k];
    s += w.x * v.x + w.y * v.y + w.z * v.z + w.w * v.w;
  }
  if (is_c) c0[(size_t)b * H_ + j] = s;
  else      h0b[(size_t)b * H_ + j] = f2bf(s);
  if (b == 0 && q == 0 && tid < B_) out_dl[tid] = (float)(cap[tid] - 1);

  // ---- compaction metadata (block (0,0) only) ----
  if (b == 0 && q == 0) {
    __syncthreads();
    if (tid < T_) {
      int cnt = 0;
      for (int bb = 0; bb < B_; ++bb) cnt += (cap[bb] - 1 > tid) ? 1 : 0;
      s_nb[tid] = cnt;
    }
    __syncthreads();
    if (tid == 0) {
      int acc = 0;
      for (int t = 0; t < T_; ++t) { s_start[t] = acc; acc += s_nb[t]; }
      s_start[T_] = acc;
      const int Mc = acc;
      const int MT = (Mc + 127) >> 7;
      meta[100] = Mc;
      meta[101] = MT;
      meta[102] = MT * NTN;
      meta[103] = M_ - Mc;
      meta[104] = M_ - Mc;        // NZI: one zero-item per masked row
      meta[105] = (M_ - Mc) + MT * NTN;
      for (int i = Mc; i < MT * 128; ++i) rowmap[i] = -1;
    }
    __syncthreads();
    if (tid < T_) {
      meta[tid] = s_start[tid];
      const int st = s_start[tid], nb = s_nb[tid];
      for (int bb = 0; bb < nb; ++bb) rowmap[st + bb] = bb * T_ + tid;
      int zst = 0;
      for (int t2 = 0; t2 < tid; ++t2) zst += B_ - s_nb[t2];
      for (int bb = nb; bb < B_; ++bb) zrowmap[zst + (bb - nb)] = bb * T_ + tid;
    }
    __syncthreads();
    if (tid < 26) {
      const int Mc = s_start[T_];
      const int MT = (Mc + 127) >> 7;
      if (tid < MT) {
        int last = tid * 128 + 127;
        if (last > Mc - 1) last = Mc - 1;
        int tlast = 0;
        for (int t2 = 0; t2 < T_; ++t2) if (s_start[t2] <= last) tlast = t2;
        meta[110 + tid] = tlast + 1;
      }
    }
  }
}

// ---------------- zero the pad rows of compact Hall ----------------
__global__ __launch_bounds__(256) void pad_kernel(const int* __restrict__ meta,
                                                  unsigned short* __restrict__ Hall) {
  const int Mc = meta[100], MT = meta[101];
  const int tot = (MT * 128 - Mc) * 64;   // 16B chunks
  for (int i = blockIdx.x * blockDim.x + threadIdx.x; i < tot;
       i += gridDim.x * blockDim.x) {
    const int row = Mc + (i >> 6), c = i & 63;
    ushort4 z; z.x = z.y = z.z = z.w = 0;
    *(ushort4*)((char*)Hall + (size_t)row * 1024 + c * 16) = z;
  }
}

// ---------------- Gx GEMM: Gx = AxB @ WihB^T + bih + bhh (128x128 tile, K=512) ----------------
__global__ __launch_bounds__(256) void gemm_gx(
    const unsigned short* __restrict__ A, const unsigned short* __restrict__ Bm,
    float* __restrict__ C, const float* __restrict__ bias0, const float* __restrict__ bias1) {
  __shared__ __align__(16) char smem[65536];
  const int tid = threadIdx.x, lane = tid & 63, wid = tid >> 6;
  const int nt = blockIdx.x, mt = blockIdx.y;
  const int wr = wid >> 1, wc = wid & 1;
  const int m0 = mt * 128, n0 = nt * 128;
  f32x4 acc[4][4] = {};

  auto stage = [&](int buf, int kit) {
    const int k0b = kit * 128;
#pragma unroll
    for (int i = 0; i < 4; ++i) {
      int chunk = wid * 4 + i;
      int d = chunk * 1024 + lane * 16;
      int row = d >> 7, colb = d & 127;
      int sc = colb ^ ((row & 7) << 4);
      async16((const char*)A + (size_t)(m0 + row) * 1024 + k0b + sc,
              smem + buf * 16384 + chunk * 1024);
      async16((const char*)Bm + (size_t)(n0 + row) * 1024 + k0b + sc,
              smem + 32768 + buf * 16384 + chunk * 1024);
    }
  };

  stage(0, 0);
  __syncthreads();
  for (int kit = 0; kit < 8; ++kit) {
    const int buf = kit & 1;
    if (kit < 7) stage(buf ^ 1, kit + 1);
    const char* Ab = smem + buf * 16384;
    const char* Bb = smem + 32768 + buf * 16384;
#pragma unroll
    for (int kb = 0; kb < 2; ++kb) {
      const int colb = kb * 64 + (lane >> 4) * 16;
      bf16x8 af[4], bfb[4];
#pragma unroll
      for (int rt = 0; rt < 4; ++rt) {
        int ar = wr * 64 + rt * 16 + (lane & 15);
        af[rt] = *(const bf16x8*)(Ab + ar * 128 + (colb ^ ((ar & 7) << 4)));
        int br = wc * 64 + rt * 16 + (lane & 15);
        bfb[rt] = *(const bf16x8*)(Bb + br * 128 + (colb ^ ((br & 7) << 4)));
      }
#pragma unroll
      for (int i = 0; i < 4; ++i)
#pragma unroll
        for (int j = 0; j < 4; ++j)
          acc[i][j] = __builtin_amdgcn_mfma_f32_16x16x32_bf16(af[i], bfb[j], acc[i][j], 0, 0, 0);
    }
    __syncthreads();
  }
#pragma unroll
  for (int i = 0; i < 4; ++i) {
    const int rbase = m0 + wr * 64 + i * 16 + (lane >> 4) * 4;
#pragma unroll
    for (int j = 0; j < 4; ++j) {
      const int col = n0 + wc * 64 + j * 16 + (lane & 15);
#pragma unroll
      for (int r = 0; r < 4; ++r)
        C[(size_t)(rbase + r) * G4_ + col] = acc[i][j][r] + bias0[col] + bias1[col];
    }
  }
}

// ---------------- fused: persistent LSTM producers (blocks 0..31) + vocab-GEMM consumers ----------------
// ctrl[w*16] = producer-w flag (monotonic); ctrl[512] = prog; ctrl[528] = tile counter.
__global__ __launch_bounds__(256) void fused_kernel(
    const float* __restrict__ Gx, const unsigned short* __restrict__ WhhB,
    const unsigned short* __restrict__ h0b, const float* __restrict__ c0,
    unsigned short* __restrict__ hsl, unsigned short* __restrict__ Hall,
    const unsigned short* __restrict__ WfcB, const float* __restrict__ bfc,
    const int* __restrict__ cap, float* __restrict__ outp,
    int* __restrict__ ctrl, const int* __restrict__ meta,
    const int* __restrict__ rowmap, const int* __restrict__ zrowmap) {
  __shared__ __align__(16) char smem[81920];
  __shared__ int s_tile;
  const int tid = threadIdx.x, lane = tid & 63, g = tid >> 6;

  if (blockIdx.x < NPROD) {
    // ================= producer: one WG = 16 h-cols, all 49 steps =================
    __builtin_amdgcn_s_setprio(1);
    const int w = blockIdx.x, hc0 = w * 16;
    const int gcol = g * 512 + hc0 + (lane & 15);
    const int ko = (lane >> 4) * 8;
    bf16x8 wf[16];
#pragma unroll
    for (int kb = 0; kb < 16; ++kb)
      wf[kb] = *(const bf16x8*)&WhhB[(size_t)gcol * 512 + kb * 32 + ko];
    const int b = tid >> 2, hq = (tid & 3) * 4, hc = hc0 + hq;
    const int dl = cap[b] - 1;
    f32x4 creg = *(const f32x4*)&c0[b * H_ + hc];
    ushort4 hold = *(const ushort4*)&h0b[b * H_ + hc];
    const int myoff = ((b * 32) ^ (((b >> 2) & 7) << 4) ^ ((hq >> 3) << 4)) + ((hq & 7) * 2);
    *(ushort4*)((char*)hsl + w * 2048 + myoff) = hold;   // h(0) slice, buf0
    int arb[4];
#pragma unroll
    for (int rt = 0; rt < 4; ++rt) {
      int ar = rt * 16 + (lane & 15);
      arb[rt] = (ar * 32) ^ (((ar >> 2) & 7) << 4) ^ (((lane >> 4) & 1) << 4);
    }
    const int chunk_hi = lane >> 5;
    float (*gl)[64][16] = (float (*)[64][16])(smem + 65536);
    __syncthreads();
    if (tid == 0)
      __hip_atomic_store(&ctrl[w * 16], 1, __ATOMIC_RELEASE, __HIP_MEMORY_SCOPE_AGENT);

    for (int t = 0; t < T_; ++t) {
      const size_t gxr = ((size_t)t * 64 + b) * (size_t)G4_ + hc;
      f32x4 xi = *(const f32x4*)&Gx[gxr + 0];
      f32x4 xf = *(const f32x4*)&Gx[gxr + 512];
      f32x4 xg = *(const f32x4*)&Gx[gxr + 1024];
      f32x4 xo = *(const f32x4*)&Gx[gxr + 1536];
      __builtin_amdgcn_sched_barrier(0);
      if (tid < 64) {
        const int need = t + 1;
        for (;;) {
          int v = (lane < NPROD)
                      ? __hip_atomic_load(&ctrl[lane * 16], __ATOMIC_RELAXED, __HIP_MEMORY_SCOPE_AGENT)
                      : need;
          if (__all(v >= need)) break;
          __builtin_amdgcn_s_sleep(1);
        }
        if (tid == 0) {
          __builtin_amdgcn_fence(__ATOMIC_ACQUIRE, "agent");
          if (w == 0 && t > 0)
            __hip_atomic_store(&ctrl[512], t, __ATOMIC_RELEASE, __HIP_MEMORY_SCOPE_AGENT);
        }
      }
      __syncthreads();
      // stage all 32 slices of h(t): 64KB linear (swizzle baked into slice data)
      {
        const char* src = (const char*)hsl + (t & 1) * 65536;
#pragma unroll
        for (int it = 0; it < 16; ++it) {
          const int chunk = g * 16 + it;
          async16(src + chunk * 1024 + lane * 16, smem + chunk * 1024);
        }
      }
      __syncthreads();
      f32x4 accp[4] = {};
#pragma unroll
      for (int kb = 0; kb < 16; ++kb) {
        const int cbase = (kb * 2 + chunk_hi) * 2048;
#pragma unroll
        for (int rt = 0; rt < 4; ++rt) {
          bf16x8 af = *(const bf16x8*)(smem + cbase + arb[rt]);
          accp[rt] = __builtin_amdgcn_mfma_f32_16x16x32_bf16(af, wf[kb], accp[rt], 0, 0, 0);
        }
      }
#pragma unroll
      for (int rt = 0; rt < 4; ++rt)
#pragma unroll
        for (int r = 0; r < 4; ++r)
          gl[g][rt * 16 + (lane >> 4) * 4 + r][lane & 15] = accp[rt][r];
      __syncthreads();
      f32x4 vi = xi + *(const f32x4*)&gl[0][b][hq];
      f32x4 vf = xf + *(const f32x4*)&gl[1][b][hq];
      f32x4 vg = xg + *(const f32x4*)&gl[2][b][hq];
      f32x4 vo = xo + *(const f32x4*)&gl[3][b][hq];
      f32x4 cn;
      ushort4 hb16;
      {
        float hv[4];
#pragma unroll
        for (int k = 0; k < 4; ++k) {
          float iv = sigf(vi[k]), fv = sigf(vf[k]), gv = tanhf(vg[k]), ov = sigf(vo[k]);
          cn[k] = fv * creg[k] + iv * gv;
          hv[k] = ov * tanhf(cn[k]);
        }
        hb16.x = f2bf(hv[0]); hb16.y = f2bf(hv[1]); hb16.z = f2bf(hv[2]); hb16.w = f2bf(hv[3]);
      }
      if (t < dl)   // valid (t,b) <=> b < nb_t : write compact row start[t]+b
        *(ushort4*)&Hall[((size_t)(meta[t] + b)) * H_ + hc] = hb16;
      if (t < dl) { hold = hb16; creg = cn; }
      if (t + 1 < T_)
        *(ushort4*)((char*)hsl + ((t + 1) & 1) * 65536 + w * 2048 + myoff) = hold;
      __syncthreads();   // drains this WG's global stores before flagging
      if (tid == 0)
        __hip_atomic_store(&ctrl[w * 16], t + 2, __ATOMIC_RELEASE, __HIP_MEMORY_SCOPE_AGENT);
    }
    if (w == 0 && tid < 64) {
      const int need = T_ + 1;
      for (;;) {
        int v = (lane < NPROD)
                    ? __hip_atomic_load(&ctrl[lane * 16], __ATOMIC_RELAXED, __HIP_MEMORY_SCOPE_AGENT)
                    : need;
        if (__all(v >= need)) break;
        __builtin_amdgcn_s_sleep(1);
      }
      if (tid == 0) {
        __builtin_amdgcn_fence(__ATOMIC_ACQUIRE, "agent");
        __hip_atomic_store(&ctrl[512], T_, __ATOMIC_RELEASE, __HIP_MEMORY_SCOPE_AGENT);
      }
    }
    __builtin_amdgcn_s_setprio(0);
  }

  // ================= consumer: zero items + compact vocab-GEMM tiles =================
  const int NZI = meta[104];
  const int NTOT = meta[105];
  const int wid = tid >> 6;
  const int wr = wid >> 1, wc = wid & 1;
  for (;;) {
    __syncthreads();
    if (tid == 0)
      s_tile = __hip_atomic_fetch_add(&ctrl[528], 1, __ATOMIC_RELAXED, __HIP_MEMORY_SCOPE_AGENT);
    __syncthreads();
    const int tile = s_tile;
    if (tile >= NTOT) break;

    if (tile < NZI) {
      // zero item: one masked output row (32000 f32)
      const int bt = zrowmap[tile];
      f32x4* dst = (f32x4*)(outp + (size_t)bt * V_);
      f32x4 z = {0.0f, 0.0f, 0.0f, 0.0f};
      for (int i = tid; i < V_ / 4; i += 256) dst[i] = z;
      continue;
    }

    const int gt = tile - NZI;
    const int mt = gt / NTN, nt = gt - mt * NTN;
    const int m0 = mt * 128, n0 = nt * 128;
    const int need = meta[110 + mt];
    if (tid == 0) {
      while (__hip_atomic_load(&ctrl[512], __ATOMIC_RELAXED, __HIP_MEMORY_SCOPE_AGENT) < need)
        __builtin_amdgcn_s_sleep(8);
      __builtin_amdgcn_fence(__ATOMIC_ACQUIRE, "agent");
    }
    __syncthreads();

    f32x4 acc[4][4] = {};
    auto stage = [&](int buf, int kit) {
      const int k0b = kit * 128;
#pragma unroll
      for (int i = 0; i < 4; ++i) {
        int chunk = wid * 4 + i;
        int d = chunk * 1024 + lane * 16;
        int row = d >> 7, colb = d & 127;
        int sc = colb ^ ((row & 7) << 4);
        async16((const char*)Hall + (size_t)(m0 + row) * 1024 + k0b + sc,
                smem + buf * 16384 + chunk * 1024);
        async16((const char*)WfcB + (size_t)(n0 + row) * 1024 + k0b + sc,
                smem + 32768 + buf * 16384 + chunk * 1024);
      }
    };
    stage(0, 0);
    __syncthreads();
    for (int kit = 0; kit < 8; ++kit) {
      const int buf = kit & 1;
      if (kit < 7) stage(buf ^ 1, kit + 1);
      const char* Ab = smem + buf * 16384;
      const char* Bb = smem + 32768 + buf * 16384;
#pragma unroll
      for (int kb = 0; kb < 2; ++kb) {
        const int colb = kb * 64 + (lane >> 4) * 16;
        bf16x8 af[4], bfb[4];
#pragma unroll
        for (int rt = 0; rt < 4; ++rt) {
          int ar = wr * 64 + rt * 16 + (lane & 15);
          af[rt] = *(const bf16x8*)(Ab + ar * 128 + (colb ^ ((ar & 7) << 4)));
          int br = wc * 64 + rt * 16 + (lane & 15);
          bfb[rt] = *(const bf16x8*)(Bb + br * 128 + (colb ^ ((br & 7) << 4)));
        }
#pragma unroll
        for (int i = 0; i < 4; ++i)
#pragma unroll
          for (int j = 0; j < 4; ++j)
            acc[i][j] = __builtin_amdgcn_mfma_f32_16x16x32_bf16(af[i], bfb[j], acc[i][j], 0, 0, 0);
      }
      __syncthreads();
    }
    // epilogue: transpose through LDS (swizzled), coalesced scatter via rowmap
    float* Ct = (float*)smem;
#pragma unroll
    for (int j = 0; j < 4; ++j) {
      const int colL = wc * 64 + j * 16 + (lane & 15);
      const float bz = bfc[n0 + colL];
#pragma unroll
      for (int i = 0; i < 4; ++i) {
        const int rb = wr * 64 + i * 16 + (lane >> 4) * 4;
#pragma unroll
        for (int r = 0; r < 4; ++r) {
          const int row = rb + r;
          Ct[row * 128 + (colL ^ ((row & 7) << 2))] = acc[i][j][r] + bz;
        }
      }
    }
    __syncthreads();
    const int c4 = tid & 31;
    const int rsub = tid >> 5;
#pragma unroll
    for (int itr = 0; itr < 16; ++itr) {
      const int row = itr * 8 + rsub;
      const int bt = rowmap[m0 + row];
      if (bt < 0) continue;
      f32x4 v = *(const f32x4*)&Ct[row * 128 + ((c4 ^ (row & 7)) << 2)];
      *(f32x4*)(outp + (size_t)bt * V_ + n0 + (c4 << 2)) = v;
    }
  }
}

// ---------------- launch ----------------
extern "C" void kernel_launch(void* const* d_in, const int* in_sizes, int n_in,
                              void* d_out, int out_size, void* d_ws, size_t ws_size,
                              hipStream_t stream) {
  const float* emb = (const float*)d_in[0];
  const float* enc = (const float*)d_in[1];
  const int*   cap = (const int*)d_in[2];
  const float* Wih = (const float*)d_in[3];
  const float* Whh = (const float*)d_in[4];
  const float* bih = (const float*)d_in[5];
  const float* bhh = (const float*)d_in[6];
  const float* Wh0 = (const float*)d_in[7];
  const float* bh0 = (const float*)d_in[8];
  const float* Wc0 = (const float*)d_in[9];
  const float* bc0 = (const float*)d_in[10];
  const float* Wfc = (const float*)d_in[11];
  const float* bfc = (const float*)d_in[12];
  float* out = (float*)d_out;

  char* ws = (char*)d_ws;
  size_t o = 0;
  auto carve = [&](size_t bytes) { void* p = ws + o; o += (bytes + 255) & ~(size_t)255; return p; };
  unsigned short* WihB = (unsigned short*)carve((size_t)G4_ * E_ * 2);
  unsigned short* WhhB = (unsigned short*)carve((size_t)G4_ * H_ * 2);
  unsigned short* WfcB = (unsigned short*)carve((size_t)V_ * H_ * 2);
  unsigned short* AxB  = (unsigned short*)carve((size_t)MPAD_ * E_ * 2);
  float*          Gx   = (float*)carve((size_t)MPAD_ * G4_ * 4);
  unsigned short* Hall = (unsigned short*)carve((size_t)MPAD_ * H_ * 2);
  unsigned short* h0b  = (unsigned short*)carve((size_t)B_ * H_ * 2);
  float*          cst  = (float*)carve((size_t)B_ * H_ * 4);
  unsigned short* hsl  = (unsigned short*)carve((size_t)2 * NPROD * 2048);
  int*            ctrl = (int*)carve(4096);
  int*            meta = (int*)carve(1024);
  int*            rowmap = (int*)carve((size_t)MPAD_ * 4);
  int*            zrowmap = (int*)carve((size_t)MPAD_ * 4);
  (void)ws_size; (void)in_sizes; (void)n_in; (void)out_size;

  hipMemsetAsync(ctrl, 0, 4096, stream);
  convert_kernel<<<dim3(2048), dim3(256), 0, stream>>>(Wih, Whh, Wfc, emb, WihB, WhhB, WfcB, AxB);
  init_kernel<<<dim3(64, 4), dim3(256), 0, stream>>>(enc, cap, Wh0, bh0, Wc0, bc0, h0b, cst,
                                                     out + (size_t)B_ * T_ * V_,
                                                     meta, rowmap, zrowmap);
  pad_kernel<<<dim3(32), dim3(256), 0, stream>>>(meta, Hall);
  gemm_gx<<<dim3(G4_ / 128, MPAD_ / 128), dim3(256), 0, stream>>>(AxB, WihB, Gx, bih, bhh);
  fused_kernel<<<dim3(NWG), dim3(256), 0, stream>>>(Gx, WhhB, h0b, cst, hsl, Hall,
                                                    WfcB, bfc, cap, out, ctrl,
                                                    meta, rowmap, zrowmap);
}

// Round 6
// 467.746 us; speedup vs baseline: 2.0908x; 1.1718x over previous
//
#include <hip/hip_runtime.h>
#include <stdint.h>

#define B_    64
#define T_    49
#define E_    512
#define H_    512
#define ENC_  1024
#define V_    32000
#define G4_   2048        // 4*H
#define M_    3136        // T_*B_
#define MPAD_ 3200        // 25*128
#define NPROD 32
#define NWG   512
#define NTN   250         // 32000/128

typedef __attribute__((ext_vector_type(8))) short bf16x8;
typedef __attribute__((ext_vector_type(4))) float f32x4;

static __device__ __forceinline__ unsigned short f2bf(float f) {
  union { float f; uint32_t u; } v; v.f = f;
  uint32_t r = v.u + 0x7FFFu + ((v.u >> 16) & 1u);
  return (unsigned short)(r >> 16);
}

static __device__ __forceinline__ void async16(const void* g, void* lds) {
  __builtin_amdgcn_global_load_lds(
      (const __attribute__((address_space(1))) unsigned int*)g,
      (__attribute__((address_space(3))) unsigned int*)lds, 16, 0, 0);
}

static __device__ __forceinline__ float sigf(float x) { return 1.0f / (1.0f + expf(-x)); }

// ---------------- convert weights to bf16 (+ embeddings transpose (b,t)->(t,b)) ----------------
__global__ __launch_bounds__(256) void convert_kernel(
    const float* __restrict__ Wih, const float* __restrict__ Whh,
    const float* __restrict__ Wfc, const float* __restrict__ emb,
    unsigned short* __restrict__ WihB, unsigned short* __restrict__ WhhB,
    unsigned short* __restrict__ WfcB, unsigned short* __restrict__ AxB) {
  const int n_wih = (G4_ * E_) / 4;
  const int n_whh = (G4_ * H_) / 4;
  const int n_wfc = (V_ * H_) / 4;
  const int n_emb = (B_ * T_ * E_) / 4;
  const int n_pad = ((MPAD_ - M_) * E_) / 4;
  const long total = (long)n_wih + n_whh + n_wfc + n_emb + n_pad;
  for (long u = (long)blockIdx.x * blockDim.x + threadIdx.x; u < total;
       u += (long)gridDim.x * blockDim.x) {
    long i = u;
    if (i < n_wih) {
      float4 v = ((const float4*)Wih)[i];
      ushort4 o; o.x = f2bf(v.x); o.y = f2bf(v.y); o.z = f2bf(v.z); o.w = f2bf(v.w);
      ((ushort4*)WihB)[i] = o; continue;
    }
    i -= n_wih;
    if (i < n_whh) {
      float4 v = ((const float4*)Whh)[i];
      ushort4 o; o.x = f2bf(v.x); o.y = f2bf(v.y); o.z = f2bf(v.z); o.w = f2bf(v.w);
      ((ushort4*)WhhB)[i] = o; continue;
    }
    i -= n_whh;
    if (i < n_wfc) {
      float4 v = ((const float4*)Wfc)[i];
      ushort4 o; o.x = f2bf(v.x); o.y = f2bf(v.y); o.z = f2bf(v.z); o.w = f2bf(v.w);
      ((ushort4*)WfcB)[i] = o; continue;
    }
    i -= n_wfc;
    if (i < n_emb) {
      int bt = (int)(i >> 7);
      int e4 = (int)(i & 127);
      int b = bt / T_, t = bt - b * T_;
      float4 v = ((const float4*)emb)[i];
      ushort4 o; o.x = f2bf(v.x); o.y = f2bf(v.y); o.z = f2bf(v.z); o.w = f2bf(v.w);
      ((ushort4*)AxB)[((long)(t * 64 + b) << 7) + e4] = o; continue;
    }
    i -= n_emb;
    ushort4 z; z.x = z.y = z.z = z.w = 0;
    ((ushort4*)AxB)[((long)M_ << 7) + i] = z;
  }
}

// ---------------- init: h0, c0, decode_lengths + compaction metadata ----------------
// meta[0..48] = start[t]; meta[100]=Mc; meta[101]=MT; meta[102]=MT*NTN;
// meta[103]=NZROW; meta[104]=NZI; meta[105]=NTOT; meta[110+mt]=need[mt]
__global__ __launch_bounds__(256) void init_kernel(
    const float* __restrict__ enc, const int* __restrict__ cap,
    const float* __restrict__ Wh, const float* __restrict__ bh,
    const float* __restrict__ Wc, const float* __restrict__ bc,
    unsigned short* __restrict__ h0b, float* __restrict__ c0,
    float* __restrict__ out_dl, int* __restrict__ meta,
    int* __restrict__ rowmap, int* __restrict__ zrowmap) {
  __shared__ __align__(16) float e[ENC_];
  __shared__ int s_nb[T_];
  __shared__ int s_start[T_ + 1];
  const int b = blockIdx.x, q = blockIdx.y, tid = threadIdx.x;
  ((float4*)e)[tid] = ((const float4*)(enc + (size_t)b * ENC_))[tid];
  __syncthreads();
  const bool is_c = tid >= 128;
  const int j = q * 128 + (tid & 127);
  const float* W = is_c ? Wc : Wh;
  float s = is_c ? bc[j] : bh[j];
  const float4* wr = (const float4*)(W + (size_t)j * ENC_);
  const float4* e4 = (const float4*)e;
#pragma unroll 4
  for (int k = 0; k < ENC_ / 4; ++k) {
    float4 w = wr[k], v = e4[k];
    s += w.x * v.x + w.y * v.y + w.z * v.z + w.w * v.w;
  }
  if (is_c) c0[(size_t)b * H_ + j] = s;
  else      h0b[(size_t)b * H_ + j] = f2bf(s);
  if (b == 0 && q == 0 && tid < B_) out_dl[tid] = (float)(cap[tid] - 1);

  // ---- compaction metadata (block (0,0) only) ----
  if (b == 0 && q == 0) {
    __syncthreads();
    if (tid < T_) {
      int cnt = 0;
      for (int bb = 0; bb < B_; ++bb) cnt += (cap[bb] - 1 > tid) ? 1 : 0;
      s_nb[tid] = cnt;
    }
    __syncthreads();
    if (tid == 0) {
      int acc = 0;
      for (int t = 0; t < T_; ++t) { s_start[t] = acc; acc += s_nb[t]; }
      s_start[T_] = acc;
      const int Mc = acc;
      const int MT = (Mc + 127) >> 7;
      meta[100] = Mc;
      meta[101] = MT;
      meta[102] = MT * NTN;
      meta[103] = M_ - Mc;
      meta[104] = M_ - Mc;        // NZI
      meta[105] = (M_ - Mc) + MT * NTN;
      for (int i = Mc; i < MT * 128; ++i) rowmap[i] = -1;
    }
    __syncthreads();
    if (tid < T_) {
      meta[tid] = s_start[tid];
      const int st = s_start[tid], nb = s_nb[tid];
      for (int bb = 0; bb < nb; ++bb) rowmap[st + bb] = bb * T_ + tid;
      int zst = 0;
      for (int t2 = 0; t2 < tid; ++t2) zst += B_ - s_nb[t2];
      for (int bb = nb; bb < B_; ++bb) zrowmap[zst + (bb - nb)] = bb * T_ + tid;
    }
    __syncthreads();
    if (tid < 26) {
      const int Mc = s_start[T_];
      const int MT = (Mc + 127) >> 7;
      if (tid < MT) {
        int last = tid * 128 + 127;
        if (last > Mc - 1) last = Mc - 1;
        int tlast = 0;
        for (int t2 = 0; t2 < T_; ++t2) if (s_start[t2] <= last) tlast = t2;
        meta[110 + tid] = tlast + 1;
      }
    }
  }
}

// ---------------- zero the pad rows of compact Hall ----------------
__global__ __launch_bounds__(256) void pad_kernel(const int* __restrict__ meta,
                                                  unsigned short* __restrict__ Hall) {
  const int Mc = meta[100], MT = meta[101];
  const int tot = (MT * 128 - Mc) * 64;   // 16B chunks
  for (int i = blockIdx.x * blockDim.x + threadIdx.x; i < tot;
       i += gridDim.x * blockDim.x) {
    const int row = Mc + (i >> 6), c = i & 63;
    ushort4 z; z.x = z.y = z.z = z.w = 0;
    *(ushort4*)((char*)Hall + (size_t)row * 1024 + c * 16) = z;
  }
}

// ---------------- Gx GEMM: Gx = AxB @ WihB^T + bih + bhh (128x128 tile, K=512) ----------------
__global__ __launch_bounds__(256) void gemm_gx(
    const unsigned short* __restrict__ A, const unsigned short* __restrict__ Bm,
    float* __restrict__ C, const float* __restrict__ bias0, const float* __restrict__ bias1) {
  __shared__ __align__(16) char smem[65536];
  const int tid = threadIdx.x, lane = tid & 63, wid = tid >> 6;
  const int nt = blockIdx.x, mt = blockIdx.y;
  const int wr = wid >> 1, wc = wid & 1;
  const int m0 = mt * 128, n0 = nt * 128;
  f32x4 acc[4][4] = {};

  auto stage = [&](int buf, int kit) {
    const int k0b = kit * 128;
#pragma unroll
    for (int i = 0; i < 4; ++i) {
      int chunk = wid * 4 + i;
      int d = chunk * 1024 + lane * 16;
      int row = d >> 7, colb = d & 127;
      int sc = colb ^ ((row & 7) << 4);
      async16((const char*)A + (size_t)(m0 + row) * 1024 + k0b + sc,
              smem + buf * 16384 + chunk * 1024);
      async16((const char*)Bm + (size_t)(n0 + row) * 1024 + k0b + sc,
              smem + 32768 + buf * 16384 + chunk * 1024);
    }
  };

  stage(0, 0);
  __syncthreads();
  for (int kit = 0; kit < 8; ++kit) {
    const int buf = kit & 1;
    if (kit < 7) stage(buf ^ 1, kit + 1);
    const char* Ab = smem + buf * 16384;
    const char* Bb = smem + 32768 + buf * 16384;
#pragma unroll
    for (int kb = 0; kb < 2; ++kb) {
      const int colb = kb * 64 + (lane >> 4) * 16;
      bf16x8 af[4], bfb[4];
#pragma unroll
      for (int rt = 0; rt < 4; ++rt) {
        int ar = wr * 64 + rt * 16 + (lane & 15);
        af[rt] = *(const bf16x8*)(Ab + ar * 128 + (colb ^ ((ar & 7) << 4)));
        int br = wc * 64 + rt * 16 + (lane & 15);
        bfb[rt] = *(const bf16x8*)(Bb + br * 128 + (colb ^ ((br & 7) << 4)));
      }
#pragma unroll
      for (int i = 0; i < 4; ++i)
#pragma unroll
        for (int j = 0; j < 4; ++j)
          acc[i][j] = __builtin_amdgcn_mfma_f32_16x16x32_bf16(af[i], bfb[j], acc[i][j], 0, 0, 0);
    }
    __syncthreads();
  }
#pragma unroll
  for (int i = 0; i < 4; ++i) {
    const int rbase = m0 + wr * 64 + i * 16 + (lane >> 4) * 4;
#pragma unroll
    for (int j = 0; j < 4; ++j) {
      const int col = n0 + wc * 64 + j * 16 + (lane & 15);
#pragma unroll
      for (int r = 0; r < 4; ++r)
        C[(size_t)(rbase + r) * G4_ + col] = acc[i][j][r] + bias0[col] + bias1[col];
    }
  }
}

// ---------------- fused: persistent LSTM producers (blocks 0..31) + vocab-GEMM consumers ----------------
// ctrl[w*16] = producer-w flag (monotonic); ctrl[512] = prog; ctrl[528] = tile counter.
// All cross-WG data moves via relaxed agent-scope atomics (coherence point), so the
// loop needs NO acquire/release fences (no wbl2/inv): release = s_waitcnt vmcnt(0)
// + barrier + relaxed flag store; readers' loads are coherent or gated-cold.
__global__ __launch_bounds__(256) void fused_kernel(
    const float* __restrict__ Gx, const unsigned short* __restrict__ WhhB,
    const unsigned short* __restrict__ h0b, const float* __restrict__ c0,
    unsigned short* __restrict__ hsl, unsigned short* __restrict__ Hall,
    const unsigned short* __restrict__ WfcB, const float* __restrict__ bfc,
    const int* __restrict__ cap, float* __restrict__ outp,
    int* __restrict__ ctrl, const int* __restrict__ meta,
    const int* __restrict__ rowmap, const int* __restrict__ zrowmap) {
  __shared__ __align__(16) char smem[81920];   // exactly 80KB -> 2 blocks/CU
  const int tid = threadIdx.x, lane = tid & 63, g = tid >> 6;
  int* s_tile = (int*)(smem + 81916);  // overlaps tail of gl; gl dead in consumer phase

  if (blockIdx.x < NPROD) {
    // ================= producer: one WG = 16 h-cols, all 49 steps =================
    __builtin_amdgcn_s_setprio(1);
    const int w = blockIdx.x, hc0 = w * 16;
    const int gcol = g * 512 + hc0 + (lane & 15);
    const int ko = (lane >> 4) * 8;
    bf16x8 wf[16];
#pragma unroll
    for (int kb = 0; kb < 16; ++kb)
      wf[kb] = *(const bf16x8*)&WhhB[(size_t)gcol * 512 + kb * 32 + ko];
    const int b = tid >> 2, hq = (tid & 3) * 4, hc = hc0 + hq;
    const int dl = cap[b] - 1;
    f32x4 creg = *(const f32x4*)&c0[b * H_ + hc];
    ushort4 hold = *(const ushort4*)&h0b[b * H_ + hc];
    const int myoff = ((b * 32) ^ (((b >> 2) & 7) << 4) ^ ((hq >> 3) << 4)) + ((hq & 7) * 2);
    {
      union { ushort4 s; unsigned long long u; } cv; cv.s = hold;
      __hip_atomic_store((unsigned long long*)((char*)hsl + w * 2048 + myoff), cv.u,
                         __ATOMIC_RELAXED, __HIP_MEMORY_SCOPE_AGENT);
    }
    int arb[4];
#pragma unroll
    for (int rt = 0; rt < 4; ++rt) {
      int ar = rt * 16 + (lane & 15);
      arb[rt] = (ar * 32) ^ (((ar >> 2) & 7) << 4) ^ (((lane >> 4) & 1) << 4);
    }
    const int chunk_hi = lane >> 5;
    float (*gl)[64][16] = (float (*)[64][16])(smem + 65536);
    asm volatile("s_waitcnt vmcnt(0)" ::: "memory");
    __syncthreads();
    if (tid == 0)
      __hip_atomic_store(&ctrl[w * 16], 1, __ATOMIC_RELAXED, __HIP_MEMORY_SCOPE_AGENT);

    for (int t = 0; t < T_; ++t) {
      const size_t gxr = ((size_t)t * 64 + b) * (size_t)G4_ + hc;
      f32x4 xi = *(const f32x4*)&Gx[gxr + 0];
      f32x4 xf = *(const f32x4*)&Gx[gxr + 512];
      f32x4 xg = *(const f32x4*)&Gx[gxr + 1024];
      f32x4 xo = *(const f32x4*)&Gx[gxr + 1536];
      __builtin_amdgcn_sched_barrier(0);
      // wait until all 32 slices of h(t) are published (flag >= t+1); no fence needed
      if (tid < 64) {
        const int need = t + 1;
        for (;;) {
          int v = (lane < NPROD)
                      ? __hip_atomic_load(&ctrl[lane * 16], __ATOMIC_RELAXED, __HIP_MEMORY_SCOPE_AGENT)
                      : need;
          if (__all(v >= need)) break;
          __builtin_amdgcn_s_sleep(1);
        }
        if (tid == 0 && w == 0 && t > 0)
          __hip_atomic_store(&ctrl[512], t, __ATOMIC_RELAXED, __HIP_MEMORY_SCOPE_AGENT);
      }
      __syncthreads();
      // stage all 32 slices of h(t): coherent u64 loads -> LDS (linear; swizzle baked in data)
      {
        const char* src = (const char*)hsl + (t & 1) * 65536 + g * 16384 + lane * 8;
        char* dst = smem + g * 16384 + lane * 8;
        unsigned long long hv[32];
#pragma unroll
        for (int i = 0; i < 32; ++i)
          hv[i] = __hip_atomic_load((const unsigned long long*)(src + i * 512),
                                    __ATOMIC_RELAXED, __HIP_MEMORY_SCOPE_AGENT);
#pragma unroll
        for (int i = 0; i < 32; ++i)
          *(unsigned long long*)(dst + i * 512) = hv[i];
      }
      __syncthreads();
      f32x4 accp[4] = {};
#pragma unroll
      for (int kb = 0; kb < 16; ++kb) {
        const int cbase = (kb * 2 + chunk_hi) * 2048;
#pragma unroll
        for (int rt = 0; rt < 4; ++rt) {
          bf16x8 af = *(const bf16x8*)(smem + cbase + arb[rt]);
          accp[rt] = __builtin_amdgcn_mfma_f32_16x16x32_bf16(af, wf[kb], accp[rt], 0, 0, 0);
        }
      }
#pragma unroll
      for (int rt = 0; rt < 4; ++rt)
#pragma unroll
        for (int r = 0; r < 4; ++r)
          gl[g][rt * 16 + (lane >> 4) * 4 + r][lane & 15] = accp[rt][r];
      __syncthreads();
      f32x4 vi = xi + *(const f32x4*)&gl[0][b][hq];
      f32x4 vf = xf + *(const f32x4*)&gl[1][b][hq];
      f32x4 vg = xg + *(const f32x4*)&gl[2][b][hq];
      f32x4 vo = xo + *(const f32x4*)&gl[3][b][hq];
      f32x4 cn;
      ushort4 hb16;
      {
        float hv[4];
#pragma unroll
        for (int k = 0; k < 4; ++k) {
          float iv = sigf(vi[k]), fv = sigf(vf[k]), gv = tanhf(vg[k]), ov = sigf(vo[k]);
          cn[k] = fv * creg[k] + iv * gv;
          hv[k] = ov * tanhf(cn[k]);
        }
        hb16.x = f2bf(hv[0]); hb16.y = f2bf(hv[1]); hb16.z = f2bf(hv[2]); hb16.w = f2bf(hv[3]);
      }
      if (t < dl) {   // valid (t,b): write compact Hall row start[t]+b (coherent store)
        union { ushort4 s; unsigned long long u; } cv; cv.s = hb16;
        __hip_atomic_store((unsigned long long*)&Hall[((size_t)(meta[t] + b)) * H_ + hc],
                           cv.u, __ATOMIC_RELAXED, __HIP_MEMORY_SCOPE_AGENT);
        hold = hb16; creg = cn;
      }
      if (t + 1 < T_) {
        union { ushort4 s; unsigned long long u; } cv; cv.s = hold;
        __hip_atomic_store(
            (unsigned long long*)((char*)hsl + ((t + 1) & 1) * 65536 + w * 2048 + myoff),
            cv.u, __ATOMIC_RELAXED, __HIP_MEMORY_SCOPE_AGENT);
      }
      asm volatile("s_waitcnt vmcnt(0)" ::: "memory");  // hand-rolled release (stores at MALL)
      __syncthreads();
      if (tid == 0)
        __hip_atomic_store(&ctrl[w * 16], t + 2, __ATOMIC_RELAXED, __HIP_MEMORY_SCOPE_AGENT);
    }
    if (w == 0 && tid < 64) {
      const int need = T_ + 1;
      for (;;) {
        int v = (lane < NPROD)
                    ? __hip_atomic_load(&ctrl[lane * 16], __ATOMIC_RELAXED, __HIP_MEMORY_SCOPE_AGENT)
                    : need;
        if (__all(v >= need)) break;
        __builtin_amdgcn_s_sleep(1);
      }
      if (tid == 0)
        __hip_atomic_store(&ctrl[512], T_, __ATOMIC_RELAXED, __HIP_MEMORY_SCOPE_AGENT);
    }
    __builtin_amdgcn_s_setprio(0);
  }

  // ================= consumer: zero items + compact vocab-GEMM tiles =================
  const int NZI = meta[104];
  const int NTOT = meta[105];
  const int wid = tid >> 6;
  const int wr = wid >> 1, wc = wid & 1;
  for (;;) {
    __syncthreads();
    if (tid == 0)
      *s_tile = __hip_atomic_fetch_add(&ctrl[528], 1, __ATOMIC_RELAXED, __HIP_MEMORY_SCOPE_AGENT);
    __syncthreads();
    const int tile = *s_tile;
    if (tile >= NTOT) break;

    if (tile < NZI) {
      const int bt = zrowmap[tile];
      f32x4* dst = (f32x4*)(outp + (size_t)bt * V_);
      f32x4 z = {0.0f, 0.0f, 0.0f, 0.0f};
      for (int i = tid; i < V_ / 4; i += 256) dst[i] = z;
      continue;
    }

    const int gt = tile - NZI;
    const int mt = gt / NTN, nt = gt - mt * NTN;
    const int m0 = mt * 128, n0 = nt * 128;
    const int need = meta[110 + mt];
    if (tid == 0) {
      while (__hip_atomic_load(&ctrl[512], __ATOMIC_RELAXED, __HIP_MEMORY_SCOPE_AGENT) < need)
        __builtin_amdgcn_s_sleep(8);
    }
    __syncthreads();

    f32x4 acc[4][4] = {};
    auto stage = [&](int buf, int kit) {
      const int k0b = kit * 128;
#pragma unroll
      for (int i = 0; i < 4; ++i) {
        int chunk = wid * 4 + i;
        int d = chunk * 1024 + lane * 16;
        int row = d >> 7, colb = d & 127;
        int sc = colb ^ ((row & 7) << 4);
        async16((const char*)Hall + (size_t)(m0 + row) * 1024 + k0b + sc,
                smem + buf * 16384 + chunk * 1024);
        async16((const char*)WfcB + (size_t)(n0 + row) * 1024 + k0b + sc,
                smem + 32768 + buf * 16384 + chunk * 1024);
      }
    };
    stage(0, 0);
    __syncthreads();
    for (int kit = 0; kit < 8; ++kit) {
      const int buf = kit & 1;
      if (kit < 7) stage(buf ^ 1, kit + 1);
      const char* Ab = smem + buf * 16384;
      const char* Bb = smem + 32768 + buf * 16384;
#pragma unroll
      for (int kb = 0; kb < 2; ++kb) {
        const int colb = kb * 64 + (lane >> 4) * 16;
        bf16x8 af[4], bfb[4];
#pragma unroll
        for (int rt = 0; rt < 4; ++rt) {
          int ar = wr * 64 + rt * 16 + (lane & 15);
          af[rt] = *(const bf16x8*)(Ab + ar * 128 + (colb ^ ((ar & 7) << 4)));
          int br = wc * 64 + rt * 16 + (lane & 15);
          bfb[rt] = *(const bf16x8*)(Bb + br * 128 + (colb ^ ((br & 7) << 4)));
        }
#pragma unroll
        for (int i = 0; i < 4; ++i)
#pragma unroll
          for (int j = 0; j < 4; ++j)
            acc[i][j] = __builtin_amdgcn_mfma_f32_16x16x32_bf16(af[i], bfb[j], acc[i][j], 0, 0, 0);
      }
      __syncthreads();
    }
    // epilogue: transpose through LDS (swizzled), coalesced scatter via rowmap
    float* Ct = (float*)smem;
#pragma unroll
    for (int j = 0; j < 4; ++j) {
      const int colL = wc * 64 + j * 16 + (lane & 15);
      const float bz = bfc[n0 + colL];
#pragma unroll
      for (int i = 0; i < 4; ++i) {
        const int rb = wr * 64 + i * 16 + (lane >> 4) * 4;
#pragma unroll
        for (int r = 0; r < 4; ++r) {
          const int row = rb + r;
          Ct[row * 128 + (colL ^ ((row & 7) << 2))] = acc[i][j][r] + bz;
        }
      }
    }
    __syncthreads();
    const int c4 = tid & 31;
    const int rsub = tid >> 5;
#pragma unroll
    for (int itr = 0; itr < 16; ++itr) {
      const int row = itr * 8 + rsub;
      const int bt = rowmap[m0 + row];
      if (bt < 0) continue;
      f32x4 v = *(const f32x4*)&Ct[row * 128 + ((c4 ^ (row & 7)) << 2)];
      *(f32x4*)(outp + (size_t)bt * V_ + n0 + (c4 << 2)) = v;
    }
  }
}

// ---------------- launch ----------------
extern "C" void kernel_launch(void* const* d_in, const int* in_sizes, int n_in,
                              void* d_out, int out_size, void* d_ws, size_t ws_size,
                              hipStream_t stream) {
  const float* emb = (const float*)d_in[0];
  const float* enc = (const float*)d_in[1];
  const int*   cap = (const int*)d_in[2];
  const float* Wih = (const float*)d_in[3];
  const float* Whh = (const float*)d_in[4];
  const float* bih = (const float*)d_in[5];
  const float* bhh = (const float*)d_in[6];
  const float* Wh0 = (const float*)d_in[7];
  const float* bh0 = (const float*)d_in[8];
  const float* Wc0 = (const float*)d_in[9];
  const float* bc0 = (const float*)d_in[10];
  const float* Wfc = (const float*)d_in[11];
  const float* bfc = (const float*)d_in[12];
  float* out = (float*)d_out;

  char* ws = (char*)d_ws;
  size_t o = 0;
  auto carve = [&](size_t bytes) { void* p = ws + o; o += (bytes + 255) & ~(size_t)255; return p; };
  unsigned short* WihB = (unsigned short*)carve((size_t)G4_ * E_ * 2);
  unsigned short* WhhB = (unsigned short*)carve((size_t)G4_ * H_ * 2);
  unsigned short* WfcB = (unsigned short*)carve((size_t)V_ * H_ * 2);
  unsigned short* AxB  = (unsigned short*)carve((size_t)MPAD_ * E_ * 2);
  float*          Gx   = (float*)carve((size_t)MPAD_ * G4_ * 4);
  unsigned short* Hall = (unsigned short*)carve((size_t)MPAD_ * H_ * 2);
  unsigned short* h0b  = (unsigned short*)carve((size_t)B_ * H_ * 2);
  float*          cst  = (float*)carve((size_t)B_ * H_ * 4);
  unsigned short* hsl  = (unsigned short*)carve((size_t)2 * 65536);
  int*            ctrl = (int*)carve(4096);
  int*            meta = (int*)carve(1024);
  int*            rowmap = (int*)carve((size_t)MPAD_ * 4);
  int*            zrowmap = (int*)carve((size_t)MPAD_ * 4);
  (void)ws_size; (void)in_sizes; (void)n_in; (void)out_size;

  hipMemsetAsync(ctrl, 0, 4096, stream);
  convert_kernel<<<dim3(2048), dim3(256), 0, stream>>>(Wih, Whh, Wfc, emb, WihB, WhhB, WfcB, AxB);
  init_kernel<<<dim3(64, 4), dim3(256), 0, stream>>>(enc, cap, Wh0, bh0, Wc0, bc0, h0b, cst,
                                                     out + (size_t)B_ * T_ * V_,
                                                     meta, rowmap, zrowmap);
  pad_kernel<<<dim3(32), dim3(256), 0, stream>>>(meta, Hall);
  gemm_gx<<<dim3(G4_ / 128, MPAD_ / 128), dim3(256), 0, stream>>>(AxB, WihB, Gx, bih, bhh);
  fused_kernel<<<dim3(NWG), dim3(256), 0, stream>>>(Gx, WhhB, h0b, cst, hsl, Hall,
                                                    WfcB, bfc, cap, out, ctrl,
                                                    meta, rowmap, zrowmap);
}

// Round 7
// 400.537 us; speedup vs baseline: 2.4416x; 1.1678x over previous
//
#include <hip/hip_runtime.h>
#include <stdint.h>

#define B_    64
#define T_    49
#define E_    512
#define H_    512
#define ENC_  1024
#define V_    32000
#define G4_   2048        // 4*H
#define M_    3136        // T_*B_
#define MPAD_ 3200        // 25*128
#define NPROD 32
#define NWG   512
#define NTN   250         // 32000/128

typedef __attribute__((ext_vector_type(8))) short bf16x8;
typedef __attribute__((ext_vector_type(4))) float f32x4;

static __device__ __forceinline__ unsigned short f2bf(float f) {
  union { float f; uint32_t u; } v; v.f = f;
  uint32_t r = v.u + 0x7FFFu + ((v.u >> 16) & 1u);
  return (unsigned short)(r >> 16);
}

static __device__ __forceinline__ void async16(const void* g, void* lds) {
  __builtin_amdgcn_global_load_lds(
      (const __attribute__((address_space(1))) unsigned int*)g,
      (__attribute__((address_space(3))) unsigned int*)lds, 16, 0, 0);
}

static __device__ __forceinline__ float sigf(float x) { return 1.0f / (1.0f + expf(-x)); }

// ---------------- convert small weights to bf16 (+ embeddings transpose) ----------------
__global__ __launch_bounds__(256) void convert_kernel(
    const float* __restrict__ Wih, const float* __restrict__ Whh,
    const float* __restrict__ emb,
    unsigned short* __restrict__ WihB, unsigned short* __restrict__ WhhB,
    unsigned short* __restrict__ AxB) {
  const int n_wih = (G4_ * E_) / 4;
  const int n_whh = (G4_ * H_) / 4;
  const int n_emb = (B_ * T_ * E_) / 4;
  const int n_pad = ((MPAD_ - M_) * E_) / 4;
  const long total = (long)n_wih + n_whh + n_emb + n_pad;
  for (long u = (long)blockIdx.x * blockDim.x + threadIdx.x; u < total;
       u += (long)gridDim.x * blockDim.x) {
    long i = u;
    if (i < n_wih) {
      float4 v = ((const float4*)Wih)[i];
      ushort4 o; o.x = f2bf(v.x); o.y = f2bf(v.y); o.z = f2bf(v.z); o.w = f2bf(v.w);
      ((ushort4*)WihB)[i] = o; continue;
    }
    i -= n_wih;
    if (i < n_whh) {
      float4 v = ((const float4*)Whh)[i];
      ushort4 o; o.x = f2bf(v.x); o.y = f2bf(v.y); o.z = f2bf(v.z); o.w = f2bf(v.w);
      ((ushort4*)WhhB)[i] = o; continue;
    }
    i -= n_whh;
    if (i < n_emb) {
      int bt = (int)(i >> 7);
      int e4 = (int)(i & 127);
      int b = bt / T_, t = bt - b * T_;
      float4 v = ((const float4*)emb)[i];
      ushort4 o; o.x = f2bf(v.x); o.y = f2bf(v.y); o.z = f2bf(v.z); o.w = f2bf(v.w);
      ((ushort4*)AxB)[((long)(t * 64 + b) << 7) + e4] = o; continue;
    }
    i -= n_emb;
    ushort4 z; z.x = z.y = z.z = z.w = 0;
    ((ushort4*)AxB)[((long)M_ << 7) + i] = z;
  }
}

// ---------------- init: h0, c0, decode_lengths + compaction metadata ----------------
// meta[0..48]=start[t]; meta[100]=Mc; meta[101]=MT; meta[104]=NZI;
// meta[105]=NTOT (=NTN converts + NZI zeros + MT*NTN tiles); meta[110+mt]=need[mt]
__global__ __launch_bounds__(256) void init_kernel(
    const float* __restrict__ enc, const int* __restrict__ cap,
    const float* __restrict__ Wh, const float* __restrict__ bh,
    const float* __restrict__ Wc, const float* __restrict__ bc,
    unsigned short* __restrict__ h0b, float* __restrict__ c0,
    float* __restrict__ out_dl, int* __restrict__ meta,
    int* __restrict__ rowmap, int* __restrict__ zrowmap) {
  __shared__ __align__(16) float e[ENC_];
  __shared__ int s_nb[T_];
  __shared__ int s_start[T_ + 1];
  const int b = blockIdx.x, q = blockIdx.y, tid = threadIdx.x;
  ((float4*)e)[tid] = ((const float4*)(enc + (size_t)b * ENC_))[tid];
  __syncthreads();
  const bool is_c = tid >= 128;
  const int j = q * 128 + (tid & 127);
  const float* W = is_c ? Wc : Wh;
  float s = is_c ? bc[j] : bh[j];
  const float4* wr = (const float4*)(W + (size_t)j * ENC_);
  const float4* e4 = (const float4*)e;
#pragma unroll 4
  for (int k = 0; k < ENC_ / 4; ++k) {
    float4 w = wr[k], v = e4[k];
    s += w.x * v.x + w.y * v.y + w.z * v.z + w.w * v.w;
  }
  if (is_c) c0[(size_t)b * H_ + j] = s;
  else      h0b[(size_t)b * H_ + j] = f2bf(s);
  if (b == 0 && q == 0 && tid < B_) out_dl[tid] = (float)(cap[tid] - 1);

  if (b == 0 && q == 0) {
    __syncthreads();
    if (tid < T_) {
      int cnt = 0;
      for (int bb = 0; bb < B_; ++bb) cnt += (cap[bb] - 1 > tid) ? 1 : 0;
      s_nb[tid] = cnt;
    }
    __syncthreads();
    if (tid == 0) {
      int acc = 0;
      for (int t = 0; t < T_; ++t) { s_start[t] = acc; acc += s_nb[t]; }
      s_start[T_] = acc;
      const int Mc = acc;
      const int MT = (Mc + 127) >> 7;
      meta[100] = Mc;
      meta[101] = MT;
      meta[104] = M_ - Mc;                       // NZI
      meta[105] = NTN + (M_ - Mc) + MT * NTN;    // NTOT
      for (int i = Mc; i < MT * 128; ++i) rowmap[i] = -1;
    }
    __syncthreads();
    if (tid < T_) {
      meta[tid] = s_start[tid];
      const int st = s_start[tid], nb = s_nb[tid];
      for (int bb = 0; bb < nb; ++bb) rowmap[st + bb] = bb * T_ + tid;
      int zst = 0;
      for (int t2 = 0; t2 < tid; ++t2) zst += B_ - s_nb[t2];
      for (int bb = nb; bb < B_; ++bb) zrowmap[zst + (bb - nb)] = bb * T_ + tid;
    }
    __syncthreads();
    if (tid < 26) {
      const int Mc = s_start[T_];
      const int MT = (Mc + 127) >> 7;
      if (tid < MT) {
        int last = tid * 128 + 127;
        if (last > Mc - 1) last = Mc - 1;
        int tlast = 0;
        for (int t2 = 0; t2 < T_; ++t2) if (s_start[t2] <= last) tlast = t2;
        meta[110 + tid] = tlast + 1;
      }
    }
  }
}

// ---------------- zero the pad rows of compact Hall ----------------
__global__ __launch_bounds__(256) void pad_kernel(const int* __restrict__ meta,
                                                  unsigned short* __restrict__ Hall) {
  const int Mc = meta[100], MT = meta[101];
  const int tot = (MT * 128 - Mc) * 64;
  for (int i = blockIdx.x * blockDim.x + threadIdx.x; i < tot;
       i += gridDim.x * blockDim.x) {
    const int row = Mc + (i >> 6), c = i & 63;
    ushort4 z; z.x = z.y = z.z = z.w = 0;
    *(ushort4*)((char*)Hall + (size_t)row * 1024 + c * 16) = z;
  }
}

// ---------------- Gx GEMM: Gx = AxB @ WihB^T + bih + bhh (128x128 tile, K=512) ----------------
__global__ __launch_bounds__(256) void gemm_gx(
    const unsigned short* __restrict__ A, const unsigned short* __restrict__ Bm,
    float* __restrict__ C, const float* __restrict__ bias0, const float* __restrict__ bias1) {
  __shared__ __align__(16) char smem[65536];
  const int tid = threadIdx.x, lane = tid & 63, wid = tid >> 6;
  const int nt = blockIdx.x, mt = blockIdx.y;
  const int wr = wid >> 1, wc = wid & 1;
  const int m0 = mt * 128, n0 = nt * 128;
  f32x4 acc[4][4] = {};

  auto stage = [&](int buf, int kit) {
    const int k0b = kit * 128;
#pragma unroll
    for (int i = 0; i < 4; ++i) {
      int chunk = wid * 4 + i;
      int d = chunk * 1024 + lane * 16;
      int row = d >> 7, colb = d & 127;
      int sc = colb ^ ((row & 7) << 4);
      async16((const char*)A + (size_t)(m0 + row) * 1024 + k0b + sc,
              smem + buf * 16384 + chunk * 1024);
      async16((const char*)Bm + (size_t)(n0 + row) * 1024 + k0b + sc,
              smem + 32768 + buf * 16384 + chunk * 1024);
    }
  };

  stage(0, 0);
  __syncthreads();
  for (int kit = 0; kit < 8; ++kit) {
    const int buf = kit & 1;
    if (kit < 7) stage(buf ^ 1, kit + 1);
    const char* Ab = smem + buf * 16384;
    const char* Bb = smem + 32768 + buf * 16384;
#pragma unroll
    for (int kb = 0; kb < 2; ++kb) {
      const int colb = kb * 64 + (lane >> 4) * 16;
      bf16x8 af[4], bfb[4];
#pragma unroll
      for (int rt = 0; rt < 4; ++rt) {
        int ar = wr * 64 + rt * 16 + (lane & 15);
        af[rt] = *(const bf16x8*)(Ab + ar * 128 + (colb ^ ((ar & 7) << 4)));
        int br = wc * 64 + rt * 16 + (lane & 15);
        bfb[rt] = *(const bf16x8*)(Bb + br * 128 + (colb ^ ((br & 7) << 4)));
      }
#pragma unroll
      for (int i = 0; i < 4; ++i)
#pragma unroll
        for (int j = 0; j < 4; ++j)
          acc[i][j] = __builtin_amdgcn_mfma_f32_16x16x32_bf16(af[i], bfb[j], acc[i][j], 0, 0, 0);
    }
    __syncthreads();
  }
#pragma unroll
  for (int i = 0; i < 4; ++i) {
    const int rbase = m0 + wr * 64 + i * 16 + (lane >> 4) * 4;
#pragma unroll
    for (int j = 0; j < 4; ++j) {
      const int col = n0 + wc * 64 + j * 16 + (lane & 15);
#pragma unroll
      for (int r = 0; r < 4; ++r)
        C[(size_t)(rbase + r) * G4_ + col] = acc[i][j][r] + bias0[col] + bias1[col];
    }
  }
}

// ---------------- fused: persistent LSTM producers + {convert|zero|GEMM} consumers ----------------
// ctrl[w*16]=producer flag; ctrl[512]=prog; ctrl[528]=work counter; ctrl[544]=converts done.
// Cross-WG data via relaxed agent-scope atomics; release = vmcnt(0)+barrier+flag.
__global__ __launch_bounds__(256) void fused_kernel(
    const float* __restrict__ Gx, const unsigned short* __restrict__ WhhB,
    const unsigned short* __restrict__ h0b, const float* __restrict__ c0,
    unsigned short* __restrict__ hsl, unsigned short* __restrict__ Hall,
    const float* __restrict__ Wfc, unsigned short* __restrict__ WfcB,
    const float* __restrict__ bfc, const int* __restrict__ cap,
    float* __restrict__ outp, int* __restrict__ ctrl, const int* __restrict__ meta,
    const int* __restrict__ rowmap, const int* __restrict__ zrowmap) {
  __shared__ __align__(16) char smem[66560];   // 65KB -> 2 blocks/CU
  const int tid = threadIdx.x, lane = tid & 63, g = tid >> 6;
  int* s_tile = (int*)(smem + 66552);

  if (blockIdx.x < NPROD) {
    // ================= producer: one WG = 16 h-cols, all 49 steps =================
    __builtin_amdgcn_s_setprio(1);
    const int w = blockIdx.x, hc0 = w * 16;
    const int gcol = g * 512 + hc0 + (lane & 15);
    const int ko = (lane >> 4) * 8;
    bf16x8 wf[16];
#pragma unroll
    for (int kb = 0; kb < 16; ++kb)
      wf[kb] = *(const bf16x8*)&WhhB[(size_t)gcol * 512 + kb * 32 + ko];
    const int b = tid >> 2, hq = (tid & 3) * 4, hc = hc0 + hq;
    const int dl = cap[b] - 1;
    f32x4 creg = *(const f32x4*)&c0[b * H_ + hc];
    ushort4 hold = *(const ushort4*)&h0b[b * H_ + hc];
    const int myoff = ((b * 32) ^ (((b >> 2) & 7) << 4) ^ ((hq >> 3) << 4)) + ((hq & 7) * 2);
    {
      union { ushort4 s; unsigned long long u; } cv; cv.s = hold;
      __hip_atomic_store((unsigned long long*)((char*)hsl + w * 2048 + myoff), cv.u,
                         __ATOMIC_RELAXED, __HIP_MEMORY_SCOPE_AGENT);
    }
    int arb[4];
#pragma unroll
    for (int rt = 0; rt < 4; ++rt) {
      int ar = rt * 16 + (lane & 15);
      arb[rt] = (ar * 32) ^ (((ar >> 2) & 7) << 4) ^ (((lane >> 4) & 1) << 4);
    }
    const int chunk_hi = lane >> 5;
    float (*gl)[64][16] = (float (*)[64][16])smem;   // overlays Hs head (dead there)
    asm volatile("s_waitcnt vmcnt(0)" ::: "memory");
    __syncthreads();
    if (tid == 0)
      __hip_atomic_store(&ctrl[w * 16], 1, __ATOMIC_RELAXED, __HIP_MEMORY_SCOPE_AGENT);

    for (int t = 0; t < T_; ++t) {
      const size_t gxr = ((size_t)t * 64 + b) * (size_t)G4_ + hc;
      f32x4 xi = *(const f32x4*)&Gx[gxr + 0];
      f32x4 xf = *(const f32x4*)&Gx[gxr + 512];
      f32x4 xg = *(const f32x4*)&Gx[gxr + 1024];
      f32x4 xo = *(const f32x4*)&Gx[gxr + 1536];
      __builtin_amdgcn_sched_barrier(0);
      if (tid < 64) {
        const int need = t + 1;
        for (;;) {
          int v = (lane < NPROD)
                      ? __hip_atomic_load(&ctrl[lane * 16], __ATOMIC_RELAXED, __HIP_MEMORY_SCOPE_AGENT)
                      : need;
          if (__all(v >= need)) break;
          __builtin_amdgcn_s_sleep(1);
        }
        if (tid == 0 && w == 0 && t > 0)
          __hip_atomic_store(&ctrl[512], t, __ATOMIC_RELAXED, __HIP_MEMORY_SCOPE_AGENT);
      }
      __syncthreads();
      // stage all 32 slices of h(t): coherent u64 loads -> LDS
      {
        const char* src = (const char*)hsl + (t & 1) * 65536 + g * 16384 + lane * 8;
        char* dst = smem + g * 16384 + lane * 8;
        unsigned long long hv[32];
#pragma unroll
        for (int i = 0; i < 32; ++i)
          hv[i] = __hip_atomic_load((const unsigned long long*)(src + i * 512),
                                    __ATOMIC_RELAXED, __HIP_MEMORY_SCOPE_AGENT);
#pragma unroll
        for (int i = 0; i < 32; ++i)
          *(unsigned long long*)(dst + i * 512) = hv[i];
      }
      __syncthreads();
      f32x4 accp[4] = {};
#pragma unroll
      for (int kb = 0; kb < 16; ++kb) {
        const int cbase = (kb * 2 + chunk_hi) * 2048;
#pragma unroll
        for (int rt = 0; rt < 4; ++rt) {
          bf16x8 af = *(const bf16x8*)(smem + cbase + arb[rt]);
          accp[rt] = __builtin_amdgcn_mfma_f32_16x16x32_bf16(af, wf[kb], accp[rt], 0, 0, 0);
        }
      }
      __syncthreads();   // Hs reads done; gl may overlay Hs head
#pragma unroll
      for (int rt = 0; rt < 4; ++rt)
#pragma unroll
        for (int r = 0; r < 4; ++r)
          gl[g][rt * 16 + (lane >> 4) * 4 + r][lane & 15] = accp[rt][r];
      __syncthreads();
      f32x4 vi = xi + *(const f32x4*)&gl[0][b][hq];
      f32x4 vf = xf + *(const f32x4*)&gl[1][b][hq];
      f32x4 vg = xg + *(const f32x4*)&gl[2][b][hq];
      f32x4 vo = xo + *(const f32x4*)&gl[3][b][hq];
      f32x4 cn;
      ushort4 hb16;
      {
        float hv[4];
#pragma unroll
        for (int k = 0; k < 4; ++k) {
          float iv = sigf(vi[k]), fv = sigf(vf[k]), gv = tanhf(vg[k]), ov = sigf(vo[k]);
          cn[k] = fv * creg[k] + iv * gv;
          hv[k] = ov * tanhf(cn[k]);
        }
        hb16.x = f2bf(hv[0]); hb16.y = f2bf(hv[1]); hb16.z = f2bf(hv[2]); hb16.w = f2bf(hv[3]);
      }
      if (t < dl) {
        union { ushort4 s; unsigned long long u; } cv; cv.s = hb16;
        __hip_atomic_store((unsigned long long*)&Hall[((size_t)(meta[t] + b)) * H_ + hc],
                           cv.u, __ATOMIC_RELAXED, __HIP_MEMORY_SCOPE_AGENT);
        hold = hb16; creg = cn;
      }
      if (t + 1 < T_) {
        union { ushort4 s; unsigned long long u; } cv; cv.s = hold;
        __hip_atomic_store(
            (unsigned long long*)((char*)hsl + ((t + 1) & 1) * 65536 + w * 2048 + myoff),
            cv.u, __ATOMIC_RELAXED, __HIP_MEMORY_SCOPE_AGENT);
      }
      asm volatile("s_waitcnt vmcnt(0)" ::: "memory");  // hand-rolled release
      __syncthreads();
      if (tid == 0)
        __hip_atomic_store(&ctrl[w * 16], t + 2, __ATOMIC_RELAXED, __HIP_MEMORY_SCOPE_AGENT);
    }
    if (w == 0 && tid < 64) {
      const int need = T_ + 1;
      for (;;) {
        int v = (lane < NPROD)
                    ? __hip_atomic_load(&ctrl[lane * 16], __ATOMIC_RELAXED, __HIP_MEMORY_SCOPE_AGENT)
                    : need;
        if (__all(v >= need)) break;
        __builtin_amdgcn_s_sleep(1);
      }
      if (tid == 0)
        __hip_atomic_store(&ctrl[512], T_, __ATOMIC_RELAXED, __HIP_MEMORY_SCOPE_AGENT);
    }
    __builtin_amdgcn_s_setprio(0);
  }

  // ================= consumer: converts, zero rows, compact vocab-GEMM tiles =================
  const int NZI = meta[104];
  const int NTOT = meta[105];
  const int wid = tid >> 6;
  const int wr = wid >> 1, wc = wid & 1;
  for (;;) {
    __syncthreads();
    if (tid == 0)
      *s_tile = __hip_atomic_fetch_add(&ctrl[528], 1, __ATOMIC_RELAXED, __HIP_MEMORY_SCOPE_AGENT);
    __syncthreads();
    const int tile = *s_tile;
    if (tile >= NTOT) break;

    if (tile < NTN) {
      // convert item: Wfc rows [tile*128, tile*128+128) f32 -> bf16 (agent-scope stores)
      const float4* src = (const float4*)(Wfc + (size_t)tile * 128 * 512);
      unsigned long long* dst = (unsigned long long*)WfcB + (size_t)tile * 16384;
      for (int i = tid; i < 16384; i += 256) {
        float4 v = src[i];
        union { ushort4 s; unsigned long long u; } cv;
        cv.s.x = f2bf(v.x); cv.s.y = f2bf(v.y); cv.s.z = f2bf(v.z); cv.s.w = f2bf(v.w);
        __hip_atomic_store(&dst[i], cv.u, __ATOMIC_RELAXED, __HIP_MEMORY_SCOPE_AGENT);
      }
      asm volatile("s_waitcnt vmcnt(0)" ::: "memory");
      __syncthreads();
      if (tid == 0)
        __hip_atomic_fetch_add(&ctrl[544], 1, __ATOMIC_RELAXED, __HIP_MEMORY_SCOPE_AGENT);
      continue;
    }

    if (tile < NTN + NZI) {
      const int bt = zrowmap[tile - NTN];
      f32x4* dst = (f32x4*)(outp + (size_t)bt * V_);
      f32x4 z = {0.0f, 0.0f, 0.0f, 0.0f};
      for (int i = tid; i < V_ / 4; i += 256) dst[i] = z;
      continue;
    }

    const int gt = tile - NTN - NZI;
    const int mt = gt / NTN, nt = gt - mt * NTN;
    const int m0 = mt * 128, n0 = nt * 128;
    const int need = meta[110 + mt];
    if (tid == 0) {
      while (__hip_atomic_load(&ctrl[544], __ATOMIC_RELAXED, __HIP_MEMORY_SCOPE_AGENT) < NTN)
        __builtin_amdgcn_s_sleep(2);
      while (__hip_atomic_load(&ctrl[512], __ATOMIC_RELAXED, __HIP_MEMORY_SCOPE_AGENT) < need)
        __builtin_amdgcn_s_sleep(8);
    }
    __syncthreads();

    f32x4 acc[4][4] = {};
    auto stage = [&](int buf, int kit) {
      const int k0b = kit * 128;
#pragma unroll
      for (int i = 0; i < 4; ++i) {
        int chunk = wid * 4 + i;
        int d = chunk * 1024 + lane * 16;
        int row = d >> 7, colb = d & 127;
        int sc = colb ^ ((row & 7) << 4);
        async16((const char*)Hall + (size_t)(m0 + row) * 1024 + k0b + sc,
                smem + buf * 16384 + chunk * 1024);
        async16((const char*)WfcB + (size_t)(n0 + row) * 1024 + k0b + sc,
                smem + 32768 + buf * 16384 + chunk * 1024);
      }
    };
    stage(0, 0);
    __syncthreads();
    for (int kit = 0; kit < 8; ++kit) {
      const int buf = kit & 1;
      if (kit < 7) stage(buf ^ 1, kit + 1);
      const char* Ab = smem + buf * 16384;
      const char* Bb = smem + 32768 + buf * 16384;
#pragma unroll
      for (int kb = 0; kb < 2; ++kb) {
        const int colb = kb * 64 + (lane >> 4) * 16;
        bf16x8 af[4], bfb[4];
#pragma unroll
        for (int rt = 0; rt < 4; ++rt) {
          int ar = wr * 64 + rt * 16 + (lane & 15);
          af[rt] = *(const bf16x8*)(Ab + ar * 128 + (colb ^ ((ar & 7) << 4)));
          int br = wc * 64 + rt * 16 + (lane & 15);
          bfb[rt] = *(const bf16x8*)(Bb + br * 128 + (colb ^ ((br & 7) << 4)));
        }
#pragma unroll
        for (int i = 0; i < 4; ++i)
#pragma unroll
          for (int j = 0; j < 4; ++j)
            acc[i][j] = __builtin_amdgcn_mfma_f32_16x16x32_bf16(af[i], bfb[j], acc[i][j], 0, 0, 0);
      }
      __syncthreads();
    }
    float* Ct = (float*)smem;
#pragma unroll
    for (int j = 0; j < 4; ++j) {
      const int colL = wc * 64 + j * 16 + (lane & 15);
      const float bz = bfc[n0 + colL];
#pragma unroll
      for (int i = 0; i < 4; ++i) {
        const int rb = wr * 64 + i * 16 + (lane >> 4) * 4;
#pragma unroll
        for (int r = 0; r < 4; ++r) {
          const int row = rb + r;
          Ct[row * 128 + (colL ^ ((row & 7) << 2))] = acc[i][j][r] + bz;
        }
      }
    }
    __syncthreads();
    const int c4 = tid & 31;
    const int rsub = tid >> 5;
#pragma unroll
    for (int itr = 0; itr < 16; ++itr) {
      const int row = itr * 8 + rsub;
      const int bt = rowmap[m0 + row];
      if (bt < 0) continue;
      f32x4 v = *(const f32x4*)&Ct[row * 128 + ((c4 ^ (row & 7)) << 2)];
      *(f32x4*)(outp + (size_t)bt * V_ + n0 + (c4 << 2)) = v;
    }
  }
}

// ---------------- launch ----------------
extern "C" void kernel_launch(void* const* d_in, const int* in_sizes, int n_in,
                              void* d_out, int out_size, void* d_ws, size_t ws_size,
                              hipStream_t stream) {
  const float* emb = (const float*)d_in[0];
  const float* enc = (const float*)d_in[1];
  const int*   cap = (const int*)d_in[2];
  const float* Wih = (const float*)d_in[3];
  const float* Whh = (const float*)d_in[4];
  const float* bih = (const float*)d_in[5];
  const float* bhh = (const float*)d_in[6];
  const float* Wh0 = (const float*)d_in[7];
  const float* bh0 = (const float*)d_in[8];
  const float* Wc0 = (const float*)d_in[9];
  const float* bc0 = (const float*)d_in[10];
  const float* Wfc = (const float*)d_in[11];
  const float* bfc = (const float*)d_in[12];
  float* out = (float*)d_out;

  char* ws = (char*)d_ws;
  size_t o = 0;
  auto carve = [&](size_t bytes) { void* p = ws + o; o += (bytes + 255) & ~(size_t)255; return p; };
  unsigned short* WihB = (unsigned short*)carve((size_t)G4_ * E_ * 2);
  unsigned short* WhhB = (unsigned short*)carve((size_t)G4_ * H_ * 2);
  unsigned short* WfcB = (unsigned short*)carve((size_t)V_ * H_ * 2);
  unsigned short* AxB  = (unsigned short*)carve((size_t)MPAD_ * E_ * 2);
  float*          Gx   = (float*)carve((size_t)MPAD_ * G4_ * 4);
  unsigned short* Hall = (unsigned short*)carve((size_t)MPAD_ * H_ * 2);
  unsigned short* h0b  = (unsigned short*)carve((size_t)B_ * H_ * 2);
  float*          cst  = (float*)carve((size_t)B_ * H_ * 4);
  unsigned short* hsl  = (unsigned short*)carve((size_t)2 * 65536);
  int*            ctrl = (int*)carve(4096);
  int*            meta = (int*)carve(1024);
  int*            rowmap = (int*)carve((size_t)MPAD_ * 4);
  int*            zrowmap = (int*)carve((size_t)MPAD_ * 4);
  (void)ws_size; (void)in_sizes; (void)n_in; (void)out_size;

  hipMemsetAsync(ctrl, 0, 4096, stream);
  convert_kernel<<<dim3(1024), dim3(256), 0, stream>>>(Wih, Whh, emb, WihB, WhhB, AxB);
  init_kernel<<<dim3(64, 4), dim3(256), 0, stream>>>(enc, cap, Wh0, bh0, Wc0, bc0, h0b, cst,
                                                     out + (size_t)B_ * T_ * V_,
                                                     meta, rowmap, zrowmap);
  pad_kernel<<<dim3(32), dim3(256), 0, stream>>>(meta, Hall);
  gemm_gx<<<dim3(G4_ / 128, MPAD_ / 128), dim3(256), 0, stream>>>(AxB, WihB, Gx, bih, bhh);
  fused_kernel<<<dim3(NWG), dim3(256), 0, stream>>>(Gx, WhhB, h0b, cst, hsl, Hall,
                                                    Wfc, WfcB, bfc, cap, out, ctrl,
                                                    meta, rowmap, zrowmap);
}

// Round 8
// 399.193 us; speedup vs baseline: 2.4499x; 1.0034x over previous
//
#include <hip/hip_runtime.h>
#include <stdint.h>

#define B_    64
#define T_    49
#define E_    512
#define H_    512
#define ENC_  1024
#define V_    32000
#define G4_   2048        // 4*H
#define M_    3136        // T_*B_
#define MPAD_ 3200        // 25*128
#define NPROD 32
#define NWG   512
#define NTN   250         // 32000/128

typedef __attribute__((ext_vector_type(8))) short bf16x8;
typedef __attribute__((ext_vector_type(4))) float f32x4;

static __device__ __forceinline__ unsigned short f2bf(float f) {
  union { float f; uint32_t u; } v; v.f = f;
  uint32_t r = v.u + 0x7FFFu + ((v.u >> 16) & 1u);
  return (unsigned short)(r >> 16);
}

static __device__ __forceinline__ void async16(const void* g, void* lds) {
  __builtin_amdgcn_global_load_lds(
      (const __attribute__((address_space(1))) unsigned int*)g,
      (__attribute__((address_space(3))) unsigned int*)lds, 16, 0, 0);
}

static __device__ __forceinline__ float sigf(float x) { return 1.0f / (1.0f + expf(-x)); }

// ---------------- convert small weights to bf16 (+ embeddings transpose) ----------------
__global__ __launch_bounds__(256) void convert_kernel(
    const float* __restrict__ Wih, const float* __restrict__ Whh,
    const float* __restrict__ emb,
    unsigned short* __restrict__ WihB, unsigned short* __restrict__ WhhB,
    unsigned short* __restrict__ AxB) {
  const int n_wih = (G4_ * E_) / 4;
  const int n_whh = (G4_ * H_) / 4;
  const int n_emb = (B_ * T_ * E_) / 4;
  const int n_pad = ((MPAD_ - M_) * E_) / 4;
  const long total = (long)n_wih + n_whh + n_emb + n_pad;
  for (long u = (long)blockIdx.x * blockDim.x + threadIdx.x; u < total;
       u += (long)gridDim.x * blockDim.x) {
    long i = u;
    if (i < n_wih) {
      float4 v = ((const float4*)Wih)[i];
      ushort4 o; o.x = f2bf(v.x); o.y = f2bf(v.y); o.z = f2bf(v.z); o.w = f2bf(v.w);
      ((ushort4*)WihB)[i] = o; continue;
    }
    i -= n_wih;
    if (i < n_whh) {
      float4 v = ((const float4*)Whh)[i];
      ushort4 o; o.x = f2bf(v.x); o.y = f2bf(v.y); o.z = f2bf(v.z); o.w = f2bf(v.w);
      ((ushort4*)WhhB)[i] = o; continue;
    }
    i -= n_whh;
    if (i < n_emb) {
      int bt = (int)(i >> 7);
      int e4 = (int)(i & 127);
      int b = bt / T_, t = bt - b * T_;
      float4 v = ((const float4*)emb)[i];
      ushort4 o; o.x = f2bf(v.x); o.y = f2bf(v.y); o.z = f2bf(v.z); o.w = f2bf(v.w);
      ((ushort4*)AxB)[((long)(t * 64 + b) << 7) + e4] = o; continue;
    }
    i -= n_emb;
    ushort4 z; z.x = z.y = z.z = z.w = 0;
    ((ushort4*)AxB)[((long)M_ << 7) + i] = z;
  }
}

// ---------------- init: h0, c0, decode_lengths + compaction metadata ----------------
// meta[0..48]=start[t]; meta[100]=Mc; meta[101]=MT; meta[104]=NZI;
// meta[105]=NTOT (=NTN converts + NZI zeros + MT*NTN tiles); meta[110+mt]=need[mt]
__global__ __launch_bounds__(256) void init_kernel(
    const float* __restrict__ enc, const int* __restrict__ cap,
    const float* __restrict__ Wh, const float* __restrict__ bh,
    const float* __restrict__ Wc, const float* __restrict__ bc,
    unsigned short* __restrict__ h0b, float* __restrict__ c0,
    float* __restrict__ out_dl, int* __restrict__ meta,
    int* __restrict__ rowmap, int* __restrict__ zrowmap) {
  __shared__ __align__(16) float e[ENC_];
  __shared__ int s_nb[T_];
  __shared__ int s_start[T_ + 1];
  const int b = blockIdx.x, q = blockIdx.y, tid = threadIdx.x;
  ((float4*)e)[tid] = ((const float4*)(enc + (size_t)b * ENC_))[tid];
  __syncthreads();
  const bool is_c = tid >= 128;
  const int j = q * 128 + (tid & 127);
  const float* W = is_c ? Wc : Wh;
  float s = is_c ? bc[j] : bh[j];
  const float4* wr = (const float4*)(W + (size_t)j * ENC_);
  const float4* e4 = (const float4*)e;
#pragma unroll 4
  for (int k = 0; k < ENC_ / 4; ++k) {
    float4 w = wr[k], v = e4[k];
    s += w.x * v.x + w.y * v.y + w.z * v.z + w.w * v.w;
  }
  if (is_c) c0[(size_t)b * H_ + j] = s;
  else      h0b[(size_t)b * H_ + j] = f2bf(s);
  if (b == 0 && q == 0 && tid < B_) out_dl[tid] = (float)(cap[tid] - 1);

  if (b == 0 && q == 0) {
    __syncthreads();
    if (tid < T_) {
      int cnt = 0;
      for (int bb = 0; bb < B_; ++bb) cnt += (cap[bb] - 1 > tid) ? 1 : 0;
      s_nb[tid] = cnt;
    }
    __syncthreads();
    if (tid == 0) {
      int acc = 0;
      for (int t = 0; t < T_; ++t) { s_start[t] = acc; acc += s_nb[t]; }
      s_start[T_] = acc;
      const int Mc = acc;
      const int MT = (Mc + 127) >> 7;
      meta[100] = Mc;
      meta[101] = MT;
      meta[104] = M_ - Mc;                       // NZI
      meta[105] = NTN + (M_ - Mc) + MT * NTN;    // NTOT
      for (int i = Mc; i < MT * 128; ++i) rowmap[i] = -1;
    }
    __syncthreads();
    if (tid < T_) {
      meta[tid] = s_start[tid];
      const int st = s_start[tid], nb = s_nb[tid];
      for (int bb = 0; bb < nb; ++bb) rowmap[st + bb] = bb * T_ + tid;
      int zst = 0;
      for (int t2 = 0; t2 < tid; ++t2) zst += B_ - s_nb[t2];
      for (int bb = nb; bb < B_; ++bb) zrowmap[zst + (bb - nb)] = bb * T_ + tid;
    }
    __syncthreads();
    if (tid < 26) {
      const int Mc = s_start[T_];
      const int MT = (Mc + 127) >> 7;
      if (tid < MT) {
        int last = tid * 128 + 127;
        if (last > Mc - 1) last = Mc - 1;
        int tlast = 0;
        for (int t2 = 0; t2 < T_; ++t2) if (s_start[t2] <= last) tlast = t2;
        meta[110 + tid] = tlast + 1;
      }
    }
  }
}

// ---------------- zero the pad rows of compact Hall ----------------
__global__ __launch_bounds__(256) void pad_kernel(const int* __restrict__ meta,
                                                  unsigned short* __restrict__ Hall) {
  const int Mc = meta[100], MT = meta[101];
  const int tot = (MT * 128 - Mc) * 64;
  for (int i = blockIdx.x * blockDim.x + threadIdx.x; i < tot;
       i += gridDim.x * blockDim.x) {
    const int row = Mc + (i >> 6), c = i & 63;
    ushort4 z; z.x = z.y = z.z = z.w = 0;
    *(ushort4*)((char*)Hall + (size_t)row * 1024 + c * 16) = z;
  }
}

// ---------------- Gx GEMM: Gx = AxB @ WihB^T + bih + bhh (128x128 tile, K=512) ----------------
__global__ __launch_bounds__(256) void gemm_gx(
    const unsigned short* __restrict__ A, const unsigned short* __restrict__ Bm,
    float* __restrict__ C, const float* __restrict__ bias0, const float* __restrict__ bias1) {
  __shared__ __align__(16) char smem[65536];
  const int tid = threadIdx.x, lane = tid & 63, wid = tid >> 6;
  const int nt = blockIdx.x, mt = blockIdx.y;
  const int wr = wid >> 1, wc = wid & 1;
  const int m0 = mt * 128, n0 = nt * 128;
  f32x4 acc[4][4] = {};

  auto stage = [&](int buf, int kit) {
    const int k0b = kit * 128;
#pragma unroll
    for (int i = 0; i < 4; ++i) {
      int chunk = wid * 4 + i;
      int d = chunk * 1024 + lane * 16;
      int row = d >> 7, colb = d & 127;
      int sc = colb ^ ((row & 7) << 4);
      async16((const char*)A + (size_t)(m0 + row) * 1024 + k0b + sc,
              smem + buf * 16384 + chunk * 1024);
      async16((const char*)Bm + (size_t)(n0 + row) * 1024 + k0b + sc,
              smem + 32768 + buf * 16384 + chunk * 1024);
    }
  };

  stage(0, 0);
  __syncthreads();
  for (int kit = 0; kit < 8; ++kit) {
    const int buf = kit & 1;
    if (kit < 7) stage(buf ^ 1, kit + 1);
    const char* Ab = smem + buf * 16384;
    const char* Bb = smem + 32768 + buf * 16384;
#pragma unroll
    for (int kb = 0; kb < 2; ++kb) {
      const int colb = kb * 64 + (lane >> 4) * 16;
      bf16x8 af[4], bfb[4];
#pragma unroll
      for (int rt = 0; rt < 4; ++rt) {
        int ar = wr * 64 + rt * 16 + (lane & 15);
        af[rt] = *(const bf16x8*)(Ab + ar * 128 + (colb ^ ((ar & 7) << 4)));
        int br = wc * 64 + rt * 16 + (lane & 15);
        bfb[rt] = *(const bf16x8*)(Bb + br * 128 + (colb ^ ((br & 7) << 4)));
      }
#pragma unroll
      for (int i = 0; i < 4; ++i)
#pragma unroll
        for (int j = 0; j < 4; ++j)
          acc[i][j] = __builtin_amdgcn_mfma_f32_16x16x32_bf16(af[i], bfb[j], acc[i][j], 0, 0, 0);
    }
    __syncthreads();
  }
#pragma unroll
  for (int i = 0; i < 4; ++i) {
    const int rbase = m0 + wr * 64 + i * 16 + (lane >> 4) * 4;
#pragma unroll
    for (int j = 0; j < 4; ++j) {
      const int col = n0 + wc * 64 + j * 16 + (lane & 15);
#pragma unroll
      for (int r = 0; r < 4; ++r)
        C[(size_t)(rbase + r) * G4_ + col] = acc[i][j][r] + bias0[col] + bias1[col];
    }
  }
}

// ---------------- fused: persistent LSTM producers + {convert|zero|GEMM} consumers ----------------
// ctrl[w*16]=producer flag; ctrl[512]=prog; ctrl[528]=work counter; ctrl[544]=converts done.
// Cross-WG data via relaxed agent-scope atomics; release = vmcnt(0)+barrier+flag.
// LDS EXACTLY 64KB: >65536B rounds to a 128KB CP slot -> 1 block/CU (rounds 5-7 evidence).
__global__ __launch_bounds__(256) void fused_kernel(
    const float* __restrict__ Gx, const unsigned short* __restrict__ WhhB,
    const unsigned short* __restrict__ h0b, const float* __restrict__ c0,
    unsigned short* __restrict__ hsl, unsigned short* __restrict__ Hall,
    const float* __restrict__ Wfc, unsigned short* __restrict__ WfcB,
    const float* __restrict__ bfc, const int* __restrict__ cap,
    float* __restrict__ outp, int* __restrict__ ctrl, const int* __restrict__ meta,
    const int* __restrict__ rowmap, const int* __restrict__ zrowmap) {
  __shared__ __align__(16) char smem[65536];   // exactly 64KB -> 2 blocks/CU
  const int tid = threadIdx.x, lane = tid & 63, g = tid >> 6;
  int* s_tile = (int*)(smem + 65532);  // barrier-separated from all other uses

  if (blockIdx.x < NPROD) {
    // ================= producer: one WG = 16 h-cols, all 49 steps =================
    __builtin_amdgcn_s_setprio(1);
    const int w = blockIdx.x, hc0 = w * 16;
    const int gcol = g * 512 + hc0 + (lane & 15);
    const int ko = (lane >> 4) * 8;
    bf16x8 wf[16];
#pragma unroll
    for (int kb = 0; kb < 16; ++kb)
      wf[kb] = *(const bf16x8*)&WhhB[(size_t)gcol * 512 + kb * 32 + ko];
    const int b = tid >> 2, hq = (tid & 3) * 4, hc = hc0 + hq;
    const int dl = cap[b] - 1;
    f32x4 creg = *(const f32x4*)&c0[b * H_ + hc];
    ushort4 hold = *(const ushort4*)&h0b[b * H_ + hc];
    const int myoff = ((b * 32) ^ (((b >> 2) & 7) << 4) ^ ((hq >> 3) << 4)) + ((hq & 7) * 2);
    {
      union { ushort4 s; unsigned long long u; } cv; cv.s = hold;
      __hip_atomic_store((unsigned long long*)((char*)hsl + w * 2048 + myoff), cv.u,
                         __ATOMIC_RELAXED, __HIP_MEMORY_SCOPE_AGENT);
    }
    int arb[4];
#pragma unroll
    for (int rt = 0; rt < 4; ++rt) {
      int ar = rt * 16 + (lane & 15);
      arb[rt] = (ar * 32) ^ (((ar >> 2) & 7) << 4) ^ (((lane >> 4) & 1) << 4);
    }
    const int chunk_hi = lane >> 5;
    float (*gl)[64][16] = (float (*)[64][16])smem;   // overlays Hs head (dead there)
    asm volatile("s_waitcnt vmcnt(0)" ::: "memory");
    __syncthreads();
    if (tid == 0)
      __hip_atomic_store(&ctrl[w * 16], 1, __ATOMIC_RELAXED, __HIP_MEMORY_SCOPE_AGENT);

    for (int t = 0; t < T_; ++t) {
      const size_t gxr = ((size_t)t * 64 + b) * (size_t)G4_ + hc;
      f32x4 xi = *(const f32x4*)&Gx[gxr + 0];
      f32x4 xf = *(const f32x4*)&Gx[gxr + 512];
      f32x4 xg = *(const f32x4*)&Gx[gxr + 1024];
      f32x4 xo = *(const f32x4*)&Gx[gxr + 1536];
      __builtin_amdgcn_sched_barrier(0);
      if (tid < 64) {
        const int need = t + 1;
        for (;;) {
          int v = (lane < NPROD)
                      ? __hip_atomic_load(&ctrl[lane * 16], __ATOMIC_RELAXED, __HIP_MEMORY_SCOPE_AGENT)
                      : need;
          if (__all(v >= need)) break;
          __builtin_amdgcn_s_sleep(1);
        }
        if (tid == 0 && w == 0 && t > 0)
          __hip_atomic_store(&ctrl[512], t, __ATOMIC_RELAXED, __HIP_MEMORY_SCOPE_AGENT);
      }
      __syncthreads();
      // stage all 32 slices of h(t): coherent u64 loads -> LDS
      {
        const char* src = (const char*)hsl + (t & 1) * 65536 + g * 16384 + lane * 8;
        char* dst = smem + g * 16384 + lane * 8;
        unsigned long long hv[32];
#pragma unroll
        for (int i = 0; i < 32; ++i)
          hv[i] = __hip_atomic_load((const unsigned long long*)(src + i * 512),
                                    __ATOMIC_RELAXED, __HIP_MEMORY_SCOPE_AGENT);
#pragma unroll
        for (int i = 0; i < 32; ++i)
          *(unsigned long long*)(dst + i * 512) = hv[i];
      }
      __syncthreads();
      f32x4 accp[4] = {};
#pragma unroll
      for (int kb = 0; kb < 16; ++kb) {
        const int cbase = (kb * 2 + chunk_hi) * 2048;
#pragma unroll
        for (int rt = 0; rt < 4; ++rt) {
          bf16x8 af = *(const bf16x8*)(smem + cbase + arb[rt]);
          accp[rt] = __builtin_amdgcn_mfma_f32_16x16x32_bf16(af, wf[kb], accp[rt], 0, 0, 0);
        }
      }
      __syncthreads();   // Hs reads done; gl may overlay Hs head
#pragma unroll
      for (int rt = 0; rt < 4; ++rt)
#pragma unroll
        for (int r = 0; r < 4; ++r)
          gl[g][rt * 16 + (lane >> 4) * 4 + r][lane & 15] = accp[rt][r];
      __syncthreads();
      f32x4 vi = xi + *(const f32x4*)&gl[0][b][hq];
      f32x4 vf = xf + *(const f32x4*)&gl[1][b][hq];
      f32x4 vg = xg + *(const f32x4*)&gl[2][b][hq];
      f32x4 vo = xo + *(const f32x4*)&gl[3][b][hq];
      f32x4 cn;
      ushort4 hb16;
      {
        float hv[4];
#pragma unroll
        for (int k = 0; k < 4; ++k) {
          float iv = sigf(vi[k]), fv = sigf(vf[k]), gv = tanhf(vg[k]), ov = sigf(vo[k]);
          cn[k] = fv * creg[k] + iv * gv;
          hv[k] = ov * tanhf(cn[k]);
        }
        hb16.x = f2bf(hv[0]); hb16.y = f2bf(hv[1]); hb16.z = f2bf(hv[2]); hb16.w = f2bf(hv[3]);
      }
      if (t < dl) {
        union { ushort4 s; unsigned long long u; } cv; cv.s = hb16;
        __hip_atomic_store((unsigned long long*)&Hall[((size_t)(meta[t] + b)) * H_ + hc],
                           cv.u, __ATOMIC_RELAXED, __HIP_MEMORY_SCOPE_AGENT);
        hold = hb16; creg = cn;
      }
      if (t + 1 < T_) {
        union { ushort4 s; unsigned long long u; } cv; cv.s = hold;
        __hip_atomic_store(
            (unsigned long long*)((char*)hsl + ((t + 1) & 1) * 65536 + w * 2048 + myoff),
            cv.u, __ATOMIC_RELAXED, __HIP_MEMORY_SCOPE_AGENT);
      }
      asm volatile("s_waitcnt vmcnt(0)" ::: "memory");  // hand-rolled release
      __syncthreads();
      if (tid == 0)
        __hip_atomic_store(&ctrl[w * 16], t + 2, __ATOMIC_RELAXED, __HIP_MEMORY_SCOPE_AGENT);
    }
    if (w == 0 && tid < 64) {
      const int need = T_ + 1;
      for (;;) {
        int v = (lane < NPROD)
                    ? __hip_atomic_load(&ctrl[lane * 16], __ATOMIC_RELAXED, __HIP_MEMORY_SCOPE_AGENT)
                    : need;
        if (__all(v >= need)) break;
        __builtin_amdgcn_s_sleep(1);
      }
      if (tid == 0)
        __hip_atomic_store(&ctrl[512], T_, __ATOMIC_RELAXED, __HIP_MEMORY_SCOPE_AGENT);
    }
    __builtin_amdgcn_s_setprio(0);
  }

  // ================= consumer: converts, zero rows, compact vocab-GEMM tiles =================
  const int NZI = meta[104];
  const int NTOT = meta[105];
  const int wid = tid >> 6;
  const int wr = wid >> 1, wc = wid & 1;
  for (;;) {
    __syncthreads();
    if (tid == 0)
      *s_tile = __hip_atomic_fetch_add(&ctrl[528], 1, __ATOMIC_RELAXED, __HIP_MEMORY_SCOPE_AGENT);
    __syncthreads();
    const int tile = *s_tile;
    if (tile >= NTOT) break;

    if (tile < NTN) {
      // convert item: Wfc rows [tile*128, tile*128+128) f32 -> bf16 (agent-scope stores)
      const float4* src = (const float4*)(Wfc + (size_t)tile * 128 * 512);
      unsigned long long* dst = (unsigned long long*)WfcB + (size_t)tile * 16384;
      for (int i = tid; i < 16384; i += 256) {
        float4 v = src[i];
        union { ushort4 s; unsigned long long u; } cv;
        cv.s.x = f2bf(v.x); cv.s.y = f2bf(v.y); cv.s.z = f2bf(v.z); cv.s.w = f2bf(v.w);
        __hip_atomic_store(&dst[i], cv.u, __ATOMIC_RELAXED, __HIP_MEMORY_SCOPE_AGENT);
      }
      asm volatile("s_waitcnt vmcnt(0)" ::: "memory");
      __syncthreads();
      if (tid == 0)
        __hip_atomic_fetch_add(&ctrl[544], 1, __ATOMIC_RELAXED, __HIP_MEMORY_SCOPE_AGENT);
      continue;
    }

    if (tile < NTN + NZI) {
      const int bt = zrowmap[tile - NTN];
      f32x4* dst = (f32x4*)(outp + (size_t)bt * V_);
      f32x4 z = {0.0f, 0.0f, 0.0f, 0.0f};
      for (int i = tid; i < V_ / 4; i += 256) dst[i] = z;
      continue;
    }

    const int gt = tile - NTN - NZI;
    const int mt = gt / NTN, nt = gt - mt * NTN;
    const int m0 = mt * 128, n0 = nt * 128;
    const int need = meta[110 + mt];
    if (tid == 0) {
      while (__hip_atomic_load(&ctrl[544], __ATOMIC_RELAXED, __HIP_MEMORY_SCOPE_AGENT) < NTN)
        __builtin_amdgcn_s_sleep(2);
      while (__hip_atomic_load(&ctrl[512], __ATOMIC_RELAXED, __HIP_MEMORY_SCOPE_AGENT) < need)
        __builtin_amdgcn_s_sleep(8);
    }
    __syncthreads();

    f32x4 acc[4][4] = {};
    auto stage = [&](int buf, int kit) {
      const int k0b = kit * 128;
#pragma unroll
      for (int i = 0; i < 4; ++i) {
        int chunk = wid * 4 + i;
        int d = chunk * 1024 + lane * 16;
        int row = d >> 7, colb = d & 127;
        int sc = colb ^ ((row & 7) << 4);
        async16((const char*)Hall + (size_t)(m0 + row) * 1024 + k0b + sc,
                smem + buf * 16384 + chunk * 1024);
        async16((const char*)WfcB + (size_t)(n0 + row) * 1024 + k0b + sc,
                smem + 32768 + buf * 16384 + chunk * 1024);
      }
    };
    stage(0, 0);
    __syncthreads();
    for (int kit = 0; kit < 8; ++kit) {
      const int buf = kit & 1;
      if (kit < 7) stage(buf ^ 1, kit + 1);
      const char* Ab = smem + buf * 16384;
      const char* Bb = smem + 32768 + buf * 16384;
#pragma unroll
      for (int kb = 0; kb < 2; ++kb) {
        const int colb = kb * 64 + (lane >> 4) * 16;
        bf16x8 af[4], bfb[4];
#pragma unroll
        for (int rt = 0; rt < 4; ++rt) {
          int ar = wr * 64 + rt * 16 + (lane & 15);
          af[rt] = *(const bf16x8*)(Ab + ar * 128 + (colb ^ ((ar & 7) << 4)));
          int br = wc * 64 + rt * 16 + (lane & 15);
          bfb[rt] = *(const bf16x8*)(Bb + br * 128 + (colb ^ ((br & 7) << 4)));
        }
#pragma unroll
        for (int i = 0; i < 4; ++i)
#pragma unroll
          for (int j = 0; j < 4; ++j)
            acc[i][j] = __builtin_amdgcn_mfma_f32_16x16x32_bf16(af[i], bfb[j], acc[i][j], 0, 0, 0);
      }
      __syncthreads();
    }
    float* Ct = (float*)smem;
#pragma unroll
    for (int j = 0; j < 4; ++j) {
      const int colL = wc * 64 + j * 16 + (lane & 15);
      const float bz = bfc[n0 + colL];
#pragma unroll
      for (int i = 0; i < 4; ++i) {
        const int rb = wr * 64 + i * 16 + (lane >> 4) * 4;
#pragma unroll
        for (int r = 0; r < 4; ++r) {
          const int row = rb + r;
          Ct[row * 128 + (colL ^ ((row & 7) << 2))] = acc[i][j][r] + bz;
        }
      }
    }
    __syncthreads();
    const int c4 = tid & 31;
    const int rsub = tid >> 5;
#pragma unroll
    for (int itr = 0; itr < 16; ++itr) {
      const int row = itr * 8 + rsub;
      const int bt = rowmap[m0 + row];
      if (bt < 0) continue;
      f32x4 v = *(const f32x4*)&Ct[row * 128 + ((c4 ^ (row & 7)) << 2)];
      *(f32x4*)(outp + (size_t)bt * V_ + n0 + (c4 << 2)) = v;
    }
  }
}

// ---------------- launch ----------------
extern "C" void kernel_launch(void* const* d_in, const int* in_sizes, int n_in,
                              void* d_out, int out_size, void* d_ws, size_t ws_size,
                              hipStream_t stream) {
  const float* emb = (const float*)d_in[0];
  const float* enc = (const float*)d_in[1];
  const int*   cap = (const int*)d_in[2];
  const float* Wih = (const float*)d_in[3];
  const float* Whh = (const float*)d_in[4];
  const float* bih = (const float*)d_in[5];
  const float* bhh = (const float*)d_in[6];
  const float* Wh0 = (const float*)d_in[7];
  const float* bh0 = (const float*)d_in[8];
  const float* Wc0 = (const float*)d_in[9];
  const float* bc0 = (const float*)d_in[10];
  const float* Wfc = (const float*)d_in[11];
  const float* bfc = (const float*)d_in[12];
  float* out = (float*)d_out;

  char* ws = (char*)d_ws;
  size_t o = 0;
  auto carve = [&](size_t bytes) { void* p = ws + o; o += (bytes + 255) & ~(size_t)255; return p; };
  unsigned short* WihB = (unsigned short*)carve((size_t)G4_ * E_ * 2);
  unsigned short* WhhB = (unsigned short*)carve((size_t)G4_ * H_ * 2);
  unsigned short* WfcB = (unsigned short*)carve((size_t)V_ * H_ * 2);
  unsigned short* AxB  = (unsigned short*)carve((size_t)MPAD_ * E_ * 2);
  float*          Gx   = (float*)carve((size_t)MPAD_ * G4_ * 4);
  unsigned short* Hall = (unsigned short*)carve((size_t)MPAD_ * H_ * 2);
  unsigned short* h0b  = (unsigned short*)carve((size_t)B_ * H_ * 2);
  float*          cst  = (float*)carve((size_t)B_ * H_ * 4);
  unsigned short* hsl  = (unsigned short*)carve((size_t)2 * 65536);
  int*            ctrl = (int*)carve(4096);
  int*            meta = (int*)carve(1024);
  int*            rowmap = (int*)carve((size_t)MPAD_ * 4);
  int*            zrowmap = (int*)carve((size_t)MPAD_ * 4);
  (void)ws_size; (void)in_sizes; (void)n_in; (void)out_size;

  hipMemsetAsync(ctrl, 0, 4096, stream);
  convert_kernel<<<dim3(1024), dim3(256), 0, stream>>>(Wih, Whh, emb, WihB, WhhB, AxB);
  init_kernel<<<dim3(64, 4), dim3(256), 0, stream>>>(enc, cap, Wh0, bh0, Wc0, bc0, h0b, cst,
                                                     out + (size_t)B_ * T_ * V_,
                                                     meta, rowmap, zrowmap);
  pad_kernel<<<dim3(32), dim3(256), 0, stream>>>(meta, Hall);
  gemm_gx<<<dim3(G4_ / 128, MPAD_ / 128), dim3(256), 0, stream>>>(AxB, WihB, Gx, bih, bhh);
  fused_kernel<<<dim3(NWG), dim3(256), 0, stream>>>(Gx, WhhB, h0b, cst, hsl, Hall,
                                                    Wfc, WfcB, bfc, cap, out, ctrl,
                                                    meta, rowmap, zrowmap);
}

// Round 9
// 397.404 us; speedup vs baseline: 2.4609x; 1.0045x over previous
//
#include <hip/hip_runtime.h>
#include <stdint.h>

#define B_    64
#define T_    49
#define E_    512
#define H_    512
#define ENC_  1024
#define V_    32000
#define G4_   2048        // 4*H
#define M_    3136        // T_*B_
#define MPAD_ 3200        // 25*128
#define NPROD 32
#define NWG   512
#define NTN   250         // 32000/128

typedef __attribute__((ext_vector_type(8))) short bf16x8;
typedef __attribute__((ext_vector_type(4))) float f32x4;

static __device__ __forceinline__ unsigned short f2bf(float f) {
  union { float f; uint32_t u; } v; v.f = f;
  uint32_t r = v.u + 0x7FFFu + ((v.u >> 16) & 1u);
  return (unsigned short)(r >> 16);
}

static __device__ __forceinline__ void async16(const void* g, void* lds) {
  __builtin_amdgcn_global_load_lds(
      (const __attribute__((address_space(1))) unsigned int*)g,
      (__attribute__((address_space(3))) unsigned int*)lds, 16, 0, 0);
}

static __device__ __forceinline__ float sigf(float x) { return 1.0f / (1.0f + expf(-x)); }

// ---------------- convert small weights to bf16 (+ embeddings transpose) ----------------
__global__ __launch_bounds__(256) void convert_kernel(
    const float* __restrict__ Wih, const float* __restrict__ Whh,
    const float* __restrict__ emb,
    unsigned short* __restrict__ WihB, unsigned short* __restrict__ WhhB,
    unsigned short* __restrict__ AxB) {
  const int n_wih = (G4_ * E_) / 4;
  const int n_whh = (G4_ * H_) / 4;
  const int n_emb = (B_ * T_ * E_) / 4;
  const int n_pad = ((MPAD_ - M_) * E_) / 4;
  const long total = (long)n_wih + n_whh + n_emb + n_pad;
  for (long u = (long)blockIdx.x * blockDim.x + threadIdx.x; u < total;
       u += (long)gridDim.x * blockDim.x) {
    long i = u;
    if (i < n_wih) {
      float4 v = ((const float4*)Wih)[i];
      ushort4 o; o.x = f2bf(v.x); o.y = f2bf(v.y); o.z = f2bf(v.z); o.w = f2bf(v.w);
      ((ushort4*)WihB)[i] = o; continue;
    }
    i -= n_wih;
    if (i < n_whh) {
      float4 v = ((const float4*)Whh)[i];
      ushort4 o; o.x = f2bf(v.x); o.y = f2bf(v.y); o.z = f2bf(v.z); o.w = f2bf(v.w);
      ((ushort4*)WhhB)[i] = o; continue;
    }
    i -= n_whh;
    if (i < n_emb) {
      int bt = (int)(i >> 7);
      int e4 = (int)(i & 127);
      int b = bt / T_, t = bt - b * T_;
      float4 v = ((const float4*)emb)[i];
      ushort4 o; o.x = f2bf(v.x); o.y = f2bf(v.y); o.z = f2bf(v.z); o.w = f2bf(v.w);
      ((ushort4*)AxB)[((long)(t * 64 + b) << 7) + e4] = o; continue;
    }
    i -= n_emb;
    ushort4 z; z.x = z.y = z.z = z.w = 0;
    ((ushort4*)AxB)[((long)M_ << 7) + i] = z;
  }
}

// ---------------- init: h0, c0, decode_lengths + compaction metadata ----------------
// meta[0..48]=start[t]; meta[100]=Mc; meta[101]=MT; meta[104]=NZI;
// meta[105]=NTOT; meta[110+mt]=need[mt]
__global__ __launch_bounds__(256) void init_kernel(
    const float* __restrict__ enc, const int* __restrict__ cap,
    const float* __restrict__ Wh, const float* __restrict__ bh,
    const float* __restrict__ Wc, const float* __restrict__ bc,
    unsigned short* __restrict__ h0b, float* __restrict__ c0,
    float* __restrict__ out_dl, int* __restrict__ meta,
    int* __restrict__ rowmap, int* __restrict__ zrowmap) {
  __shared__ __align__(16) float e[ENC_];
  __shared__ int s_nb[T_];
  __shared__ int s_start[T_ + 1];
  const int b = blockIdx.x, q = blockIdx.y, tid = threadIdx.x;
  ((float4*)e)[tid] = ((const float4*)(enc + (size_t)b * ENC_))[tid];
  __syncthreads();
  const bool is_c = tid >= 128;
  const int j = q * 128 + (tid & 127);
  const float* W = is_c ? Wc : Wh;
  float s = is_c ? bc[j] : bh[j];
  const float4* wr = (const float4*)(W + (size_t)j * ENC_);
  const float4* e4 = (const float4*)e;
#pragma unroll 4
  for (int k = 0; k < ENC_ / 4; ++k) {
    float4 w = wr[k], v = e4[k];
    s += w.x * v.x + w.y * v.y + w.z * v.z + w.w * v.w;
  }
  if (is_c) c0[(size_t)b * H_ + j] = s;
  else      h0b[(size_t)b * H_ + j] = f2bf(s);
  if (b == 0 && q == 0 && tid < B_) out_dl[tid] = (float)(cap[tid] - 1);

  if (b == 0 && q == 0) {
    __syncthreads();
    if (tid < T_) {
      int cnt = 0;
      for (int bb = 0; bb < B_; ++bb) cnt += (cap[bb] - 1 > tid) ? 1 : 0;
      s_nb[tid] = cnt;
    }
    __syncthreads();
    if (tid == 0) {
      int acc = 0;
      for (int t = 0; t < T_; ++t) { s_start[t] = acc; acc += s_nb[t]; }
      s_start[T_] = acc;
      const int Mc = acc;
      const int MT = (Mc + 127) >> 7;
      meta[100] = Mc;
      meta[101] = MT;
      meta[104] = M_ - Mc;                       // NZI
      meta[105] = NTN + (M_ - Mc) + MT * NTN;    // NTOT
      for (int i = Mc; i < MT * 128; ++i) rowmap[i] = -1;
    }
    __syncthreads();
    if (tid < T_) {
      meta[tid] = s_start[tid];
      const int st = s_start[tid], nb = s_nb[tid];
      for (int bb = 0; bb < nb; ++bb) rowmap[st + bb] = bb * T_ + tid;
      int zst = 0;
      for (int t2 = 0; t2 < tid; ++t2) zst += B_ - s_nb[t2];
      for (int bb = nb; bb < B_; ++bb) zrowmap[zst + (bb - nb)] = bb * T_ + tid;
    }
    __syncthreads();
    if (tid < 26) {
      const int Mc = s_start[T_];
      const int MT = (Mc + 127) >> 7;
      if (tid < MT) {
        int last = tid * 128 + 127;
        if (last > Mc - 1) last = Mc - 1;
        int tlast = 0;
        for (int t2 = 0; t2 < T_; ++t2) if (s_start[t2] <= last) tlast = t2;
        meta[110 + tid] = tlast + 1;
      }
    }
  }
}

// ---------------- zero the pad rows of compact Hall ----------------
__global__ __launch_bounds__(256) void pad_kernel(const int* __restrict__ meta,
                                                  unsigned short* __restrict__ Hall) {
  const int Mc = meta[100], MT = meta[101];
  const int tot = (MT * 128 - Mc) * 64;
  for (int i = blockIdx.x * blockDim.x + threadIdx.x; i < tot;
       i += gridDim.x * blockDim.x) {
    const int row = Mc + (i >> 6), c = i & 63;
    ushort4 z; z.x = z.y = z.z = z.w = 0;
    *(ushort4*)((char*)Hall + (size_t)row * 1024 + c * 16) = z;
  }
}

// ---------------- Gx GEMM: Gx = AxB @ WihB^T + bih + bhh (128x128 tile, K=512) ----------------
__global__ __launch_bounds__(256) void gemm_gx(
    const unsigned short* __restrict__ A, const unsigned short* __restrict__ Bm,
    float* __restrict__ C, const float* __restrict__ bias0, const float* __restrict__ bias1) {
  __shared__ __align__(16) char smem[65536];
  const int tid = threadIdx.x, lane = tid & 63, wid = tid >> 6;
  const int nt = blockIdx.x, mt = blockIdx.y;
  const int wr = wid >> 1, wc = wid & 1;
  const int m0 = mt * 128, n0 = nt * 128;
  f32x4 acc[4][4] = {};

  auto stage = [&](int buf, int kit) {
    const int k0b = kit * 128;
#pragma unroll
    for (int i = 0; i < 4; ++i) {
      int chunk = wid * 4 + i;
      int d = chunk * 1024 + lane * 16;
      int row = d >> 7, colb = d & 127;
      int sc = colb ^ ((row & 7) << 4);
      async16((const char*)A + (size_t)(m0 + row) * 1024 + k0b + sc,
              smem + buf * 16384 + chunk * 1024);
      async16((const char*)Bm + (size_t)(n0 + row) * 1024 + k0b + sc,
              smem + 32768 + buf * 16384 + chunk * 1024);
    }
  };

  stage(0, 0);
  __syncthreads();
  for (int kit = 0; kit < 8; ++kit) {
    const int buf = kit & 1;
    if (kit < 7) stage(buf ^ 1, kit + 1);
    const char* Ab = smem + buf * 16384;
    const char* Bb = smem + 32768 + buf * 16384;
#pragma unroll
    for (int kb = 0; kb < 2; ++kb) {
      const int colb = kb * 64 + (lane >> 4) * 16;
      bf16x8 af[4], bfb[4];
#pragma unroll
      for (int rt = 0; rt < 4; ++rt) {
        int ar = wr * 64 + rt * 16 + (lane & 15);
        af[rt] = *(const bf16x8*)(Ab + ar * 128 + (colb ^ ((ar & 7) << 4)));
        int br = wc * 64 + rt * 16 + (lane & 15);
        bfb[rt] = *(const bf16x8*)(Bb + br * 128 + (colb ^ ((br & 7) << 4)));
      }
#pragma unroll
      for (int i = 0; i < 4; ++i)
#pragma unroll
        for (int j = 0; j < 4; ++j)
          acc[i][j] = __builtin_amdgcn_mfma_f32_16x16x32_bf16(af[i], bfb[j], acc[i][j], 0, 0, 0);
    }
    __syncthreads();
  }
#pragma unroll
  for (int i = 0; i < 4; ++i) {
    const int rbase = m0 + wr * 64 + i * 16 + (lane >> 4) * 4;
#pragma unroll
    for (int j = 0; j < 4; ++j) {
      const int col = n0 + wc * 64 + j * 16 + (lane & 15);
#pragma unroll
      for (int r = 0; r < 4; ++r)
        C[(size_t)(rbase + r) * G4_ + col] = acc[i][j][r] + bias0[col] + bias1[col];
    }
  }
}

// ---------------- fused: XCD-elected LSTM producers + {convert|zero|GEMM} consumers ----------------
// ctrl[w*16]=producer flag (agent); ctrl[512]=prog; ctrl[528]=work ctr; ctrl[544]=converts;
// ctrl[560]=elected XCD+1; ctrl[576]=producer-slot ctr; ctrl[592+x*16]=arrival ctr of XCD x.
// Producers all live on ONE XCD: h-slices move via plain stores (shared L2, vmcnt-drained
// BEFORE the agent flag) + sc0 (L1-bypass) loads. Flags/prog/Hall stay agent-scope (MALL).
__global__ __launch_bounds__(256) void fused_kernel(
    const float* __restrict__ Gx, const unsigned short* __restrict__ WhhB,
    const unsigned short* __restrict__ h0b, const float* __restrict__ c0,
    unsigned short* __restrict__ hsl, unsigned short* __restrict__ Hall,
    const float* __restrict__ Wfc, unsigned short* __restrict__ WfcB,
    const float* __restrict__ bfc, const int* __restrict__ cap,
    float* __restrict__ outp, int* __restrict__ ctrl, const int* __restrict__ meta,
    const int* __restrict__ rowmap, const int* __restrict__ zrowmap) {
  __shared__ __align__(16) char smem[65536];
  const int tid = threadIdx.x, lane = tid & 63, g = tid >> 6;
  int* s_tile = (int*)(smem + 65532);
  int* s_role = (int*)(smem + 65528);

  // ---- role election: first XCD to 32 arrivals owns the 32 producer slots ----
  {
    int xcc;
    asm volatile("s_getreg_b32 %0, hwreg(HW_REG_XCC_ID)" : "=s"(xcc));
    if (tid == 0) {
      xcc &= 7;
      int a = __hip_atomic_fetch_add(&ctrl[592 + xcc * 16], 1, __ATOMIC_RELAXED,
                                     __HIP_MEMORY_SCOPE_AGENT);
      if (a == NPROD - 1) {
        int expected = 0;
        __hip_atomic_compare_exchange_strong(&ctrl[560], &expected, xcc + 1,
                                             __ATOMIC_RELAXED, __ATOMIC_RELAXED,
                                             __HIP_MEMORY_SCOPE_AGENT);
      }
      int e;
      for (;;) {
        e = __hip_atomic_load(&ctrl[560], __ATOMIC_RELAXED, __HIP_MEMORY_SCOPE_AGENT);
        if (e) break;
        __builtin_amdgcn_s_sleep(2);
      }
      int slot = NPROD;
      if (e - 1 == xcc)
        slot = __hip_atomic_fetch_add(&ctrl[576], 1, __ATOMIC_RELAXED,
                                      __HIP_MEMORY_SCOPE_AGENT);
      *s_role = slot;
    }
    __syncthreads();
  }
  const int w = *s_role;
  __syncthreads();

  if (w < NPROD) {
    // ================= producer: one WG = 16 h-cols, all 49 steps =================
    __builtin_amdgcn_s_setprio(1);
    const int hc0 = w * 16;
    const int gcol = g * 512 + hc0 + (lane & 15);
    const int ko = (lane >> 4) * 8;
    bf16x8 wf[16];
#pragma unroll
    for (int kb = 0; kb < 16; ++kb)
      wf[kb] = *(const bf16x8*)&WhhB[(size_t)gcol * 512 + kb * 32 + ko];
    const int b = tid >> 2, hq = (tid & 3) * 4, hc = hc0 + hq;
    const int dl = cap[b] - 1;
    f32x4 creg = *(const f32x4*)&c0[b * H_ + hc];
    ushort4 hold = *(const ushort4*)&h0b[b * H_ + hc];
    const int myoff = ((b * 32) ^ (((b >> 2) & 7) << 4) ^ ((hq >> 3) << 4)) + ((hq & 7) * 2);
    {
      union { ushort4 s; unsigned long long u; } cv; cv.s = hold;
      *(unsigned long long*)((char*)hsl + w * 2048 + myoff) = cv.u;   // plain -> shared L2
    }
    int arb[4];
#pragma unroll
    for (int rt = 0; rt < 4; ++rt) {
      int ar = rt * 16 + (lane & 15);
      arb[rt] = (ar * 32) ^ (((ar >> 2) & 7) << 4) ^ (((lane >> 4) & 1) << 4);
    }
    const int chunk_hi = lane >> 5;
    float (*gl)[64][16] = (float (*)[64][16])smem;   // overlays Hs head (dead there)
    asm volatile("s_waitcnt vmcnt(0)" ::: "memory"); // slice in L2 before flag
    __syncthreads();
    if (tid == 0)
      __hip_atomic_store(&ctrl[w * 16], 1, __ATOMIC_RELAXED, __HIP_MEMORY_SCOPE_AGENT);

    for (int t = 0; t < T_; ++t) {
      const size_t gxr = ((size_t)t * 64 + b) * (size_t)G4_ + hc;
      f32x4 xi = *(const f32x4*)&Gx[gxr + 0];
      f32x4 xf = *(const f32x4*)&Gx[gxr + 512];
      f32x4 xg = *(const f32x4*)&Gx[gxr + 1024];
      f32x4 xo = *(const f32x4*)&Gx[gxr + 1536];
      __builtin_amdgcn_sched_barrier(0);
      if (tid < 64) {
        const int need = t + 1;
        for (;;) {
          int v = (lane < NPROD)
                      ? __hip_atomic_load(&ctrl[lane * 16], __ATOMIC_RELAXED, __HIP_MEMORY_SCOPE_AGENT)
                      : need;
          if (__all(v >= need)) break;
          __builtin_amdgcn_s_sleep(1);
        }
        if (tid == 0 && w == 0 && t > 0)
          __hip_atomic_store(&ctrl[512], t, __ATOMIC_RELAXED, __HIP_MEMORY_SCOPE_AGENT);
      }
      __syncthreads();
      // stage all 32 slices of h(t): sc0 (L1-bypass) 16B loads from shared L2 -> LDS
      {
        const char* src = (const char*)hsl + (t & 1) * 65536 + g * 16384 + lane * 16;
        char* dst = smem + g * 16384 + lane * 16;
        int4 hv[16];
#pragma unroll
        for (int i = 0; i < 16; ++i)
          asm volatile("global_load_dwordx4 %0, %1, off sc0"
                       : "=&v"(hv[i]) : "v"(src + i * 1024));
        asm volatile("s_waitcnt vmcnt(0)" ::: "memory");
#pragma unroll
        for (int i = 0; i < 16; ++i)
          *(int4*)(dst + i * 1024) = hv[i];
      }
      __syncthreads();
      f32x4 accp[4] = {};
#pragma unroll
      for (int kb = 0; kb < 16; ++kb) {
        const int cbase = (kb * 2 + chunk_hi) * 2048;
#pragma unroll
        for (int rt = 0; rt < 4; ++rt) {
          bf16x8 af = *(const bf16x8*)(smem + cbase + arb[rt]);
          accp[rt] = __builtin_amdgcn_mfma_f32_16x16x32_bf16(af, wf[kb], accp[rt], 0, 0, 0);
        }
      }
      __syncthreads();   // Hs reads done; gl may overlay Hs head
#pragma unroll
      for (int rt = 0; rt < 4; ++rt)
#pragma unroll
        for (int r = 0; r < 4; ++r)
          gl[g][rt * 16 + (lane >> 4) * 4 + r][lane & 15] = accp[rt][r];
      __syncthreads();
      f32x4 vi = xi + *(const f32x4*)&gl[0][b][hq];
      f32x4 vf = xf + *(const f32x4*)&gl[1][b][hq];
      f32x4 vg = xg + *(const f32x4*)&gl[2][b][hq];
      f32x4 vo = xo + *(const f32x4*)&gl[3][b][hq];
      f32x4 cn;
      ushort4 hb16;
      {
        float hv4[4];
#pragma unroll
        for (int k = 0; k < 4; ++k) {
          float iv = sigf(vi[k]), fv = sigf(vf[k]), gv = tanhf(vg[k]), ov = sigf(vo[k]);
          cn[k] = fv * creg[k] + iv * gv;
          hv4[k] = ov * tanhf(cn[k]);
        }
        hb16.x = f2bf(hv4[0]); hb16.y = f2bf(hv4[1]); hb16.z = f2bf(hv4[2]); hb16.w = f2bf(hv4[3]);
      }
      if (t < dl) {   // Hall read cross-XCD: keep agent-scope (MALL)
        union { ushort4 s; unsigned long long u; } cv; cv.s = hb16;
        __hip_atomic_store((unsigned long long*)&Hall[((size_t)(meta[t] + b)) * H_ + hc],
                           cv.u, __ATOMIC_RELAXED, __HIP_MEMORY_SCOPE_AGENT);
        hold = hb16; creg = cn;
      }
      if (t + 1 < T_) {   // slice exchange intra-XCD: plain store -> shared L2
        union { ushort4 s; unsigned long long u; } cv; cv.s = hold;
        *(unsigned long long*)((char*)hsl + ((t + 1) & 1) * 65536 + w * 2048 + myoff) = cv.u;
      }
      asm volatile("s_waitcnt vmcnt(0)" ::: "memory");  // drain data before flag
      __syncthreads();
      if (tid == 0)
        __hip_atomic_store(&ctrl[w * 16], t + 2, __ATOMIC_RELAXED, __HIP_MEMORY_SCOPE_AGENT);
    }
    if (w == 0 && tid < 64) {
      const int need = T_ + 1;
      for (;;) {
        int v = (lane < NPROD)
                    ? __hip_atomic_load(&ctrl[lane * 16], __ATOMIC_RELAXED, __HIP_MEMORY_SCOPE_AGENT)
                    : need;
        if (__all(v >= need)) break;
        __builtin_amdgcn_s_sleep(1);
      }
      if (tid == 0)
        __hip_atomic_store(&ctrl[512], T_, __ATOMIC_RELAXED, __HIP_MEMORY_SCOPE_AGENT);
    }
    __builtin_amdgcn_s_setprio(0);
  }

  // ================= consumer: converts, zero rows, compact vocab-GEMM tiles =================
  const int NZI = meta[104];
  const int NTOT = meta[105];
  const int wid = tid >> 6;
  const int wr = wid >> 1, wc = wid & 1;
  for (;;) {
    __syncthreads();
    if (tid == 0)
      *s_tile = __hip_atomic_fetch_add(&ctrl[528], 1, __ATOMIC_RELAXED, __HIP_MEMORY_SCOPE_AGENT);
    __syncthreads();
    const int tile = *s_tile;
    __syncthreads();   // s_tile lives inside the staging region: read before any LDS write
    if (tile >= NTOT) break;

    if (tile < NTN) {
      // convert item: Wfc rows [tile*128, tile*128+128) f32 -> bf16 (agent-scope stores)
      const float4* src = (const float4*)(Wfc + (size_t)tile * 128 * 512);
      unsigned long long* dst = (unsigned long long*)WfcB + (size_t)tile * 16384;
      for (int i = tid; i < 16384; i += 256) {
        float4 v = src[i];
        union { ushort4 s; unsigned long long u; } cv;
        cv.s.x = f2bf(v.x); cv.s.y = f2bf(v.y); cv.s.z = f2bf(v.z); cv.s.w = f2bf(v.w);
        __hip_atomic_store(&dst[i], cv.u, __ATOMIC_RELAXED, __HIP_MEMORY_SCOPE_AGENT);
      }
      asm volatile("s_waitcnt vmcnt(0)" ::: "memory");
      __syncthreads();
      if (tid == 0)
        __hip_atomic_fetch_add(&ctrl[544], 1, __ATOMIC_RELAXED, __HIP_MEMORY_SCOPE_AGENT);
      continue;
    }

    if (tile < NTN + NZI) {
      const int bt = zrowmap[tile - NTN];
      f32x4* dst = (f32x4*)(outp + (size_t)bt * V_);
      f32x4 z = {0.0f, 0.0f, 0.0f, 0.0f};
      for (int i = tid; i < V_ / 4; i += 256) dst[i] = z;
      continue;
    }

    const int gt = tile - NTN - NZI;
    const int mt = gt / NTN, nt = gt - mt * NTN;
    const int m0 = mt * 128, n0 = nt * 128;
    const int need = meta[110 + mt];
    if (tid == 0) {
      while (__hip_atomic_load(&ctrl[544], __ATOMIC_RELAXED, __HIP_MEMORY_SCOPE_AGENT) < NTN)
        __builtin_amdgcn_s_sleep(2);
      while (__hip_atomic_load(&ctrl[512], __ATOMIC_RELAXED, __HIP_MEMORY_SCOPE_AGENT) < need)
        __builtin_amdgcn_s_sleep(8);
    }
    __syncthreads();

    f32x4 acc[4][4] = {};
    auto stage = [&](int buf, int kit) {
      const int k0b = kit * 128;
#pragma unroll
      for (int i = 0; i < 4; ++i) {
        int chunk = wid * 4 + i;
        int d = chunk * 1024 + lane * 16;
        int row = d >> 7, colb = d & 127;
        int sc = colb ^ ((row & 7) << 4);
        async16((const char*)Hall + (size_t)(m0 + row) * 1024 + k0b + sc,
                smem + buf * 16384 + chunk * 1024);
        async16((const char*)WfcB + (size_t)(n0 + row) * 1024 + k0b + sc,
                smem + 32768 + buf * 16384 + chunk * 1024);
      }
    };
    stage(0, 0);
    __syncthreads();
    for (int kit = 0; kit < 8; ++kit) {
      const int buf = kit & 1;
      if (kit < 7) stage(buf ^ 1, kit + 1);
      const char* Ab = smem + buf * 16384;
      const char* Bb = smem + 32768 + buf * 16384;
#pragma unroll
      for (int kb = 0; kb < 2; ++kb) {
        const int colb = kb * 64 + (lane >> 4) * 16;
        bf16x8 af[4], bfb[4];
#pragma unroll
        for (int rt = 0; rt < 4; ++rt) {
          int ar = wr * 64 + rt * 16 + (lane & 15);
          af[rt] = *(const bf16x8*)(Ab + ar * 128 + (colb ^ ((ar & 7) << 4)));
          int br = wc * 64 + rt * 16 + (lane & 15);
          bfb[rt] = *(const bf16x8*)(Bb + br * 128 + (colb ^ ((br & 7) << 4)));
        }
#pragma unroll
        for (int i = 0; i < 4; ++i)
#pragma unroll
          for (int j = 0; j < 4; ++j)
            acc[i][j] = __builtin_amdgcn_mfma_f32_16x16x32_bf16(af[i], bfb[j], acc[i][j], 0, 0, 0);
      }
      __syncthreads();
    }
    float* Ct = (float*)smem;
#pragma unroll
    for (int j = 0; j < 4; ++j) {
      const int colL = wc * 64 + j * 16 + (lane & 15);
      const float bz = bfc[n0 + colL];
#pragma unroll
      for (int i = 0; i < 4; ++i) {
        const int rb = wr * 64 + i * 16 + (lane >> 4) * 4;
#pragma unroll
        for (int r = 0; r < 4; ++r) {
          const int row = rb + r;
          Ct[row * 128 + (colL ^ ((row & 7) << 2))] = acc[i][j][r] + bz;
        }
      }
    }
    __syncthreads();
    const int c4 = tid & 31;
    const int rsub = tid >> 5;
#pragma unroll
    for (int itr = 0; itr < 16; ++itr) {
      const int row = itr * 8 + rsub;
      const int bt = rowmap[m0 + row];
      if (bt < 0) continue;
      f32x4 v = *(const f32x4*)&Ct[row * 128 + ((c4 ^ (row & 7)) << 2)];
      *(f32x4*)(outp + (size_t)bt * V_ + n0 + (c4 << 2)) = v;
    }
  }
}

// ---------------- launch ----------------
extern "C" void kernel_launch(void* const* d_in, const int* in_sizes, int n_in,
                              void* d_out, int out_size, void* d_ws, size_t ws_size,
                              hipStream_t stream) {
  const float* emb = (const float*)d_in[0];
  const float* enc = (const float*)d_in[1];
  const int*   cap = (const int*)d_in[2];
  const float* Wih = (const float*)d_in[3];
  const float* Whh = (const float*)d_in[4];
  const float* bih = (const float*)d_in[5];
  const float* bhh = (const float*)d_in[6];
  const float* Wh0 = (const float*)d_in[7];
  const float* bh0 = (const float*)d_in[8];
  const float* Wc0 = (const float*)d_in[9];
  const float* bc0 = (const float*)d_in[10];
  const float* Wfc = (const float*)d_in[11];
  const float* bfc = (const float*)d_in[12];
  float* out = (float*)d_out;

  char* ws = (char*)d_ws;
  size_t o = 0;
  auto carve = [&](size_t bytes) { void* p = ws + o; o += (bytes + 255) & ~(size_t)255; return p; };
  unsigned short* WihB = (unsigned short*)carve((size_t)G4_ * E_ * 2);
  unsigned short* WhhB = (unsigned short*)carve((size_t)G4_ * H_ * 2);
  unsigned short* WfcB = (unsigned short*)carve((size_t)V_ * H_ * 2);
  unsigned short* AxB  = (unsigned short*)carve((size_t)MPAD_ * E_ * 2);
  float*          Gx   = (float*)carve((size_t)MPAD_ * G4_ * 4);
  unsigned short* Hall = (unsigned short*)carve((size_t)MPAD_ * H_ * 2);
  unsigned short* h0b  = (unsigned short*)carve((size_t)B_ * H_ * 2);
  float*          cst  = (float*)carve((size_t)B_ * H_ * 4);
  unsigned short* hsl  = (unsigned short*)carve((size_t)2 * 65536);
  int*            ctrl = (int*)carve(4096);
  int*            meta = (int*)carve(1024);
  int*            rowmap = (int*)carve((size_t)MPAD_ * 4);
  int*            zrowmap = (int*)carve((size_t)MPAD_ * 4);
  (void)ws_size; (void)in_sizes; (void)n_in; (void)out_size;

  hipMemsetAsync(ctrl, 0, 4096, stream);
  convert_kernel<<<dim3(1024), dim3(256), 0, stream>>>(Wih, Whh, emb, WihB, WhhB, AxB);
  init_kernel<<<dim3(64, 4), dim3(256), 0, stream>>>(enc, cap, Wh0, bh0, Wc0, bc0, h0b, cst,
                                                     out + (size_t)B_ * T_ * V_,
                                                     meta, rowmap, zrowmap);
  pad_kernel<<<dim3(32), dim3(256), 0, stream>>>(meta, Hall);
  gemm_gx<<<dim3(G4_ / 128, MPAD_ / 128), dim3(256), 0, stream>>>(AxB, WihB, Gx, bih, bhh);
  fused_kernel<<<dim3(NWG), dim3(256), 0, stream>>>(Gx, WhhB, h0b, cst, hsl, Hall,
                                                    Wfc, WfcB, bfc, cap, out, ctrl,
                                                    meta, rowmap, zrowmap);
}

// Round 11
// 387.364 us; speedup vs baseline: 2.5247x; 1.0259x over previous
//
#include <hip/hip_runtime.h>
#include <stdint.h>

#define B_    64
#define T_    49
#define E_    512
#define H_    512
#define ENC_  1024
#define V_    32000
#define G4_   2048        // 4*H
#define M_    3136        // T_*B_
#define MPAD_ 3200        // 25*128
#define NPROD 32
#define NWG   256
#define NTN   250         // 32000/128

typedef __attribute__((ext_vector_type(8))) short bf16x8;
typedef __attribute__((ext_vector_type(4))) float f32x4;

static __device__ __forceinline__ unsigned short f2bf(float f) {
  union { float f; uint32_t u; } v; v.f = f;
  uint32_t r = v.u + 0x7FFFu + ((v.u >> 16) & 1u);
  return (unsigned short)(r >> 16);
}

static __device__ __forceinline__ void async16(const void* g, void* lds) {
  __builtin_amdgcn_global_load_lds(
      (const __attribute__((address_space(1))) unsigned int*)g,
      (__attribute__((address_space(3))) unsigned int*)lds, 16, 0, 0);
}

static __device__ __forceinline__ float sigf(float x) { return 1.0f / (1.0f + expf(-x)); }

// ---------------- convert small weights to bf16 (+ embeddings transpose) ----------------
__global__ __launch_bounds__(256) void convert_kernel(
    const float* __restrict__ Wih, const float* __restrict__ Whh,
    const float* __restrict__ emb,
    unsigned short* __restrict__ WihB, unsigned short* __restrict__ WhhB,
    unsigned short* __restrict__ AxB) {
  const int n_wih = (G4_ * E_) / 4;
  const int n_whh = (G4_ * H_) / 4;
  const int n_emb = (B_ * T_ * E_) / 4;
  const int n_pad = ((MPAD_ - M_) * E_) / 4;
  const long total = (long)n_wih + n_whh + n_emb + n_pad;
  for (long u = (long)blockIdx.x * blockDim.x + threadIdx.x; u < total;
       u += (long)gridDim.x * blockDim.x) {
    long i = u;
    if (i < n_wih) {
      float4 v = ((const float4*)Wih)[i];
      ushort4 o; o.x = f2bf(v.x); o.y = f2bf(v.y); o.z = f2bf(v.z); o.w = f2bf(v.w);
      ((ushort4*)WihB)[i] = o; continue;
    }
    i -= n_wih;
    if (i < n_whh) {
      float4 v = ((const float4*)Whh)[i];
      ushort4 o; o.x = f2bf(v.x); o.y = f2bf(v.y); o.z = f2bf(v.z); o.w = f2bf(v.w);
      ((ushort4*)WhhB)[i] = o; continue;
    }
    i -= n_whh;
    if (i < n_emb) {
      int bt = (int)(i >> 7);
      int e4 = (int)(i & 127);
      int b = bt / T_, t = bt - b * T_;
      float4 v = ((const float4*)emb)[i];
      ushort4 o; o.x = f2bf(v.x); o.y = f2bf(v.y); o.z = f2bf(v.z); o.w = f2bf(v.w);
      ((ushort4*)AxB)[((long)(t * 64 + b) << 7) + e4] = o; continue;
    }
    i -= n_emb;
    ushort4 z; z.x = z.y = z.z = z.w = 0;
    ((ushort4*)AxB)[((long)M_ << 7) + i] = z;
  }
}

// ---------------- init: h0, c0, decode_lengths + compaction metadata ----------------
// meta[0..48]=start[t]; meta[100]=Mc; meta[101]=MT; meta[104]=NZI;
// meta[105]=NTOT; meta[110+mt]=need[mt]
__global__ __launch_bounds__(256) void init_kernel(
    const float* __restrict__ enc, const int* __restrict__ cap,
    const float* __restrict__ Wh, const float* __restrict__ bh,
    const float* __restrict__ Wc, const float* __restrict__ bc,
    unsigned short* __restrict__ h0b, float* __restrict__ c0,
    float* __restrict__ out_dl, int* __restrict__ meta,
    int* __restrict__ rowmap, int* __restrict__ zrowmap) {
  __shared__ __align__(16) float e[ENC_];
  __shared__ int s_nb[T_];
  __shared__ int s_start[T_ + 1];
  const int b = blockIdx.x, q = blockIdx.y, tid = threadIdx.x;
  ((float4*)e)[tid] = ((const float4*)(enc + (size_t)b * ENC_))[tid];
  __syncthreads();
  const bool is_c = tid >= 128;
  const int j = q * 128 + (tid & 127);
  const float* W = is_c ? Wc : Wh;
  float s = is_c ? bc[j] : bh[j];
  const float4* wr = (const float4*)(W + (size_t)j * ENC_);
  const float4* e4 = (const float4*)e;
#pragma unroll 4
  for (int k = 0; k < ENC_ / 4; ++k) {
    float4 w = wr[k], v = e4[k];
    s += w.x * v.x + w.y * v.y + w.z * v.z + w.w * v.w;
  }
  if (is_c) c0[(size_t)b * H_ + j] = s;
  else      h0b[(size_t)b * H_ + j] = f2bf(s);
  if (b == 0 && q == 0 && tid < B_) out_dl[tid] = (float)(cap[tid] - 1);

  if (b == 0 && q == 0) {
    __syncthreads();
    if (tid < T_) {
      int cnt = 0;
      for (int bb = 0; bb < B_; ++bb) cnt += (cap[bb] - 1 > tid) ? 1 : 0;
      s_nb[tid] = cnt;
    }
    __syncthreads();
    if (tid == 0) {
      int acc = 0;
      for (int t = 0; t < T_; ++t) { s_start[t] = acc; acc += s_nb[t]; }
      s_start[T_] = acc;
      const int Mc = acc;
      const int MT = (Mc + 127) >> 7;
      meta[100] = Mc;
      meta[101] = MT;
      meta[104] = M_ - Mc;                       // NZI
      meta[105] = NTN + (M_ - Mc) + MT * NTN;    // NTOT
      for (int i = Mc; i < MT * 128; ++i) rowmap[i] = -1;
    }
    __syncthreads();
    if (tid < T_) {
      meta[tid] = s_start[tid];
      const int st = s_start[tid], nb = s_nb[tid];
      for (int bb = 0; bb < nb; ++bb) rowmap[st + bb] = bb * T_ + tid;
      int zst = 0;
      for (int t2 = 0; t2 < tid; ++t2) zst += B_ - s_nb[t2];
      for (int bb = nb; bb < B_; ++bb) zrowmap[zst + (bb - nb)] = bb * T_ + tid;
    }
    __syncthreads();
    if (tid < 26) {
      const int Mc = s_start[T_];
      const int MT = (Mc + 127) >> 7;
      if (tid < MT) {
        int last = tid * 128 + 127;
        if (last > Mc - 1) last = Mc - 1;
        int tlast = 0;
        for (int t2 = 0; t2 < T_; ++t2) if (s_start[t2] <= last) tlast = t2;
        meta[110 + tid] = tlast + 1;
      }
    }
  }
}

// ---------------- zero the pad rows of compact Hall ----------------
__global__ __launch_bounds__(256) void pad_kernel(const int* __restrict__ meta,
                                                  unsigned short* __restrict__ Hall) {
  const int Mc = meta[100], MT = meta[101];
  const int tot = (MT * 128 - Mc) * 64;
  for (int i = blockIdx.x * blockDim.x + threadIdx.x; i < tot;
       i += gridDim.x * blockDim.x) {
    const int row = Mc + (i >> 6), c = i & 63;
    ushort4 z; z.x = z.y = z.z = z.w = 0;
    *(ushort4*)((char*)Hall + (size_t)row * 1024 + c * 16) = z;
  }
}

// ---------------- Gx GEMM: Gx = AxB @ WihB^T + bih + bhh (128x128 tile, K=512) ----------------
__global__ __launch_bounds__(256) void gemm_gx(
    const unsigned short* __restrict__ A, const unsigned short* __restrict__ Bm,
    float* __restrict__ C, const float* __restrict__ bias0, const float* __restrict__ bias1) {
  __shared__ __align__(16) char smem[65536];
  const int tid = threadIdx.x, lane = tid & 63, wid = tid >> 6;
  const int nt = blockIdx.x, mt = blockIdx.y;
  const int wr = wid >> 1, wc = wid & 1;
  const int m0 = mt * 128, n0 = nt * 128;
  f32x4 acc[4][4] = {};

  auto stage = [&](int buf, int kit) {
    const int k0b = kit * 128;
#pragma unroll
    for (int i = 0; i < 4; ++i) {
      int chunk = wid * 4 + i;
      int d = chunk * 1024 + lane * 16;
      int row = d >> 7, colb = d & 127;
      int sc = colb ^ ((row & 7) << 4);
      async16((const char*)A + (size_t)(m0 + row) * 1024 + k0b + sc,
              smem + buf * 16384 + chunk * 1024);
      async16((const char*)Bm + (size_t)(n0 + row) * 1024 + k0b + sc,
              smem + 32768 + buf * 16384 + chunk * 1024);
    }
  };

  stage(0, 0);
  __syncthreads();
  for (int kit = 0; kit < 8; ++kit) {
    const int buf = kit & 1;
    if (kit < 7) stage(buf ^ 1, kit + 1);
    const char* Ab = smem + buf * 16384;
    const char* Bb = smem + 32768 + buf * 16384;
#pragma unroll
    for (int kb = 0; kb < 2; ++kb) {
      const int colb = kb * 64 + (lane >> 4) * 16;
      bf16x8 af[4], bfb[4];
#pragma unroll
      for (int rt = 0; rt < 4; ++rt) {
        int ar = wr * 64 + rt * 16 + (lane & 15);
        af[rt] = *(const bf16x8*)(Ab + ar * 128 + (colb ^ ((ar & 7) << 4)));
        int br = wc * 64 + rt * 16 + (lane & 15);
        bfb[rt] = *(const bf16x8*)(Bb + br * 128 + (colb ^ ((br & 7) << 4)));
      }
#pragma unroll
      for (int i = 0; i < 4; ++i)
#pragma unroll
        for (int j = 0; j < 4; ++j)
          acc[i][j] = __builtin_amdgcn_mfma_f32_16x16x32_bf16(af[i], bfb[j], acc[i][j], 0, 0, 0);
    }
    __syncthreads();
  }
#pragma unroll
  for (int i = 0; i < 4; ++i) {
    const int rbase = m0 + wr * 64 + i * 16 + (lane >> 4) * 4;
#pragma unroll
    for (int j = 0; j < 4; ++j) {
      const int col = n0 + wc * 64 + j * 16 + (lane & 15);
#pragma unroll
      for (int r = 0; r < 4; ++r)
        C[(size_t)(rbase + r) * G4_ + col] = acc[i][j][r] + bias0[col] + bias1[col];
    }
  }
}

// ---------------- fused: XCD-exclusive LSTM producers + {convert|zero|GEMM} consumers ----------------
// 256 blocks x 512 thr, 128KB LDS -> EXACTLY 1 block/CU (no producer/consumer CU sharing).
// Elected XCD's 32 blocks are ALL producers (exclusive XCD + L2). Flags = proven agent-scope
// (MALL) protocol of round 9: ctrl[w*16]=step flag; ctrl[512]=prog; ctrl[528]=work ctr;
// ctrl[544]=converts; ctrl[560]=elected XCD+1; ctrl[576]=slot ctr; ctrl[592+x*16]=arrivals.
// h-slice data stays on the elected XCD's L2: plain stores + sc0 loads (streaming, L1-evicted).
__global__ __launch_bounds__(512, 1) void fused_kernel(
    const float* __restrict__ Gx, const unsigned short* __restrict__ WhhB,
    const unsigned short* __restrict__ h0b, const float* __restrict__ c0,
    unsigned short* __restrict__ hsl, unsigned short* __restrict__ Hall,
    const float* __restrict__ Wfc, unsigned short* __restrict__ WfcB,
    const float* __restrict__ bfc, const int* __restrict__ cap,
    float* __restrict__ outp, int* __restrict__ ctrl, const int* __restrict__ meta,
    const int* __restrict__ rowmap, const int* __restrict__ zrowmap) {
  __shared__ __align__(16) char smem[131072];
  const int tid = threadIdx.x, lane = tid & 63, wid = tid >> 6;
  int* s_tile = (int*)(smem + 131068);
  int* s_role = (int*)(smem + 131064);

  // ---- role election: first XCD to 32 arrivals owns the 32 producer slots ----
  {
    int xcc;
    asm volatile("s_getreg_b32 %0, hwreg(HW_REG_XCC_ID)" : "=s"(xcc));
    if (tid == 0) {
      xcc &= 7;
      int a = __hip_atomic_fetch_add(&ctrl[592 + xcc * 16], 1, __ATOMIC_RELAXED,
                                     __HIP_MEMORY_SCOPE_AGENT);
      if (a == NPROD - 1) {
        int expected = 0;
        __hip_atomic_compare_exchange_strong(&ctrl[560], &expected, xcc + 1,
                                             __ATOMIC_RELAXED, __ATOMIC_RELAXED,
                                             __HIP_MEMORY_SCOPE_AGENT);
      }
      int e;
      for (;;) {
        e = __hip_atomic_load(&ctrl[560], __ATOMIC_RELAXED, __HIP_MEMORY_SCOPE_AGENT);
        if (e) break;
        __builtin_amdgcn_s_sleep(2);
      }
      int slot = NPROD;
      if (e - 1 == xcc)
        slot = __hip_atomic_fetch_add(&ctrl[576], 1, __ATOMIC_RELAXED,
                                      __HIP_MEMORY_SCOPE_AGENT);
      *s_role = slot;
    }
    __syncthreads();
  }
  const int w = *s_role;
  __syncthreads();

  if (w < NPROD) {
    // ============ producer: one 512-thr WG (waves 0-3 compute) = 16 h-cols, 49 steps ============
    __builtin_amdgcn_s_setprio(1);
    const int hc0 = w * 16;
    const bool act = tid < 256;
    const int g = wid;               // gate group for act threads (0..3)
    const int chunk_hi = lane >> 5;
    bf16x8 wf[16];
    f32x4 creg = {};
    ushort4 hold = {};
    int b = 0, hq = 0, hc = 0, dl = 0, myoff = 0;
    int arb[4] = {};
    if (act) {
      const int gcol = g * 512 + hc0 + (lane & 15);
      const int ko = (lane >> 4) * 8;
#pragma unroll
      for (int kb = 0; kb < 16; ++kb)
        wf[kb] = *(const bf16x8*)&WhhB[(size_t)gcol * 512 + kb * 32 + ko];
      b = tid >> 2; hq = (tid & 3) * 4; hc = hc0 + hq;
      dl = cap[b] - 1;
      creg = *(const f32x4*)&c0[b * H_ + hc];
      hold = *(const ushort4*)&h0b[b * H_ + hc];
      myoff = ((b * 32) ^ (((b >> 2) & 7) << 4) ^ ((hq >> 3) << 4)) + ((hq & 7) * 2);
      union { ushort4 s; unsigned long long u; } cv; cv.s = hold;
      *(unsigned long long*)((char*)hsl + w * 2048 + myoff) = cv.u;   // plain -> shared L2
#pragma unroll
      for (int rt = 0; rt < 4; ++rt) {
        int ar = rt * 16 + (lane & 15);
        arb[rt] = (ar * 32) ^ (((ar >> 2) & 7) << 4) ^ (((lane >> 4) & 1) << 4);
      }
    }
    float (*gl)[64][16] = (float (*)[64][16])(smem + 65536);   // own region (128KB LDS)
    asm volatile("s_waitcnt vmcnt(0)" ::: "memory"); // slice in L2 before flag
    __syncthreads();
    if (tid == 0)
      __hip_atomic_store(&ctrl[w * 16], 1, __ATOMIC_RELAXED, __HIP_MEMORY_SCOPE_AGENT);

    for (int t = 0; t < T_; ++t) {
      f32x4 xi = {}, xf = {}, xg = {}, xo = {};
      if (act) {
        const size_t gxr = ((size_t)t * 64 + b) * (size_t)G4_ + hc;
        xi = *(const f32x4*)&Gx[gxr + 0];
        xf = *(const f32x4*)&Gx[gxr + 512];
        xg = *(const f32x4*)&Gx[gxr + 1024];
        xo = *(const f32x4*)&Gx[gxr + 1536];
      }
      __builtin_amdgcn_sched_barrier(0);
      // wait for all 32 agent flags >= t+1 (MALL; proven protocol)
      if (tid < 64) {
        const int need = t + 1;
        for (;;) {
          int v = (lane < NPROD)
                      ? __hip_atomic_load(&ctrl[lane * 16], __ATOMIC_RELAXED, __HIP_MEMORY_SCOPE_AGENT)
                      : need;
          if (__all(v >= need)) break;
          __builtin_amdgcn_s_sleep(1);
        }
        if (tid == 0 && w == 0 && t > 0)
          __hip_atomic_store(&ctrl[512], t, __ATOMIC_RELAXED, __HIP_MEMORY_SCOPE_AGENT);
      }
      __syncthreads();
      // stage all 32 slices of h(t): sc0 16B loads from shared L2 -> LDS (512 thr)
      {
        const char* src = (const char*)hsl + (t & 1) * 65536 + tid * 16;
        char* dst = smem + tid * 16;
        int4 hv[8];
#pragma unroll
        for (int i = 0; i < 8; ++i)
          asm volatile("global_load_dwordx4 %0, %1, off sc0"
                       : "=&v"(hv[i]) : "v"(src + i * 8192));
        asm volatile("s_waitcnt vmcnt(0)" ::: "memory");
#pragma unroll
        for (int i = 0; i < 8; ++i)
          *(int4*)(dst + i * 8192) = hv[i];
      }
      __syncthreads();
      if (act) {
        f32x4 accp[4] = {};
#pragma unroll
        for (int kb = 0; kb < 16; ++kb) {
          const int cbase = (kb * 2 + chunk_hi) * 2048;
#pragma unroll
          for (int rt = 0; rt < 4; ++rt) {
            bf16x8 af = *(const bf16x8*)(smem + cbase + arb[rt]);
            accp[rt] = __builtin_amdgcn_mfma_f32_16x16x32_bf16(af, wf[kb], accp[rt], 0, 0, 0);
          }
        }
#pragma unroll
        for (int rt = 0; rt < 4; ++rt)
#pragma unroll
          for (int r = 0; r < 4; ++r)
            gl[g][rt * 16 + (lane >> 4) * 4 + r][lane & 15] = accp[rt][r];
      }
      __syncthreads();
      if (act) {
        f32x4 vi = xi + *(const f32x4*)&gl[0][b][hq];
        f32x4 vf = xf + *(const f32x4*)&gl[1][b][hq];
        f32x4 vg = xg + *(const f32x4*)&gl[2][b][hq];
        f32x4 vo = xo + *(const f32x4*)&gl[3][b][hq];
        f32x4 cn;
        ushort4 hb16;
        {
          float hv4[4];
#pragma unroll
          for (int k = 0; k < 4; ++k) {
            float iv = sigf(vi[k]), fv = sigf(vf[k]), gv = tanhf(vg[k]), ov = sigf(vo[k]);
            cn[k] = fv * creg[k] + iv * gv;
            hv4[k] = ov * tanhf(cn[k]);
          }
          hb16.x = f2bf(hv4[0]); hb16.y = f2bf(hv4[1]); hb16.z = f2bf(hv4[2]); hb16.w = f2bf(hv4[3]);
        }
        if (t < dl) {   // Hall read cross-XCD: agent-scope (MALL)
          union { ushort4 s; unsigned long long u; } cv; cv.s = hb16;
          __hip_atomic_store((unsigned long long*)&Hall[((size_t)(meta[t] + b)) * H_ + hc],
                             cv.u, __ATOMIC_RELAXED, __HIP_MEMORY_SCOPE_AGENT);
          hold = hb16; creg = cn;
        }
        if (t + 1 < T_) {   // slice exchange intra-XCD: plain store -> shared L2
          union { ushort4 s; unsigned long long u; } cv; cv.s = hold;
          *(unsigned long long*)((char*)hsl + ((t + 1) & 1) * 65536 + w * 2048 + myoff) = cv.u;
        }
      }
      asm volatile("s_waitcnt vmcnt(0)" ::: "memory");  // drain hsl (L2) + Hall (MALL)
      __syncthreads();
      if (tid == 0)
        __hip_atomic_store(&ctrl[w * 16], t + 2, __ATOMIC_RELAXED, __HIP_MEMORY_SCOPE_AGENT);
    }
    if (w == 0 && tid < 64) {
      const int need = T_ + 1;
      for (;;) {
        int v = (lane < NPROD)
                    ? __hip_atomic_load(&ctrl[lane * 16], __ATOMIC_RELAXED, __HIP_MEMORY_SCOPE_AGENT)
                    : need;
        if (__all(v >= need)) break;
        __builtin_amdgcn_s_sleep(1);
      }
      if (tid == 0)
        __hip_atomic_store(&ctrl[512], T_, __ATOMIC_RELAXED, __HIP_MEMORY_SCOPE_AGENT);
    }
    __builtin_amdgcn_s_setprio(0);
  }

  // ================= consumer: converts, zero rows, compact vocab-GEMM tiles (8 waves) =========
  const int NZI = meta[104];
  const int NTOT = meta[105];
  const int wr = wid >> 2, wc = wid & 3;   // 2M x 4N waves over the 128x128 tile
  for (;;) {
    __syncthreads();
    if (tid == 0)
      *s_tile = __hip_atomic_fetch_add(&ctrl[528], 1, __ATOMIC_RELAXED, __HIP_MEMORY_SCOPE_AGENT);
    __syncthreads();
    const int tile = *s_tile;
    __syncthreads();
    if (tile >= NTOT) break;

    if (tile < NTN) {
      // convert item: Wfc rows [tile*128, tile*128+128) f32 -> bf16 (agent-scope stores)
      const float4* src = (const float4*)(Wfc + (size_t)tile * 128 * 512);
      unsigned long long* dst = (unsigned long long*)WfcB + (size_t)tile * 16384;
      for (int i = tid; i < 16384; i += 512) {
        float4 v = src[i];
        union { ushort4 s; unsigned long long u; } cv;
        cv.s.x = f2bf(v.x); cv.s.y = f2bf(v.y); cv.s.z = f2bf(v.z); cv.s.w = f2bf(v.w);
        __hip_atomic_store(&dst[i], cv.u, __ATOMIC_RELAXED, __HIP_MEMORY_SCOPE_AGENT);
      }
      asm volatile("s_waitcnt vmcnt(0)" ::: "memory");
      __syncthreads();
      if (tid == 0)
        __hip_atomic_fetch_add(&ctrl[544], 1, __ATOMIC_RELAXED, __HIP_MEMORY_SCOPE_AGENT);
      continue;
    }

    if (tile < NTN + NZI) {
      const int bt = zrowmap[tile - NTN];
      f32x4* dst = (f32x4*)(outp + (size_t)bt * V_);
      f32x4 z = {0.0f, 0.0f, 0.0f, 0.0f};
      for (int i = tid; i < V_ / 4; i += 512) dst[i] = z;
      continue;
    }

    const int gt = tile - NTN - NZI;
    const int mt = gt / NTN, nt = gt - mt * NTN;
    const int m0 = mt * 128, n0 = nt * 128;
    const int need = meta[110 + mt];
    if (tid == 0) {
      while (__hip_atomic_load(&ctrl[544], __ATOMIC_RELAXED, __HIP_MEMORY_SCOPE_AGENT) < NTN)
        __builtin_amdgcn_s_sleep(2);
      while (__hip_atomic_load(&ctrl[512], __ATOMIC_RELAXED, __HIP_MEMORY_SCOPE_AGENT) < need)
        __builtin_amdgcn_s_sleep(8);
    }
    __syncthreads();

    f32x4 acc[4][2] = {};
    auto stage = [&](int buf, int kit) {
      const int k0b = kit * 128;
#pragma unroll
      for (int i = 0; i < 2; ++i) {
        int chunk = wid * 2 + i;            // 0..15, 1KB each
        int d = chunk * 1024 + lane * 16;
        int row = d >> 7, colb = d & 127;
        int sc = colb ^ ((row & 7) << 4);
        async16((const char*)Hall + (size_t)(m0 + row) * 1024 + k0b + sc,
                smem + buf * 16384 + chunk * 1024);
        async16((const char*)WfcB + (size_t)(n0 + row) * 1024 + k0b + sc,
                smem + 32768 + buf * 16384 + chunk * 1024);
      }
    };
    stage(0, 0);
    __syncthreads();
    for (int kit = 0; kit < 8; ++kit) {
      const int buf = kit & 1;
      if (kit < 7) stage(buf ^ 1, kit + 1);
      const char* Ab = smem + buf * 16384;
      const char* Bb = smem + 32768 + buf * 16384;
#pragma unroll
      for (int kb = 0; kb < 2; ++kb) {
        const int colb = kb * 64 + (lane >> 4) * 16;
        bf16x8 bfb[2];
#pragma unroll
        for (int j = 0; j < 2; ++j) {
          int br = wc * 32 + j * 16 + (lane & 15);
          bfb[j] = *(const bf16x8*)(Bb + br * 128 + (colb ^ ((br & 7) << 4)));
        }
#pragma unroll
        for (int rt = 0; rt < 4; ++rt) {
          int ar = wr * 64 + rt * 16 + (lane & 15);
          bf16x8 af = *(const bf16x8*)(Ab + ar * 128 + (colb ^ ((ar & 7) << 4)));
#pragma unroll
          for (int j = 0; j < 2; ++j)
            acc[rt][j] = __builtin_amdgcn_mfma_f32_16x16x32_bf16(af, bfb[j], acc[rt][j], 0, 0, 0);
        }
      }
      __syncthreads();
    }
    float* Ct = (float*)smem;
#pragma unroll
    for (int j = 0; j < 2; ++j) {
      const int colL = wc * 32 + j * 16 + (lane & 15);
      const float bz = bfc[n0 + colL];
#pragma unroll
      for (int rt = 0; rt < 4; ++rt) {
        const int rb = wr * 64 + rt * 16 + (lane >> 4) * 4;
#pragma unroll
        for (int r = 0; r < 4; ++r) {
          const int row = rb + r;
          Ct[row * 128 + (colL ^ ((row & 7) << 2))] = acc[rt][j][r] + bz;
        }
      }
    }
    __syncthreads();
    const int c4 = tid & 31;
    const int rsub = tid >> 5;    // 0..15
#pragma unroll
    for (int itr = 0; itr < 8; ++itr) {
      const int row = itr * 16 + rsub;
      const int bt = rowmap[m0 + row];
      if (bt < 0) continue;
      f32x4 v = *(const f32x4*)&Ct[row * 128 + ((c4 ^ (row & 7)) << 2)];
      *(f32x4*)(outp + (size_t)bt * V_ + n0 + (c4 << 2)) = v;
    }
  }
}

// ---------------- launch ----------------
extern "C" void kernel_launch(void* const* d_in, const int* in_sizes, int n_in,
                              void* d_out, int out_size, void* d_ws, size_t ws_size,
                              hipStream_t stream) {
  const float* emb = (const float*)d_in[0];
  const float* enc = (const float*)d_in[1];
  const int*   cap = (const int*)d_in[2];
  const float* Wih = (const float*)d_in[3];
  const float* Whh = (const float*)d_in[4];
  const float* bih = (const float*)d_in[5];
  const float* bhh = (const float*)d_in[6];
  const float* Wh0 = (const float*)d_in[7];
  const float* bh0 = (const float*)d_in[8];
  const float* Wc0 = (const float*)d_in[9];
  const float* bc0 = (const float*)d_in[10];
  const float* Wfc = (const float*)d_in[11];
  const float* bfc = (const float*)d_in[12];
  float* out = (float*)d_out;

  char* ws = (char*)d_ws;
  size_t o = 0;
  auto carve = [&](size_t bytes) { void* p = ws + o; o += (bytes + 255) & ~(size_t)255; return p; };
  unsigned short* WihB = (unsigned short*)carve((size_t)G4_ * E_ * 2);
  unsigned short* WhhB = (unsigned short*)carve((size_t)G4_ * H_ * 2);
  unsigned short* WfcB = (unsigned short*)carve((size_t)V_ * H_ * 2);
  unsigned short* AxB  = (unsigned short*)carve((size_t)MPAD_ * E_ * 2);
  float*          Gx   = (float*)carve((size_t)MPAD_ * G4_ * 4);
  unsigned short* Hall = (unsigned short*)carve((size_t)MPAD_ * H_ * 2);
  unsigned short* h0b  = (unsigned short*)carve((size_t)B_ * H_ * 2);
  float*          cst  = (float*)carve((size_t)B_ * H_ * 4);
  unsigned short* hsl  = (unsigned short*)carve((size_t)2 * 65536);
  int*            ctrl = (int*)carve(4096);
  int*            meta = (int*)carve(1024);
  int*            rowmap = (int*)carve((size_t)MPAD_ * 4);
  int*            zrowmap = (int*)carve((size_t)MPAD_ * 4);
  (void)ws_size; (void)in_sizes; (void)n_in; (void)out_size;

  hipMemsetAsync(ctrl, 0, 4096, stream);
  convert_kernel<<<dim3(1024), dim3(256), 0, stream>>>(Wih, Whh, emb, WihB, WhhB, AxB);
  init_kernel<<<dim3(64, 4), dim3(256), 0, stream>>>(enc, cap, Wh0, bh0, Wc0, bc0, h0b, cst,
                                                     out + (size_t)B_ * T_ * V_,
                                                     meta, rowmap, zrowmap);
  pad_kernel<<<dim3(32), dim3(256), 0, stream>>>(meta, Hall);
  gemm_gx<<<dim3(G4_ / 128, MPAD_ / 128), dim3(256), 0, stream>>>(AxB, WihB, Gx, bih, bhh);
  fused_kernel<<<dim3(NWG), dim3(512), 0, stream>>>(Gx, WhhB, h0b, cst, hsl, Hall,
                                                    Wfc, WfcB, bfc, cap, out, ctrl,
                                                    meta, rowmap, zrowmap);
}

// Round 12
// 380.423 us; speedup vs baseline: 2.5707x; 1.0182x over previous
//
#include <hip/hip_runtime.h>
#include <stdint.h>

#define B_    64
#define T_    49
#define E_    512
#define H_    512
#define ENC_  1024
#define V_    32000
#define G4_   2048        // 4*H
#define M_    3136        // T_*B_
#define MPAD_ 3200        // 25*128
#define NPROD 16
#define NSCR  8
#define NWG   256
#define NTN   250         // 32000/128

typedef __attribute__((ext_vector_type(8))) short bf16x8;
typedef __attribute__((ext_vector_type(4))) float f32x4;

static __device__ __forceinline__ unsigned short f2bf(float f) {
  union { float f; uint32_t u; } v; v.f = f;
  uint32_t r = v.u + 0x7FFFu + ((v.u >> 16) & 1u);
  return (unsigned short)(r >> 16);
}
static __device__ __forceinline__ float bf2f(unsigned short u) {
  union { uint32_t i; float f; } c; c.i = (uint32_t)u << 16; return c.f;
}

static __device__ __forceinline__ void async16(const void* g, void* lds) {
  __builtin_amdgcn_global_load_lds(
      (const __attribute__((address_space(1))) unsigned int*)g,
      (__attribute__((address_space(3))) unsigned int*)lds, 16, 0, 0);
}

static __device__ __forceinline__ float sigf(float x) { return 1.0f / (1.0f + expf(-x)); }

// ---------------- convert small weights to bf16 (+ embeddings transpose) ----------------
__global__ __launch_bounds__(256) void convert_kernel(
    const float* __restrict__ Wih, const float* __restrict__ Whh,
    const float* __restrict__ emb,
    unsigned short* __restrict__ WihB, unsigned short* __restrict__ WhhB,
    unsigned short* __restrict__ AxB) {
  const int n_wih = (G4_ * E_) / 4;
  const int n_whh = (G4_ * H_) / 4;
  const int n_emb = (B_ * T_ * E_) / 4;
  const int n_pad = ((MPAD_ - M_) * E_) / 4;
  const long total = (long)n_wih + n_whh + n_emb + n_pad;
  for (long u = (long)blockIdx.x * blockDim.x + threadIdx.x; u < total;
       u += (long)gridDim.x * blockDim.x) {
    long i = u;
    if (i < n_wih) {
      float4 v = ((const float4*)Wih)[i];
      ushort4 o; o.x = f2bf(v.x); o.y = f2bf(v.y); o.z = f2bf(v.z); o.w = f2bf(v.w);
      ((ushort4*)WihB)[i] = o; continue;
    }
    i -= n_wih;
    if (i < n_whh) {
      float4 v = ((const float4*)Whh)[i];
      ushort4 o; o.x = f2bf(v.x); o.y = f2bf(v.y); o.z = f2bf(v.z); o.w = f2bf(v.w);
      ((ushort4*)WhhB)[i] = o; continue;
    }
    i -= n_whh;
    if (i < n_emb) {
      int bt = (int)(i >> 7);
      int e4 = (int)(i & 127);
      int b = bt / T_, t = bt - b * T_;
      float4 v = ((const float4*)emb)[i];
      ushort4 o; o.x = f2bf(v.x); o.y = f2bf(v.y); o.z = f2bf(v.z); o.w = f2bf(v.w);
      ((ushort4*)AxB)[((long)(t * 64 + b) << 7) + e4] = o; continue;
    }
    i -= n_emb;
    ushort4 z; z.x = z.y = z.z = z.w = 0;
    ((ushort4*)AxB)[((long)M_ << 7) + i] = z;
  }
}

// ---------------- init: h0, c0, decode_lengths + compaction metadata ----------------
// meta[0..48]=start[t]; meta[100]=Mc; meta[101]=MT; meta[104]=NZI;
// meta[105]=NTOT; meta[110+mt]=need[mt]
__global__ __launch_bounds__(256) void init_kernel(
    const float* __restrict__ enc, const int* __restrict__ cap,
    const float* __restrict__ Wh, const float* __restrict__ bh,
    const float* __restrict__ Wc, const float* __restrict__ bc,
    unsigned short* __restrict__ h0b, float* __restrict__ c0,
    float* __restrict__ out_dl, int* __restrict__ meta,
    int* __restrict__ rowmap, int* __restrict__ zrowmap) {
  __shared__ __align__(16) float e[ENC_];
  __shared__ int s_nb[T_];
  __shared__ int s_start[T_ + 1];
  const int b = blockIdx.x, q = blockIdx.y, tid = threadIdx.x;
  ((float4*)e)[tid] = ((const float4*)(enc + (size_t)b * ENC_))[tid];
  __syncthreads();
  const bool is_c = tid >= 128;
  const int j = q * 128 + (tid & 127);
  const float* W = is_c ? Wc : Wh;
  float s = is_c ? bc[j] : bh[j];
  const float4* wr = (const float4*)(W + (size_t)j * ENC_);
  const float4* e4 = (const float4*)e;
#pragma unroll 4
  for (int k = 0; k < ENC_ / 4; ++k) {
    float4 w = wr[k], v = e4[k];
    s += w.x * v.x + w.y * v.y + w.z * v.z + w.w * v.w;
  }
  if (is_c) c0[(size_t)b * H_ + j] = s;
  else      h0b[(size_t)b * H_ + j] = f2bf(s);
  if (b == 0 && q == 0 && tid < B_) out_dl[tid] = (float)(cap[tid] - 1);

  if (b == 0 && q == 0) {
    __syncthreads();
    if (tid < T_) {
      int cnt = 0;
      for (int bb = 0; bb < B_; ++bb) cnt += (cap[bb] - 1 > tid) ? 1 : 0;
      s_nb[tid] = cnt;
    }
    __syncthreads();
    if (tid == 0) {
      int acc = 0;
      for (int t = 0; t < T_; ++t) { s_start[t] = acc; acc += s_nb[t]; }
      s_start[T_] = acc;
      const int Mc = acc;
      const int MT = (Mc + 127) >> 7;
      meta[100] = Mc;
      meta[101] = MT;
      meta[104] = M_ - Mc;                       // NZI
      meta[105] = NTN + (M_ - Mc) + MT * NTN;    // NTOT
      for (int i = Mc; i < MT * 128; ++i) rowmap[i] = -1;
    }
    __syncthreads();
    if (tid < T_) {
      meta[tid] = s_start[tid];
      const int st = s_start[tid], nb = s_nb[tid];
      for (int bb = 0; bb < nb; ++bb) rowmap[st + bb] = bb * T_ + tid;
      int zst = 0;
      for (int t2 = 0; t2 < tid; ++t2) zst += B_ - s_nb[t2];
      for (int bb = nb; bb < B_; ++bb) zrowmap[zst + (bb - nb)] = bb * T_ + tid;
    }
    __syncthreads();
    if (tid < 26) {
      const int Mc = s_start[T_];
      const int MT = (Mc + 127) >> 7;
      if (tid < MT) {
        int last = tid * 128 + 127;
        if (last > Mc - 1) last = Mc - 1;
        int tlast = 0;
        for (int t2 = 0; t2 < T_; ++t2) if (s_start[t2] <= last) tlast = t2;
        meta[110 + tid] = tlast + 1;
      }
    }
  }
}

// ---------------- zero the pad rows of compact Hall ----------------
__global__ __launch_bounds__(256) void pad_kernel(const int* __restrict__ meta,
                                                  unsigned short* __restrict__ Hall) {
  const int Mc = meta[100], MT = meta[101];
  const int tot = (MT * 128 - Mc) * 64;
  for (int i = blockIdx.x * blockDim.x + threadIdx.x; i < tot;
       i += gridDim.x * blockDim.x) {
    const int row = Mc + (i >> 6), c = i & 63;
    ushort4 z; z.x = z.y = z.z = z.w = 0;
    *(ushort4*)((char*)Hall + (size_t)row * 1024 + c * 16) = z;
  }
}

// ---------------- Gx GEMM: GxB = bf16(AxB @ WihB^T + bih + bhh) (128x128 tile, K=512) --------
__global__ __launch_bounds__(256) void gemm_gx(
    const unsigned short* __restrict__ A, const unsigned short* __restrict__ Bm,
    unsigned short* __restrict__ C, const float* __restrict__ bias0,
    const float* __restrict__ bias1) {
  __shared__ __align__(16) char smem[65536];
  const int tid = threadIdx.x, lane = tid & 63, wid = tid >> 6;
  const int nt = blockIdx.x, mt = blockIdx.y;
  const int wr = wid >> 1, wc = wid & 1;
  const int m0 = mt * 128, n0 = nt * 128;
  f32x4 acc[4][4] = {};

  auto stage = [&](int buf, int kit) {
    const int k0b = kit * 128;
#pragma unroll
    for (int i = 0; i < 4; ++i) {
      int chunk = wid * 4 + i;
      int d = chunk * 1024 + lane * 16;
      int row = d >> 7, colb = d & 127;
      int sc = colb ^ ((row & 7) << 4);
      async16((const char*)A + (size_t)(m0 + row) * 1024 + k0b + sc,
              smem + buf * 16384 + chunk * 1024);
      async16((const char*)Bm + (size_t)(n0 + row) * 1024 + k0b + sc,
              smem + 32768 + buf * 16384 + chunk * 1024);
    }
  };

  stage(0, 0);
  __syncthreads();
  for (int kit = 0; kit < 8; ++kit) {
    const int buf = kit & 1;
    if (kit < 7) stage(buf ^ 1, kit + 1);
    const char* Ab = smem + buf * 16384;
    const char* Bb = smem + 32768 + buf * 16384;
#pragma unroll
    for (int kb = 0; kb < 2; ++kb) {
      const int colb = kb * 64 + (lane >> 4) * 16;
      bf16x8 af[4], bfb[4];
#pragma unroll
      for (int rt = 0; rt < 4; ++rt) {
        int ar = wr * 64 + rt * 16 + (lane & 15);
        af[rt] = *(const bf16x8*)(Ab + ar * 128 + (colb ^ ((ar & 7) << 4)));
        int br = wc * 64 + rt * 16 + (lane & 15);
        bfb[rt] = *(const bf16x8*)(Bb + br * 128 + (colb ^ ((br & 7) << 4)));
      }
#pragma unroll
      for (int i = 0; i < 4; ++i)
#pragma unroll
        for (int j = 0; j < 4; ++j)
          acc[i][j] = __builtin_amdgcn_mfma_f32_16x16x32_bf16(af[i], bfb[j], acc[i][j], 0, 0, 0);
    }
    __syncthreads();
  }
#pragma unroll
  for (int i = 0; i < 4; ++i) {
    const int rbase = m0 + wr * 64 + i * 16 + (lane >> 4) * 4;
#pragma unroll
    for (int j = 0; j < 4; ++j) {
      const int col = n0 + wc * 64 + j * 16 + (lane & 15);
      const float bz = bias0[col] + bias1[col];
#pragma unroll
      for (int r = 0; r < 4; ++r)
        C[(size_t)(rbase + r) * G4_ + col] = f2bf(acc[i][j][r] + bz);
    }
  }
}

// ---------------- fused: producers(16) + scribes(8) on elected XCD + consumers ----------------
// ctrl[w*16] w<16: producer step flag (MALL); w in [16,24): scribe flag (Hall rows t<flag done).
// ctrl[528]=work ctr; ctrl[544]=converts; ctrl[560]=elected XCD+1; ctrl[576]=slot ctr;
// ctrl[592+x*16]=arrivals. hsl = 3 x 64KB (triple buffer, elected-XCD L2, plain stores + sc0).
// Producer release = vmcnt(0) [L2 only: no Hall stores!] + barrier + flag. Scribes copy
// hsl -> Hall (agent) with 2-step slack (producers gate on scribe >= t-2).
__global__ __launch_bounds__(512, 1) void fused_kernel(
    const unsigned short* __restrict__ GxB, const unsigned short* __restrict__ WhhB,
    const unsigned short* __restrict__ h0b, const float* __restrict__ c0,
    unsigned short* __restrict__ hsl, unsigned short* __restrict__ Hall,
    const float* __restrict__ Wfc, unsigned short* __restrict__ WfcB,
    const float* __restrict__ bfc, const int* __restrict__ cap,
    float* __restrict__ outp, int* __restrict__ ctrl, const int* __restrict__ meta,
    const int* __restrict__ rowmap, const int* __restrict__ zrowmap) {
  __shared__ __align__(16) char smem[131072];
  const int tid = threadIdx.x, lane = tid & 63, wid = tid >> 6;
  int* s_tile = (int*)(smem + 131068);
  int* s_role = (int*)(smem + 131064);

  // ---- role election: first XCD to NPROD+NSCR arrivals owns producer+scribe slots ----
  {
    int xcc;
    asm volatile("s_getreg_b32 %0, hwreg(HW_REG_XCC_ID)" : "=s"(xcc));
    if (tid == 0) {
      xcc &= 7;
      int a = __hip_atomic_fetch_add(&ctrl[592 + xcc * 16], 1, __ATOMIC_RELAXED,
                                     __HIP_MEMORY_SCOPE_AGENT);
      if (a == NPROD + NSCR - 1) {
        int expected = 0;
        __hip_atomic_compare_exchange_strong(&ctrl[560], &expected, xcc + 1,
                                             __ATOMIC_RELAXED, __ATOMIC_RELAXED,
                                             __HIP_MEMORY_SCOPE_AGENT);
      }
      int e;
      for (;;) {
        e = __hip_atomic_load(&ctrl[560], __ATOMIC_RELAXED, __HIP_MEMORY_SCOPE_AGENT);
        if (e) break;
        __builtin_amdgcn_s_sleep(2);
      }
      int slot = 1000;
      if (e - 1 == xcc)
        slot = __hip_atomic_fetch_add(&ctrl[576], 1, __ATOMIC_RELAXED,
                                      __HIP_MEMORY_SCOPE_AGENT);
      *s_role = slot;
    }
    __syncthreads();
  }
  const int w = *s_role;
  __syncthreads();

  if (w < NPROD) {
    // ============ producer: 512 thr (8 waves all compute), 32 h-cols, 49 steps ============
    __builtin_amdgcn_s_setprio(1);
    const int hc0 = w * 32;
    // wf: wave wid -> gate g=wid>>1, col-half ch=wid&1
    const int gcol = (wid >> 1) * 512 + hc0 + (wid & 1) * 16 + (lane & 15);
    const int ko = (lane >> 4) * 8;
    bf16x8 wf[16];
#pragma unroll
    for (int kb = 0; kb < 16; ++kb)
      wf[kb] = *(const bf16x8*)&WhhB[(size_t)gcol * 512 + kb * 32 + ko];
    const int b = tid >> 3, hq = (tid & 7) * 4, hc = hc0 + hq;
    const int dl = cap[b] - 1;
    f32x4 creg = *(const f32x4*)&c0[b * H_ + hc];
    ushort4 hold = *(const ushort4*)&h0b[b * H_ + hc];
    const int myoff = w * 4096 + (hq >> 4) * 2048 +
                      ((b * 32) ^ (((b >> 2) & 7) << 4) ^ (((hq >> 3) & 1) << 4)) +
                      (hq & 7) * 2;
    {
      union { ushort4 s; unsigned long long u; } cv; cv.s = hold;
      *(unsigned long long*)((char*)hsl + myoff) = cv.u;   // h(0) -> buffer 0 (plain, L2)
    }
    int arb[4];
#pragma unroll
    for (int rt = 0; rt < 4; ++rt) {
      int ar = rt * 16 + (lane & 15);
      arb[rt] = (ar * 32) ^ (((ar >> 2) & 7) << 4) ^ (((lane >> 4) & 1) << 4);
    }
    const int chunk_hi = lane >> 5;
    float (*gl)[64][16] = (float (*)[64][16])(smem + 65536);   // [8][64][16]
    asm volatile("s_waitcnt vmcnt(0)" ::: "memory");
    __syncthreads();
    if (tid == 0)
      __hip_atomic_store(&ctrl[w * 16], 1, __ATOMIC_RELAXED, __HIP_MEMORY_SCOPE_AGENT);

    for (int t = 0; t < T_; ++t) {
      // Gx prefetch (bf16, 4 gates x 4 cols = 4x8B)
      const size_t gxr = ((size_t)t * 64 + b) * (size_t)G4_ + hc0 + hq;
      ushort4 gx0 = *(const ushort4*)&GxB[gxr + 0];
      ushort4 gx1 = *(const ushort4*)&GxB[gxr + 512];
      ushort4 gx2 = *(const ushort4*)&GxB[gxr + 1024];
      ushort4 gx3 = *(const ushort4*)&GxB[gxr + 1536];
      __builtin_amdgcn_sched_barrier(0);
      // wait: producers >= t+1, scribes >= t-2 (triple-buffer slack)
      if (tid < 64) {
        const int need_p = t + 1;
        const int need_s = (t >= 2) ? (t - 2) : 0;
        for (;;) {
          int v = 0x7fffffff, need = 0;
          if (lane < NPROD) { v = __hip_atomic_load(&ctrl[lane * 16], __ATOMIC_RELAXED, __HIP_MEMORY_SCOPE_AGENT); need = need_p; }
          else if (lane < NPROD + NSCR) { v = __hip_atomic_load(&ctrl[lane * 16], __ATOMIC_RELAXED, __HIP_MEMORY_SCOPE_AGENT); need = need_s; }
          if (__all(v >= need)) break;
          __builtin_amdgcn_s_sleep(1);
        }
      }
      __syncthreads();
      // stage h(t) (buffer t%3): sc0 16B loads from shared L2 -> LDS
      {
        const char* src = (const char*)hsl + (t % 3) * 65536 + tid * 16;
        char* dst = smem + tid * 16;
        int4 hv[8];
#pragma unroll
        for (int i = 0; i < 8; ++i)
          asm volatile("global_load_dwordx4 %0, %1, off sc0"
                       : "=&v"(hv[i]) : "v"(src + i * 8192));
        asm volatile("s_waitcnt vmcnt(0)" ::: "memory");
#pragma unroll
        for (int i = 0; i < 8; ++i)
          *(int4*)(dst + i * 8192) = hv[i];
      }
      __syncthreads();
      // all 8 waves: gates block (16 gate-rows each) = h(t) @ Whh^T
      {
        f32x4 accp[4] = {};
#pragma unroll
        for (int kb = 0; kb < 16; ++kb) {
          const int cbase = (kb * 2 + chunk_hi) * 2048;
#pragma unroll
          for (int rt = 0; rt < 4; ++rt) {
            bf16x8 af = *(const bf16x8*)(smem + cbase + arb[rt]);
            accp[rt] = __builtin_amdgcn_mfma_f32_16x16x32_bf16(af, wf[kb], accp[rt], 0, 0, 0);
          }
        }
#pragma unroll
        for (int rt = 0; rt < 4; ++rt)
#pragma unroll
          for (int r = 0; r < 4; ++r)
            gl[wid][rt * 16 + (lane >> 4) * 4 + r][lane & 15] = accp[rt][r];
      }
      __syncthreads();
      // elementwise: thread owns (batch b, cols hc..hc+4); gate g in wave 2g+(hq>>4)
      {
        const int wsel = hq >> 4, ci = hq & 15;
        f32x4 vi = *(const f32x4*)&gl[0 + wsel][b][ci];
        f32x4 vf = *(const f32x4*)&gl[2 + wsel][b][ci];
        f32x4 vg = *(const f32x4*)&gl[4 + wsel][b][ci];
        f32x4 vo = *(const f32x4*)&gl[6 + wsel][b][ci];
        vi[0] += bf2f(gx0.x); vi[1] += bf2f(gx0.y); vi[2] += bf2f(gx0.z); vi[3] += bf2f(gx0.w);
        vf[0] += bf2f(gx1.x); vf[1] += bf2f(gx1.y); vf[2] += bf2f(gx1.z); vf[3] += bf2f(gx1.w);
        vg[0] += bf2f(gx2.x); vg[1] += bf2f(gx2.y); vg[2] += bf2f(gx2.z); vg[3] += bf2f(gx2.w);
        vo[0] += bf2f(gx3.x); vo[1] += bf2f(gx3.y); vo[2] += bf2f(gx3.z); vo[3] += bf2f(gx3.w);
        f32x4 cn;
        ushort4 hb16;
        float hv4[4];
#pragma unroll
        for (int k = 0; k < 4; ++k) {
          float iv = sigf(vi[k]), fv = sigf(vf[k]), gv = tanhf(vg[k]), ov = sigf(vo[k]);
          cn[k] = fv * creg[k] + iv * gv;
          hv4[k] = ov * tanhf(cn[k]);
        }
        hb16.x = f2bf(hv4[0]); hb16.y = f2bf(hv4[1]); hb16.z = f2bf(hv4[2]); hb16.w = f2bf(hv4[3]);
        if (t < dl) { hold = hb16; creg = cn; }
        union { ushort4 s; unsigned long long u; } cv; cv.s = hold;
        *(unsigned long long*)((char*)hsl + ((t + 1) % 3) * 65536 + myoff) = cv.u;
      }
      asm volatile("s_waitcnt vmcnt(0)" ::: "memory");  // drain hsl (L2-only; fast)
      __syncthreads();
      if (tid == 0)
        __hip_atomic_store(&ctrl[w * 16], t + 2, __ATOMIC_RELAXED, __HIP_MEMORY_SCOPE_AGENT);
    }
    __builtin_amdgcn_s_setprio(0);
  } else if (w < NPROD + NSCR) {
    // ============ scribe: copy hsl slices -> compact Hall (agent), publish hall flags ========
    const int s = w - NPROD;
    const int r8 = tid >> 6;              // 0..7
    const int b = s * 8 + r8;             // batch row
    const int l = lane;                   // 16B chunk (col c = l*8)
    const int srcoff = (l >> 2) * 4096 + ((l >> 1) & 1) * 2048 +
                       ((b * 32) ^ (((b >> 2) & 7) << 4) ^ ((l & 1) << 4));
    for (int tau = 1; tau <= T_; ++tau) {
      if (tid < 64) {
        for (;;) {
          int v = (lane < NPROD)
                      ? __hip_atomic_load(&ctrl[lane * 16], __ATOMIC_RELAXED, __HIP_MEMORY_SCOPE_AGENT)
                      : (tau + 1);
          if (__all(v >= tau + 1)) break;
          __builtin_amdgcn_s_sleep(1);
        }
      }
      __syncthreads();
      const int st = meta[tau - 1];
      const int nb = ((tau < T_) ? meta[tau] : meta[100]) - st;
      if (b < nb) {
        int4 hv;
        const char* src = (const char*)hsl + (tau % 3) * 65536 + srcoff;
        asm volatile("global_load_dwordx4 %0, %1, off sc0" : "=&v"(hv) : "v"(src));
        asm volatile("s_waitcnt vmcnt(0)" ::: "memory");
        union { int4 v; unsigned long long u[2]; } cv; cv.v = hv;
        unsigned long long* dst = (unsigned long long*)&Hall[(size_t)(st + b) * H_ + l * 8];
        __hip_atomic_store(&dst[0], cv.u[0], __ATOMIC_RELAXED, __HIP_MEMORY_SCOPE_AGENT);
        __hip_atomic_store(&dst[1], cv.u[1], __ATOMIC_RELAXED, __HIP_MEMORY_SCOPE_AGENT);
      }
      asm volatile("s_waitcnt vmcnt(0)" ::: "memory");
      __syncthreads();
      if (tid == 0)
        __hip_atomic_store(&ctrl[w * 16], tau, __ATOMIC_RELAXED, __HIP_MEMORY_SCOPE_AGENT);
    }
  }

  // ================= consumer: converts, zero rows, compact vocab-GEMM tiles (8 waves) =========
  const int NZI = meta[104];
  const int NTOT = meta[105];
  const int wr = wid >> 2, wc = wid & 3;   // 2M x 4N waves over the 128x128 tile
  for (;;) {
    __syncthreads();
    if (tid == 0)
      *s_tile = __hip_atomic_fetch_add(&ctrl[528], 1, __ATOMIC_RELAXED, __HIP_MEMORY_SCOPE_AGENT);
    __syncthreads();
    const int tile = *s_tile;
    __syncthreads();
    if (tile >= NTOT) break;

    if (tile < NTN) {
      const float4* src = (const float4*)(Wfc + (size_t)tile * 128 * 512);
      unsigned long long* dst = (unsigned long long*)WfcB + (size_t)tile * 16384;
      for (int i = tid; i < 16384; i += 512) {
        float4 v = src[i];
        union { ushort4 s; unsigned long long u; } cv;
        cv.s.x = f2bf(v.x); cv.s.y = f2bf(v.y); cv.s.z = f2bf(v.z); cv.s.w = f2bf(v.w);
        __hip_atomic_store(&dst[i], cv.u, __ATOMIC_RELAXED, __HIP_MEMORY_SCOPE_AGENT);
      }
      asm volatile("s_waitcnt vmcnt(0)" ::: "memory");
      __syncthreads();
      if (tid == 0)
        __hip_atomic_fetch_add(&ctrl[544], 1, __ATOMIC_RELAXED, __HIP_MEMORY_SCOPE_AGENT);
      continue;
    }

    if (tile < NTN + NZI) {
      const int bt = zrowmap[tile - NTN];
      f32x4* dst = (f32x4*)(outp + (size_t)bt * V_);
      f32x4 z = {0.0f, 0.0f, 0.0f, 0.0f};
      for (int i = tid; i < V_ / 4; i += 512) dst[i] = z;
      continue;
    }

    const int gt = tile - NTN - NZI;
    const int mt = gt / NTN, nt = gt - mt * NTN;
    const int m0 = mt * 128, n0 = nt * 128;
    const int need = meta[110 + mt];
    if (tid == 0) {
      while (__hip_atomic_load(&ctrl[544], __ATOMIC_RELAXED, __HIP_MEMORY_SCOPE_AGENT) < NTN)
        __builtin_amdgcn_s_sleep(2);
    }
    if (tid < 64) {   // wait all 8 scribe flags >= need
      for (;;) {
        int v = (lane < NSCR)
                    ? __hip_atomic_load(&ctrl[(NPROD + lane) * 16], __ATOMIC_RELAXED, __HIP_MEMORY_SCOPE_AGENT)
                    : need;
        if (__all(v >= need)) break;
        __builtin_amdgcn_s_sleep(8);
      }
    }
    __syncthreads();

    f32x4 acc[4][2] = {};
    auto stage = [&](int buf, int kit) {
      const int k0b = kit * 128;
#pragma unroll
      for (int i = 0; i < 2; ++i) {
        int chunk = wid * 2 + i;
        int d = chunk * 1024 + lane * 16;
        int row = d >> 7, colb = d & 127;
        int sc = colb ^ ((row & 7) << 4);
        async16((const char*)Hall + (size_t)(m0 + row) * 1024 + k0b + sc,
                smem + buf * 16384 + chunk * 1024);
        async16((const char*)WfcB + (size_t)(n0 + row) * 1024 + k0b + sc,
                smem + 32768 + buf * 16384 + chunk * 1024);
      }
    };
    stage(0, 0);
    __syncthreads();
    for (int kit = 0; kit < 8; ++kit) {
      const int buf = kit & 1;
      if (kit < 7) stage(buf ^ 1, kit + 1);
      const char* Ab = smem + buf * 16384;
      const char* Bb = smem + 32768 + buf * 16384;
#pragma unroll
      for (int kb = 0; kb < 2; ++kb) {
        const int colb = kb * 64 + (lane >> 4) * 16;
        bf16x8 bfb[2];
#pragma unroll
        for (int j = 0; j < 2; ++j) {
          int br = wc * 32 + j * 16 + (lane & 15);
          bfb[j] = *(const bf16x8*)(Bb + br * 128 + (colb ^ ((br & 7) << 4)));
        }
#pragma unroll
        for (int rt = 0; rt < 4; ++rt) {
          int ar = wr * 64 + rt * 16 + (lane & 15);
          bf16x8 af = *(const bf16x8*)(Ab + ar * 128 + (colb ^ ((ar & 7) << 4)));
#pragma unroll
          for (int j = 0; j < 2; ++j)
            acc[rt][j] = __builtin_amdgcn_mfma_f32_16x16x32_bf16(af, bfb[j], acc[rt][j], 0, 0, 0);
        }
      }
      __syncthreads();
    }
    float* Ct = (float*)smem;
#pragma unroll
    for (int j = 0; j < 2; ++j) {
      const int colL = wc * 32 + j * 16 + (lane & 15);
      const float bz = bfc[n0 + colL];
#pragma unroll
      for (int rt = 0; rt < 4; ++rt) {
        const int rb = wr * 64 + rt * 16 + (lane >> 4) * 4;
#pragma unroll
        for (int r = 0; r < 4; ++r) {
          const int row = rb + r;
          Ct[row * 128 + (colL ^ ((row & 7) << 2))] = acc[rt][j][r] + bz;
        }
      }
    }
    __syncthreads();
    const int c4 = tid & 31;
    const int rsub = tid >> 5;
#pragma unroll
    for (int itr = 0; itr < 8; ++itr) {
      const int row = itr * 16 + rsub;
      const int bt = rowmap[m0 + row];
      if (bt < 0) continue;
      f32x4 v = *(const f32x4*)&Ct[row * 128 + ((c4 ^ (row & 7)) << 2)];
      *(f32x4*)(outp + (size_t)bt * V_ + n0 + (c4 << 2)) = v;
    }
  }
}

// ---------------- launch ----------------
extern "C" void kernel_launch(void* const* d_in, const int* in_sizes, int n_in,
                              void* d_out, int out_size, void* d_ws, size_t ws_size,
                              hipStream_t stream) {
  const float* emb = (const float*)d_in[0];
  const float* enc = (const float*)d_in[1];
  const int*   cap = (const int*)d_in[2];
  const float* Wih = (const float*)d_in[3];
  const float* Whh = (const float*)d_in[4];
  const float* bih = (const float*)d_in[5];
  const float* bhh = (const float*)d_in[6];
  const float* Wh0 = (const float*)d_in[7];
  const float* bh0 = (const float*)d_in[8];
  const float* Wc0 = (const float*)d_in[9];
  const float* bc0 = (const float*)d_in[10];
  const float* Wfc = (const float*)d_in[11];
  const float* bfc = (const float*)d_in[12];
  float* out = (float*)d_out;

  char* ws = (char*)d_ws;
  size_t o = 0;
  auto carve = [&](size_t bytes) { void* p = ws + o; o += (bytes + 255) & ~(size_t)255; return p; };
  unsigned short* WihB = (unsigned short*)carve((size_t)G4_ * E_ * 2);
  unsigned short* WhhB = (unsigned short*)carve((size_t)G4_ * H_ * 2);
  unsigned short* WfcB = (unsigned short*)carve((size_t)V_ * H_ * 2);
  unsigned short* AxB  = (unsigned short*)carve((size_t)MPAD_ * E_ * 2);
  unsigned short* GxB  = (unsigned short*)carve((size_t)MPAD_ * G4_ * 2);  // bf16, 13 MB
  unsigned short* Hall = (unsigned short*)carve((size_t)MPAD_ * H_ * 2);
  unsigned short* h0b  = (unsigned short*)carve((size_t)B_ * H_ * 2);
  float*          cst  = (float*)carve((size_t)B_ * H_ * 4);
  unsigned short* hsl  = (unsigned short*)carve((size_t)3 * 65536);       // triple buffer
  int*            ctrl = (int*)carve(4096);
  int*            meta = (int*)carve(1024);
  int*            rowmap = (int*)carve((size_t)MPAD_ * 4);
  int*            zrowmap = (int*)carve((size_t)MPAD_ * 4);
  (void)ws_size; (void)in_sizes; (void)n_in; (void)out_size;

  hipMemsetAsync(ctrl, 0, 4096, stream);
  convert_kernel<<<dim3(1024), dim3(256), 0, stream>>>(Wih, Whh, emb, WihB, WhhB, AxB);
  init_kernel<<<dim3(64, 4), dim3(256), 0, stream>>>(enc, cap, Wh0, bh0, Wc0, bc0, h0b, cst,
                                                     out + (size_t)B_ * T_ * V_,
                                                     meta, rowmap, zrowmap);
  pad_kernel<<<dim3(32), dim3(256), 0, stream>>>(meta, Hall);
  gemm_gx<<<dim3(G4_ / 128, MPAD_ / 128), dim3(256), 0, stream>>>(AxB, WihB, GxB, bih, bhh);
  fused_kernel<<<dim3(NWG), dim3(512), 0, stream>>>(GxB, WhhB, h0b, cst, hsl, Hall,
                                                    Wfc, WfcB, bfc, cap, out, ctrl,
                                                    meta, rowmap, zrowmap);
}